// Round 4
// baseline (1037.790 us; speedup 1.0000x reference)
//
#include <hip/hip_runtime.h>
#include <hip/hip_bf16.h>

#define DEV __device__ __forceinline__

typedef short bf16x8 __attribute__((ext_vector_type(8)));
typedef float f32x4 __attribute__((ext_vector_type(4)));

static constexpr int BATCH  = 2;
static constexpr int SEQ    = 1024;
static constexpr int DMODEL = 1024;
static constexpr int DINNER = 2048;
static constexpr int DSTATE = 64;
static constexpr int NH     = 32;
static constexpr int HD     = 64;
static constexpr int CONVD  = 2176;
static constexpr int DPROJ  = 4256;
static constexpr int MROWS  = BATCH * SEQ;   // 2048

// ---- workspace layout (bytes) ---- peak ~55.7 MB
static constexpr size_t OFF_ZX = 0;
static constexpr size_t OFF_XS = OFF_ZX + (size_t)2*MROWS*DPROJ*2;   // bf16 [4096][2048]; reused as yn
static constexpr size_t OFF_BB = OFF_XS + (size_t)2*MROWS*DINNER*2;  // f32 [4096][64]
static constexpr size_t OFF_CC = OFF_BB + (size_t)2*MROWS*DSTATE*4;  // f32 [4096][64]
static constexpr size_t OFF_DT = OFF_CC + (size_t)2*MROWS*DSTATE*4;  // f32 [4][32][1024] (transposed)
static constexpr size_t OFF_DA = OFF_DT + (size_t)2*MROWS*NH*4;      // f32 [4][32][1024] (transposed)
static constexpr size_t OFF_DR = OFF_DA + (size_t)2*MROWS*NH*4;      // f32 [4096][32] raw dt spill
static constexpr size_t OFF_DO = 0;                                  // bf16 [4096][1024] (aliases zx)
static constexpr size_t OFF_H  = OFF_DO + (size_t)2*MROWS*DMODEL*2;  // f32  [2048][1024] (aliases zx)

DEV float b2f(ushort u) {
    union { unsigned int i; float f; } v;
    v.i = ((unsigned int)u) << 16;
    return v.f;
}
DEV ushort f2b(float f) {
    union { float f; unsigned int u; } v;
    v.f = f;
    unsigned int r = 0x7FFFu + ((v.u >> 16) & 1u);
    return (ushort)((v.u + r) >> 16);
}

// ---------------------------------------------------------------------------
// GEMM: C[m][n] = sum_k A[m][k] * W[n][k]   (W row-major (N,K), fp32 ->bf16)
// ---------------------------------------------------------------------------
template<int MODE>
__global__ __launch_bounds__(256) void gemm_k(
    const void* __restrict__ asrc_,
    const float* __restrict__ w0, const float* __restrict__ w1,
    void* __restrict__ outp,
    const float* __restrict__ resid, const float* __restrict__ bias,
    float* __restrict__ dtraw, int N, int K)
{
    constexpr int BM = 128, BN = 64, BK = 32;
    __shared__ ushort As[BM][BK + 8];
    __shared__ ushort Bs[BN][BK + 8];
    const int tid  = threadIdx.x;
    const int wave = tid >> 6, lane = tid & 63;
    const int bn = blockIdx.x * BN, bm = blockIdx.y * BM;
    const int dir = blockIdx.z;
    const float* w = dir ? w1 : w0;

    f32x4 acc[2][4] = {};

    for (int k0 = 0; k0 < K; k0 += BK) {
        if (MODE == 0) {
            const float* xf = (const float*)asrc_;
            #pragma unroll
            for (int pass = 0; pass < 4; pass++) {
                int idx = pass * 256 + tid;
                int row = idx >> 3, cg = (idx & 7) * 4;
                int m = bm + row, k = k0 + cg;
                int b = m >> 10, l = m & 1023;
                int ls = dir ? (1023 - l) : l;
                float4 f = *(const float4*)(xf + (size_t)(b * SEQ + ls) * DMODEL + k);
                ushort4 u;
                u.x = f2b(f.x); u.y = f2b(f.y); u.z = f2b(f.z); u.w = f2b(f.w);
                *(ushort4*)&As[row][cg] = u;
            }
        } else {
            const ushort* ab = (const ushort*)asrc_;
            #pragma unroll
            for (int pass = 0; pass < 2; pass++) {
                int idx = pass * 256 + tid;
                int row = idx >> 2, cg = (idx & 3) * 8;
                int m = bm + row, k = k0 + cg;
                const ushort* src;
                if (MODE == 1) {
                    src = ab + ((size_t)(dir * MROWS + m) * DINNER + k);
                } else {
                    if (k < DMODEL) {
                        src = ab + ((size_t)m * DMODEL + k);
                    } else {
                        int l = m & 1023;
                        int m2 = (m & ~1023) | (1023 - l);
                        src = ab + ((size_t)(MROWS + m2) * DMODEL + (k - DMODEL));
                    }
                }
                *(uint4*)&As[row][cg] = *(const uint4*)src;
            }
        }
        #pragma unroll
        for (int pass = 0; pass < 2; pass++) {
            int idx = pass * 256 + tid;
            int row = idx >> 3, cg = (idx & 7) * 4;
            int n = bn + row, k = k0 + cg;
            float4 f = {0.f, 0.f, 0.f, 0.f};
            if (n < N) f = *(const float4*)(w + (size_t)n * K + k);
            ushort4 u;
            u.x = f2b(f.x); u.y = f2b(f.y); u.z = f2b(f.z); u.w = f2b(f.w);
            *(ushort4*)&Bs[row][cg] = u;
        }
        __syncthreads();

        const int ar = wave * 32 + (lane & 15);
        const int ko = (lane >> 4) * 8;
        bf16x8 a0 = *(const bf16x8*)&As[ar][ko];
        bf16x8 a1 = *(const bf16x8*)&As[ar + 16][ko];
        #pragma unroll
        for (int ni = 0; ni < 4; ni++) {
            bf16x8 bfr = *(const bf16x8*)&Bs[ni * 16 + (lane & 15)][ko];
            acc[0][ni] = __builtin_amdgcn_mfma_f32_16x16x32_bf16(a0, bfr, acc[0][ni], 0, 0, 0);
            acc[1][ni] = __builtin_amdgcn_mfma_f32_16x16x32_bf16(a1, bfr, acc[1][ni], 0, 0, 0);
        }
        __syncthreads();
    }

    #pragma unroll
    for (int mi = 0; mi < 2; mi++) {
        #pragma unroll
        for (int ni = 0; ni < 4; ni++) {
            #pragma unroll
            for (int j = 0; j < 4; j++) {
                int row = bm + wave * 32 + mi * 16 + (lane >> 4) * 4 + j;
                int col = bn + ni * 16 + (lane & 15);
                if (col >= N) continue;
                float v = acc[mi][ni][j];
                if (MODE == 0) {
                    ((ushort*)outp)[(size_t)(dir * MROWS + row) * DPROJ + col] = f2b(v);
                    if (col >= 4224)
                        dtraw[(size_t)(dir * MROWS + row) * NH + (col - 4224)] = v;
                } else if (MODE == 1) {
                    ((ushort*)outp)[(size_t)(dir * MROWS + row) * DMODEL + col] = f2b(v);
                } else {
                    float r = resid[(size_t)row * DMODEL + col] + bias[col];
                    ((float*)outp)[(size_t)row * DMODEL + col] = v + r;
                }
            }
        }
    }
}

// ---------------------------------------------------------------------------
// causal depthwise conv(width 4) + bias + SiLU; dt = softplus(raw+bias); dA
// dt/dA written TRANSPOSED: [dirb*32+h][l]
// ---------------------------------------------------------------------------
__global__ __launch_bounds__(256) void conv_k(
    const ushort* __restrict__ zx, const float* __restrict__ dtr,
    const float* __restrict__ cw0, const float* __restrict__ cb0,
    const float* __restrict__ cw1, const float* __restrict__ cb1,
    const float* __restrict__ dtb0, const float* __restrict__ al0,
    const float* __restrict__ dtb1, const float* __restrict__ al1,
    ushort* __restrict__ xs, float* __restrict__ Bq, float* __restrict__ Cq,
    float* __restrict__ dtq, float* __restrict__ daq)
{
    int id = blockIdx.x;                 // dirb*1024 + l
    int dir = id >> 11;
    int m = id & 2047;
    int l = m & 1023;
    const float* cw = dir ? cw1 : cw0;
    const float* cb = dir ? cb1 : cb0;
    int tid = threadIdx.x;

    for (int c = tid; c < CONVD; c += 256) {
        float acc = cb[c];
        #pragma unroll
        for (int t = 0; t < 4; t++) {
            int ls = l - 3 + t;
            if (ls >= 0) {
                acc += cw[t * CONVD + c] *
                       b2f(zx[(size_t)(id - l + ls) * DPROJ + 2048 + c]);
            }
        }
        float v = acc / (1.f + expf(-acc));   // SiLU
        if (c < DINNER) {
            xs[(size_t)id * DINNER + c] = f2b(v);
        } else if (c < DINNER + DSTATE) {
            Bq[(size_t)id * DSTATE + (c - DINNER)] = v;
        } else {
            Cq[(size_t)id * DSTATE + (c - DINNER - DSTATE)] = v;
        }
    }
    if (tid < NH) {
        const float* dtb = dir ? dtb1 : dtb0;
        const float* al  = dir ? al1 : al0;
        float raw = dtr[(size_t)id * NH + tid] + dtb[tid];
        float dt = raw > 20.f ? raw : log1pf(expf(raw));
        float dA = expf(-expf(al[tid]) * dt);
        int dirb = id >> 10;
        dtq[(size_t)(dirb * NH + tid) * SEQ + l] = dt;
        daq[(size_t)(dirb * NH + tid) * SEQ + l] = dA;
    }
}

// ---------------------------------------------------------------------------
// sequential SSM scan — register-pipelined chunks of 4 steps, double-buffered.
// grid: (128 = dir*64 + b*32 + h, 4 = p-split), 256 thr.
// thread: p = ps*16 + (tid>>4), owns n in [(tid&15)*4, +4). y via 16-lane shfl
// (batched 4-wide). y (+ D*x) stored bf16 into zx cols 2048.. .
// ---------------------------------------------------------------------------
struct BCBuf { float4 B[4], C[4]; float4 da, dt; };

DEV void fetch_bc(BCBuf& s, const float* Bp, const float* Cp,
                  const float* dap, const float* dtp, int c)
{
    int l0 = c * 4;
    #pragma unroll
    for (int j = 0; j < 4; j++) {
        s.B[j] = *(const float4*)(Bp + (size_t)(l0 + j) * DSTATE);
        s.C[j] = *(const float4*)(Cp + (size_t)(l0 + j) * DSTATE);
    }
    s.da = *(const float4*)(dap + l0);
    s.dt = *(const float4*)(dtp + l0);
}

DEV void fetch_x(float* xv, const ushort* xp, int c)
{
    int l0 = c * 4;
    #pragma unroll
    for (int j = 0; j < 4; j++)
        xv[j] = b2f(xp[(size_t)(l0 + j) * DINNER]);
}

DEV void chunk_comp(const BCBuf& s, const float* xv,
                    float& s0, float& s1, float& s2, float& s3,
                    float Dv, bool lead, ushort* yo)
{
    float part[4];
    const float da[4] = { s.da.x, s.da.y, s.da.z, s.da.w };
    const float dt[4] = { s.dt.x, s.dt.y, s.dt.z, s.dt.w };
    #pragma unroll
    for (int j = 0; j < 4; j++) {
        float cf = dt[j] * xv[j];
        s0 = fmaf(s0, da[j], cf * s.B[j].x);
        s1 = fmaf(s1, da[j], cf * s.B[j].y);
        s2 = fmaf(s2, da[j], cf * s.B[j].z);
        s3 = fmaf(s3, da[j], cf * s.B[j].w);
        part[j] = (s0 * s.C[j].x + s1 * s.C[j].y) + (s2 * s.C[j].z + s3 * s.C[j].w);
    }
    #pragma unroll
    for (int st = 1; st < 16; st <<= 1) {
        part[0] += __shfl_xor(part[0], st);
        part[1] += __shfl_xor(part[1], st);
        part[2] += __shfl_xor(part[2], st);
        part[3] += __shfl_xor(part[3], st);
    }
    if (lead) {
        #pragma unroll
        for (int j = 0; j < 4; j++)
            yo[(size_t)j * DPROJ] = f2b(part[j] + Dv * xv[j]);
    }
}

__global__ __launch_bounds__(256) void scan_k(
    const float* __restrict__ Bq, const float* __restrict__ Cq,
    const float* __restrict__ dtT, const float* __restrict__ daT,
    const ushort* __restrict__ xsq,
    const float* __restrict__ D0, const float* __restrict__ D1,
    ushort* __restrict__ yout)
{
    int id = blockIdx.x;                 // dir*64 + b*32 + h
    int dir = id >> 6, h = id & 31;
    int ps = blockIdx.y;
    int tid = threadIdx.x;
    int p  = ps * 16 + (tid >> 4);
    int nb = (tid & 15) * 4;
    bool lead = (tid & 15) == 0;
    float Dv = (dir ? D1 : D0)[h];
    int base = (id >> 5) << 10;          // dirb * 1024

    const float*  Bp  = Bq  + (size_t)base * DSTATE + nb;
    const float*  Cp  = Cq  + (size_t)base * DSTATE + nb;
    const float*  dap = daT + (size_t)id * SEQ;
    const float*  dtp = dtT + (size_t)id * SEQ;
    const ushort* xp  = xsq + (size_t)base * DINNER + h * HD + p;
    ushort*       yo  = yout + (size_t)base * DPROJ + 2048 + h * HD + p;

    BCBuf A, Bb;
    float xa[4], xb[4];
    fetch_bc(A,  Bp, Cp, dap, dtp, 0);
    fetch_x(xa, xp, 0);
    fetch_bc(Bb, Bp, Cp, dap, dtp, 1);
    fetch_x(xb, xp, 1);

    float s0 = 0.f, s1 = 0.f, s2 = 0.f, s3 = 0.f;
    for (int lc = 0; lc < 256; lc += 2) {
        chunk_comp(A, xa, s0, s1, s2, s3, Dv, lead, yo + (size_t)(lc * 4) * DPROJ);
        {
            int c = lc + 2 < 256 ? lc + 2 : 255;
            fetch_bc(A, Bp, Cp, dap, dtp, c);
            fetch_x(xa, xp, c);
        }
        chunk_comp(Bb, xb, s0, s1, s2, s3, Dv, lead, yo + (size_t)((lc + 1) * 4) * DPROJ);
        {
            int c = lc + 3 < 256 ? lc + 3 : 255;
            fetch_bc(Bb, Bp, Cp, dap, dtp, c);
            fetch_x(xb, xp, c);
        }
    }
}

// ---------------------------------------------------------------------------
// gated RMSNorm: g = y * silu(z); g * rsqrt(mean(g^2)+eps) * rms_w -> bf16
// ---------------------------------------------------------------------------
__global__ __launch_bounds__(256) void grms_k(
    const ushort* __restrict__ zx,
    const float* __restrict__ rw0, const float* __restrict__ rw1,
    ushort* __restrict__ yn)
{
    int id = blockIdx.x;
    int dir = id >> 11;
    const float* rw = dir ? rw1 : rw0;
    int tid = threadIdx.x;
    float g[8];
    float ss = 0.f;
    #pragma unroll
    for (int i = 0; i < 8; i++) {
        int c = i * 256 + tid;
        float z  = b2f(zx[(size_t)id * DPROJ + c]);
        float yv = b2f(zx[(size_t)id * DPROJ + 2048 + c]);
        float v = yv * (z / (1.f + expf(-z)));
        g[i] = v;
        ss += v * v;
    }
    for (int o = 32; o; o >>= 1) ss += __shfl_down(ss, o);
    __shared__ float t4[4];
    if ((tid & 63) == 0) t4[tid >> 6] = ss;
    __syncthreads();
    ss = t4[0] + t4[1] + t4[2] + t4[3];
    float sc = rsqrtf(ss * (1.f / DINNER) + 1e-5f);
    #pragma unroll
    for (int i = 0; i < 8; i++) {
        int c = i * 256 + tid;
        yn[(size_t)id * DINNER + c] = f2b(g[i] * sc * rw[c]);
    }
}

// ---------------------------------------------------------------------------
// LayerNorm over 1024 + affine -> fp32 out
// ---------------------------------------------------------------------------
__global__ __launch_bounds__(256) void ln_k(
    const float* __restrict__ h, const float* __restrict__ lw,
    const float* __restrict__ lb, float* __restrict__ out)
{
    int m = blockIdx.x;
    int tid = threadIdx.x;
    float v[4];
    float s = 0.f, s2 = 0.f;
    #pragma unroll
    for (int i = 0; i < 4; i++) {
        int c = i * 256 + tid;
        v[i] = h[(size_t)m * DMODEL + c];
        s += v[i];
        s2 += v[i] * v[i];
    }
    for (int o = 32; o; o >>= 1) { s += __shfl_down(s, o); s2 += __shfl_down(s2, o); }
    __shared__ float ts[4], ts2[4];
    if ((tid & 63) == 0) { ts[tid >> 6] = s; ts2[tid >> 6] = s2; }
    __syncthreads();
    s  = ts[0] + ts[1] + ts[2] + ts[3];
    s2 = ts2[0] + ts2[1] + ts2[2] + ts2[3];
    float mu  = s * (1.f / DMODEL);
    float var = s2 * (1.f / DMODEL) - mu * mu;
    float sc  = rsqrtf(var + 1e-5f);
    #pragma unroll
    for (int i = 0; i < 4; i++) {
        int c = i * 256 + tid;
        out[(size_t)m * DMODEL + c] = (v[i] - mu) * sc * lw[c] + lb[c];
    }
}

extern "C" void kernel_launch(void* const* d_in, const int* in_sizes, int n_in,
                              void* d_out, int out_size, void* d_ws, size_t ws_size,
                              hipStream_t stream)
{
    const float* x     = (const float*)d_in[0];
    const float* f_inw = (const float*)d_in[1];
    const float* f_cw  = (const float*)d_in[2];
    const float* f_cb  = (const float*)d_in[3];
    const float* f_dtb = (const float*)d_in[4];
    const float* f_al  = (const float*)d_in[5];
    const float* f_Dp  = (const float*)d_in[6];
    const float* f_rw  = (const float*)d_in[7];
    const float* f_ow  = (const float*)d_in[8];
    const float* b_inw = (const float*)d_in[9];
    const float* b_cw  = (const float*)d_in[10];
    const float* b_cb  = (const float*)d_in[11];
    const float* b_dtb = (const float*)d_in[12];
    const float* b_al  = (const float*)d_in[13];
    const float* b_Dp  = (const float*)d_in[14];
    const float* b_rw  = (const float*)d_in[15];
    const float* b_ow  = (const float*)d_in[16];
    const float* projw = (const float*)d_in[17];
    const float* projb = (const float*)d_in[18];
    const float* lnw   = (const float*)d_in[19];
    const float* lnb   = (const float*)d_in[20];

    char* ws = (char*)d_ws;
    ushort* zx  = (ushort*)(ws + OFF_ZX);
    ushort* xs  = (ushort*)(ws + OFF_XS);
    float*  Bq  = (float*)(ws + OFF_BB);
    float*  Cq  = (float*)(ws + OFF_CC);
    float*  dtq = (float*)(ws + OFF_DT);
    float*  daq = (float*)(ws + OFF_DA);
    float*  dtr = (float*)(ws + OFF_DR);
    ushort* yn  = (ushort*)(ws + OFF_XS);   // aliases xs (dead after scan)
    ushort* dou = (ushort*)(ws + OFF_DO);   // aliases zx (dead after grms)
    float*  hb  = (float*)(ws + OFF_H);     // aliases zx (dead after grms)

    // K1: in_proj (both dirs), N=4256, K=1024 (+ fp32 dt spill)
    gemm_k<0><<<dim3((DPROJ + 63) / 64, MROWS / 128, 2), 256, 0, stream>>>(
        (const void*)x, f_inw, b_inw, (void*)zx, nullptr, nullptr, dtr, DPROJ, DMODEL);

    // K2: conv + activations + dt/dA (dt/dA transposed)
    conv_k<<<dim3(2 * MROWS), 256, 0, stream>>>(
        zx, dtr, f_cw, f_cb, b_cw, b_cb, f_dtb, f_al, b_dtb, b_al,
        xs, Bq, Cq, dtq, daq);

    // K3: sequential scan (register-pipelined; writes y bf16 into zx cols 2048..)
    scan_k<<<dim3(128, 4), 256, 0, stream>>>(Bq, Cq, dtq, daq, xs, f_Dp, b_Dp, zx);

    // K4: gated RMSNorm
    grms_k<<<dim3(2 * MROWS), 256, 0, stream>>>(zx, f_rw, b_rw, yn);

    // K5: out_proj (both dirs), N=1024, K=2048
    gemm_k<1><<<dim3(DMODEL / 64, MROWS / 128, 2), 256, 0, stream>>>(
        (const void*)yn, f_ow, b_ow, (void*)dou, nullptr, nullptr, nullptr, DMODEL, DINNER);

    // K6: final proj + residual + bias, N=1024, K=2048 (fp32 out)
    gemm_k<2><<<dim3(DMODEL / 64, MROWS / 128, 1), 256, 0, stream>>>(
        (const void*)dou, projw, projw, (void*)hb, x, projb, nullptr, DMODEL, DINNER);

    // K7: LayerNorm -> fp32 out
    ln_k<<<dim3(MROWS), 256, 0, stream>>>(hb, lnw, lnb, (float*)d_out);
}

// Round 5
// 742.812 us; speedup vs baseline: 1.3971x; 1.3971x over previous
//
#include <hip/hip_runtime.h>
#include <hip/hip_bf16.h>

#define DEV __device__ __forceinline__

typedef short bf16x8 __attribute__((ext_vector_type(8)));
typedef float f32x4 __attribute__((ext_vector_type(4)));

static constexpr int BATCH  = 2;
static constexpr int SEQ    = 1024;
static constexpr int DMODEL = 1024;
static constexpr int DINNER = 2048;
static constexpr int DSTATE = 64;
static constexpr int NH     = 32;
static constexpr int HD     = 64;
static constexpr int CONVD  = 2176;
static constexpr int DPROJ  = 4256;
static constexpr int MROWS  = BATCH * SEQ;   // 2048
static constexpr int NCHUNK = 16;            // 16 chunks x 64 steps
static constexpr int QC     = 64;            // chunk length

// ---- workspace layout (bytes) ---- peak ~72.5 MB
static constexpr size_t OFF_ZX = 0;
static constexpr size_t OFF_XS = OFF_ZX + (size_t)2*MROWS*DPROJ*2;   // bf16 [4096][2048]; reused as yn
static constexpr size_t OFF_BB = OFF_XS + (size_t)2*MROWS*DINNER*2;  // f32 [4096][64]
static constexpr size_t OFF_CC = OFF_BB + (size_t)2*MROWS*DSTATE*4;  // f32 [4096][64]
static constexpr size_t OFF_DT = OFF_CC + (size_t)2*MROWS*DSTATE*4;  // f32 [4][32][1024] (transposed)
static constexpr size_t OFF_DA = OFF_DT + (size_t)2*MROWS*NH*4;      // f32 [4][32][1024] (transposed)
static constexpr size_t OFF_DR = OFF_DA + (size_t)2*MROWS*NH*4;      // f32 [4096][32] raw dt spill
static constexpr size_t OFF_CS = OFF_DR + (size_t)2*MROWS*NH*4;      // bf16 [128][16][64][64] chunk states
static constexpr size_t OFF_DO = 0;                                  // bf16 [4096][1024] (aliases zx)
static constexpr size_t OFF_H  = OFF_DO + (size_t)2*MROWS*DMODEL*2;  // f32  [2048][1024] (aliases zx)

DEV float b2f(ushort u) {
    union { unsigned int i; float f; } v;
    v.i = ((unsigned int)u) << 16;
    return v.f;
}
DEV ushort f2b(float f) {
    union { float f; unsigned int u; } v;
    v.f = f;
    unsigned int r = 0x7FFFu + ((v.u >> 16) & 1u);
    return (ushort)((v.u + r) >> 16);
}

// ---------------------------------------------------------------------------
// GEMM: C[m][n] = sum_k A[m][k] * W[n][k]   (W row-major (N,K), fp32 ->bf16)
// ---------------------------------------------------------------------------
template<int MODE>
__global__ __launch_bounds__(256) void gemm_k(
    const void* __restrict__ asrc_,
    const float* __restrict__ w0, const float* __restrict__ w1,
    void* __restrict__ outp,
    const float* __restrict__ resid, const float* __restrict__ bias,
    float* __restrict__ dtraw, int N, int K)
{
    constexpr int BM = 128, BN = 64, BK = 32;
    __shared__ ushort As[BM][BK + 8];
    __shared__ ushort Bs[BN][BK + 8];
    const int tid  = threadIdx.x;
    const int wave = tid >> 6, lane = tid & 63;
    const int bn = blockIdx.x * BN, bm = blockIdx.y * BM;
    const int dir = blockIdx.z;
    const float* w = dir ? w1 : w0;

    f32x4 acc[2][4] = {};

    for (int k0 = 0; k0 < K; k0 += BK) {
        if (MODE == 0) {
            const float* xf = (const float*)asrc_;
            #pragma unroll
            for (int pass = 0; pass < 4; pass++) {
                int idx = pass * 256 + tid;
                int row = idx >> 3, cg = (idx & 7) * 4;
                int m = bm + row, k = k0 + cg;
                int b = m >> 10, l = m & 1023;
                int ls = dir ? (1023 - l) : l;
                float4 f = *(const float4*)(xf + (size_t)(b * SEQ + ls) * DMODEL + k);
                ushort4 u;
                u.x = f2b(f.x); u.y = f2b(f.y); u.z = f2b(f.z); u.w = f2b(f.w);
                *(ushort4*)&As[row][cg] = u;
            }
        } else {
            const ushort* ab = (const ushort*)asrc_;
            #pragma unroll
            for (int pass = 0; pass < 2; pass++) {
                int idx = pass * 256 + tid;
                int row = idx >> 2, cg = (idx & 3) * 8;
                int m = bm + row, k = k0 + cg;
                const ushort* src;
                if (MODE == 1) {
                    src = ab + ((size_t)(dir * MROWS + m) * DINNER + k);
                } else {
                    if (k < DMODEL) {
                        src = ab + ((size_t)m * DMODEL + k);
                    } else {
                        int l = m & 1023;
                        int m2 = (m & ~1023) | (1023 - l);
                        src = ab + ((size_t)(MROWS + m2) * DMODEL + (k - DMODEL));
                    }
                }
                *(uint4*)&As[row][cg] = *(const uint4*)src;
            }
        }
        #pragma unroll
        for (int pass = 0; pass < 2; pass++) {
            int idx = pass * 256 + tid;
            int row = idx >> 3, cg = (idx & 7) * 4;
            int n = bn + row, k = k0 + cg;
            float4 f = {0.f, 0.f, 0.f, 0.f};
            if (n < N) f = *(const float4*)(w + (size_t)n * K + k);
            ushort4 u;
            u.x = f2b(f.x); u.y = f2b(f.y); u.z = f2b(f.z); u.w = f2b(f.w);
            *(ushort4*)&Bs[row][cg] = u;
        }
        __syncthreads();

        const int ar = wave * 32 + (lane & 15);
        const int ko = (lane >> 4) * 8;
        bf16x8 a0 = *(const bf16x8*)&As[ar][ko];
        bf16x8 a1 = *(const bf16x8*)&As[ar + 16][ko];
        #pragma unroll
        for (int ni = 0; ni < 4; ni++) {
            bf16x8 bfr = *(const bf16x8*)&Bs[ni * 16 + (lane & 15)][ko];
            acc[0][ni] = __builtin_amdgcn_mfma_f32_16x16x32_bf16(a0, bfr, acc[0][ni], 0, 0, 0);
            acc[1][ni] = __builtin_amdgcn_mfma_f32_16x16x32_bf16(a1, bfr, acc[1][ni], 0, 0, 0);
        }
        __syncthreads();
    }

    #pragma unroll
    for (int mi = 0; mi < 2; mi++) {
        #pragma unroll
        for (int ni = 0; ni < 4; ni++) {
            #pragma unroll
            for (int j = 0; j < 4; j++) {
                int row = bm + wave * 32 + mi * 16 + (lane >> 4) * 4 + j;
                int col = bn + ni * 16 + (lane & 15);
                if (col >= N) continue;
                float v = acc[mi][ni][j];
                if (MODE == 0) {
                    ((ushort*)outp)[(size_t)(dir * MROWS + row) * DPROJ + col] = f2b(v);
                    if (col >= 4224)
                        dtraw[(size_t)(dir * MROWS + row) * NH + (col - 4224)] = v;
                } else if (MODE == 1) {
                    ((ushort*)outp)[(size_t)(dir * MROWS + row) * DMODEL + col] = f2b(v);
                } else {
                    float r = resid[(size_t)row * DMODEL + col] + bias[col];
                    ((float*)outp)[(size_t)row * DMODEL + col] = v + r;
                }
            }
        }
    }
}

// ---------------------------------------------------------------------------
// causal depthwise conv(width 4) + bias + SiLU; dt = softplus(raw+bias); dA
// dt/dA written TRANSPOSED: [dirb*32+h][l]
// ---------------------------------------------------------------------------
__global__ __launch_bounds__(256) void conv_k(
    const ushort* __restrict__ zx, const float* __restrict__ dtr,
    const float* __restrict__ cw0, const float* __restrict__ cb0,
    const float* __restrict__ cw1, const float* __restrict__ cb1,
    const float* __restrict__ dtb0, const float* __restrict__ al0,
    const float* __restrict__ dtb1, const float* __restrict__ al1,
    ushort* __restrict__ xs, float* __restrict__ Bq, float* __restrict__ Cq,
    float* __restrict__ dtq, float* __restrict__ daq)
{
    int id = blockIdx.x;
    int dir = id >> 11;
    int m = id & 2047;
    int l = m & 1023;
    const float* cw = dir ? cw1 : cw0;
    const float* cb = dir ? cb1 : cb0;
    int tid = threadIdx.x;

    for (int c = tid; c < CONVD; c += 256) {
        float acc = cb[c];
        #pragma unroll
        for (int t = 0; t < 4; t++) {
            int ls = l - 3 + t;
            if (ls >= 0) {
                acc += cw[t * CONVD + c] *
                       b2f(zx[(size_t)(id - l + ls) * DPROJ + 2048 + c]);
            }
        }
        float v = acc / (1.f + expf(-acc));   // SiLU
        if (c < DINNER) {
            xs[(size_t)id * DINNER + c] = f2b(v);
        } else if (c < DINNER + DSTATE) {
            Bq[(size_t)id * DSTATE + (c - DINNER)] = v;
        } else {
            Cq[(size_t)id * DSTATE + (c - DINNER - DSTATE)] = v;
        }
    }
    if (tid < NH) {
        const float* dtb = dir ? dtb1 : dtb0;
        const float* al  = dir ? al1 : al0;
        float raw = dtr[(size_t)id * NH + tid] + dtb[tid];
        float dt = raw > 20.f ? raw : log1pf(expf(raw));
        float dA = expf(-expf(al[tid]) * dt);
        int dirb = id >> 10;
        dtq[(size_t)(dirb * NH + tid) * SEQ + l] = dt;
        daq[(size_t)(dirb * NH + tid) * SEQ + l] = dA;
    }
}

// ---------------------------------------------------------------------------
// Chunked scan, pass 1: per-chunk end state from zero init.
// grid (128 ids, 4 ps, 16 chunks), 256 thr. thread: p = ps*16+(tid>>4),
// n = (tid&15)*4..+4. Stores S_c bf16 to cs[id][c][p][n].
// ---------------------------------------------------------------------------
__global__ __launch_bounds__(256) void chunkstate_k(
    const float* __restrict__ Bq,
    const float* __restrict__ dtT, const float* __restrict__ daT,
    const ushort* __restrict__ xsq, ushort* __restrict__ cs)
{
    int id = blockIdx.x;                 // dirb*32 + h
    int h = id & 31;
    int ps = blockIdx.y, c = blockIdx.z;
    int tid = threadIdx.x;
    int p  = ps * 16 + (tid >> 4);
    int nb = (tid & 15) * 4;
    int base = (id >> 5) << 10;          // dirb * 1024

    const float*  Bp  = Bq  + (size_t)base * DSTATE + nb;
    const float*  dap = daT + (size_t)id * SEQ;
    const float*  dtp = dtT + (size_t)id * SEQ;
    const ushort* xp  = xsq + (size_t)base * DINNER + h * HD + p;
    int l0 = c * QC;

    float s0 = 0.f, s1 = 0.f, s2 = 0.f, s3 = 0.f;
    for (int j = 0; j < QC; j++) {
        int l = l0 + j;
        float dA = dap[l];
        float dt = dtp[l];
        float4 Bv = *(const float4*)(Bp + (size_t)l * DSTATE);
        float xv = b2f(xp[(size_t)l * DINNER]);
        float cf = dt * xv;
        s0 = fmaf(s0, dA, cf * Bv.x);
        s1 = fmaf(s1, dA, cf * Bv.y);
        s2 = fmaf(s2, dA, cf * Bv.z);
        s3 = fmaf(s3, dA, cf * Bv.w);
    }
    ushort4 u;
    u.x = f2b(s0); u.y = f2b(s1); u.z = f2b(s2); u.w = f2b(s3);
    *(ushort4*)&cs[(((size_t)id * NCHUNK + c) * HD + p) * DSTATE + nb] = u;
}

// ---------------------------------------------------------------------------
// Chunked scan, pass 2: stitch. 128 blocks. H_{c+1} = S_c + D_c * H_c,
// rewriting cs[id][c] in place with the chunk-START state H_c (H_0 = 0).
// thread owns p = tid>>2, n = (tid&3)*16..+16 (16 elems).
// ---------------------------------------------------------------------------
__global__ __launch_bounds__(256) void stitch_k(
    const float* __restrict__ daT, ushort* __restrict__ cs)
{
    int id = blockIdx.x;
    int tid = threadIdx.x;
    __shared__ float red[256];
    __shared__ float dec[NCHUNK];

    float4 d4 = *(const float4*)(daT + (size_t)id * SEQ + tid * 4);
    red[tid] = d4.x * d4.y * d4.z * d4.w;
    __syncthreads();
    if (tid < NCHUNK) {
        float d = 1.f;
        #pragma unroll
        for (int i = 0; i < 16; i++) d *= red[tid * 16 + i];
        dec[tid] = d;
    }
    __syncthreads();

    int p = tid >> 2, n0 = (tid & 3) * 16;
    ushort* ptr = cs + (size_t)id * NCHUNK * HD * DSTATE + p * DSTATE + n0;

    float st[16];
    #pragma unroll
    for (int i = 0; i < 16; i++) st[i] = 0.f;

    for (int c = 0; c < NCHUNK; c++) {
        ushort* row = ptr + (size_t)c * HD * DSTATE;
        float tmp[16];
        #pragma unroll
        for (int i = 0; i < 16; i++) tmp[i] = b2f(row[i]);
        #pragma unroll
        for (int i = 0; i < 16; i++) row[i] = f2b(st[i]);     // H_c
        float d = dec[c];
        #pragma unroll
        for (int i = 0; i < 16; i++) st[i] = fmaf(d, st[i], tmp[i]);
    }
}

// ---------------------------------------------------------------------------
// Chunked scan, pass 3: y for each chunk, seeded with H_c.
// grid (128 ids, 4 ps, 16 chunks), 256 thr; same thread layout as pass 1.
// y (+ D*x) stored bf16 into zx cols 2048.. .
// ---------------------------------------------------------------------------
__global__ __launch_bounds__(256) void scan_k(
    const float* __restrict__ Bq, const float* __restrict__ Cq,
    const float* __restrict__ dtT, const float* __restrict__ daT,
    const ushort* __restrict__ xsq, const ushort* __restrict__ cs,
    const float* __restrict__ D0, const float* __restrict__ D1,
    ushort* __restrict__ yout)
{
    int id = blockIdx.x;                 // dirb*32 + h
    int dir = id >> 6, h = id & 31;
    int ps = blockIdx.y, c = blockIdx.z;
    int tid = threadIdx.x;
    int p  = ps * 16 + (tid >> 4);
    int nb = (tid & 15) * 4;
    float Dv = (dir ? D1 : D0)[h];
    int base = (id >> 5) << 10;          // dirb * 1024

    const float*  Bp  = Bq  + (size_t)base * DSTATE + nb;
    const float*  Cp  = Cq  + (size_t)base * DSTATE + nb;
    const float*  dap = daT + (size_t)id * SEQ;
    const float*  dtp = dtT + (size_t)id * SEQ;
    const ushort* xp  = xsq + (size_t)base * DINNER + h * HD + p;
    ushort*       yo  = yout + (size_t)base * DPROJ + 2048 + h * HD + p;

    ushort4 hu = *(const ushort4*)&cs[(((size_t)id * NCHUNK + c) * HD + p) * DSTATE + nb];
    float s0 = b2f(hu.x), s1 = b2f(hu.y), s2 = b2f(hu.z), s3 = b2f(hu.w);

    int l0 = c * QC;
    for (int j = 0; j < QC; j++) {
        int l = l0 + j;
        float dA = dap[l];
        float dt = dtp[l];
        float4 Bv = *(const float4*)(Bp + (size_t)l * DSTATE);
        float4 Cv = *(const float4*)(Cp + (size_t)l * DSTATE);
        float xv = b2f(xp[(size_t)l * DINNER]);
        float cf = dt * xv;
        s0 = fmaf(s0, dA, cf * Bv.x);
        s1 = fmaf(s1, dA, cf * Bv.y);
        s2 = fmaf(s2, dA, cf * Bv.z);
        s3 = fmaf(s3, dA, cf * Bv.w);
        float part = (s0 * Cv.x + s1 * Cv.y) + (s2 * Cv.z + s3 * Cv.w);
        part += __shfl_xor(part, 1);
        part += __shfl_xor(part, 2);
        part += __shfl_xor(part, 4);
        part += __shfl_xor(part, 8);
        if ((tid & 15) == 0)
            yo[(size_t)l * DPROJ] = f2b(part + Dv * xv);
    }
}

// ---------------------------------------------------------------------------
// gated RMSNorm: g = y * silu(z); g * rsqrt(mean(g^2)+eps) * rms_w -> bf16
// ---------------------------------------------------------------------------
__global__ __launch_bounds__(256) void grms_k(
    const ushort* __restrict__ zx,
    const float* __restrict__ rw0, const float* __restrict__ rw1,
    ushort* __restrict__ yn)
{
    int id = blockIdx.x;
    int dir = id >> 11;
    const float* rw = dir ? rw1 : rw0;
    int tid = threadIdx.x;
    float g[8];
    float ss = 0.f;
    #pragma unroll
    for (int i = 0; i < 8; i++) {
        int c = i * 256 + tid;
        float z  = b2f(zx[(size_t)id * DPROJ + c]);
        float yv = b2f(zx[(size_t)id * DPROJ + 2048 + c]);
        float v = yv * (z / (1.f + expf(-z)));
        g[i] = v;
        ss += v * v;
    }
    for (int o = 32; o; o >>= 1) ss += __shfl_down(ss, o);
    __shared__ float t4[4];
    if ((tid & 63) == 0) t4[tid >> 6] = ss;
    __syncthreads();
    ss = t4[0] + t4[1] + t4[2] + t4[3];
    float sc = rsqrtf(ss * (1.f / DINNER) + 1e-5f);
    #pragma unroll
    for (int i = 0; i < 8; i++) {
        int c = i * 256 + tid;
        yn[(size_t)id * DINNER + c] = f2b(g[i] * sc * rw[c]);
    }
}

// ---------------------------------------------------------------------------
// LayerNorm over 1024 + affine -> fp32 out
// ---------------------------------------------------------------------------
__global__ __launch_bounds__(256) void ln_k(
    const float* __restrict__ h, const float* __restrict__ lw,
    const float* __restrict__ lb, float* __restrict__ out)
{
    int m = blockIdx.x;
    int tid = threadIdx.x;
    float v[4];
    float s = 0.f, s2 = 0.f;
    #pragma unroll
    for (int i = 0; i < 4; i++) {
        int c = i * 256 + tid;
        v[i] = h[(size_t)m * DMODEL + c];
        s += v[i];
        s2 += v[i] * v[i];
    }
    for (int o = 32; o; o >>= 1) { s += __shfl_down(s, o); s2 += __shfl_down(s2, o); }
    __shared__ float ts[4], ts2[4];
    if ((tid & 63) == 0) { ts[tid >> 6] = s; ts2[tid >> 6] = s2; }
    __syncthreads();
    s  = ts[0] + ts[1] + ts[2] + ts[3];
    s2 = ts2[0] + ts2[1] + ts2[2] + ts2[3];
    float mu  = s * (1.f / DMODEL);
    float var = s2 * (1.f / DMODEL) - mu * mu;
    float sc  = rsqrtf(var + 1e-5f);
    #pragma unroll
    for (int i = 0; i < 4; i++) {
        int c = i * 256 + tid;
        out[(size_t)m * DMODEL + c] = (v[i] - mu) * sc * lw[c] + lb[c];
    }
}

extern "C" void kernel_launch(void* const* d_in, const int* in_sizes, int n_in,
                              void* d_out, int out_size, void* d_ws, size_t ws_size,
                              hipStream_t stream)
{
    const float* x     = (const float*)d_in[0];
    const float* f_inw = (const float*)d_in[1];
    const float* f_cw  = (const float*)d_in[2];
    const float* f_cb  = (const float*)d_in[3];
    const float* f_dtb = (const float*)d_in[4];
    const float* f_al  = (const float*)d_in[5];
    const float* f_Dp  = (const float*)d_in[6];
    const float* f_rw  = (const float*)d_in[7];
    const float* f_ow  = (const float*)d_in[8];
    const float* b_inw = (const float*)d_in[9];
    const float* b_cw  = (const float*)d_in[10];
    const float* b_cb  = (const float*)d_in[11];
    const float* b_dtb = (const float*)d_in[12];
    const float* b_al  = (const float*)d_in[13];
    const float* b_Dp  = (const float*)d_in[14];
    const float* b_rw  = (const float*)d_in[15];
    const float* b_ow  = (const float*)d_in[16];
    const float* projw = (const float*)d_in[17];
    const float* projb = (const float*)d_in[18];
    const float* lnw   = (const float*)d_in[19];
    const float* lnb   = (const float*)d_in[20];

    char* ws = (char*)d_ws;
    ushort* zx  = (ushort*)(ws + OFF_ZX);
    ushort* xs  = (ushort*)(ws + OFF_XS);
    float*  Bq  = (float*)(ws + OFF_BB);
    float*  Cq  = (float*)(ws + OFF_CC);
    float*  dtq = (float*)(ws + OFF_DT);
    float*  daq = (float*)(ws + OFF_DA);
    float*  dtr = (float*)(ws + OFF_DR);
    ushort* cs  = (ushort*)(ws + OFF_CS);
    ushort* yn  = (ushort*)(ws + OFF_XS);   // aliases xs (dead after scan)
    ushort* dou = (ushort*)(ws + OFF_DO);   // aliases zx (dead after grms)
    float*  hb  = (float*)(ws + OFF_H);     // aliases zx (dead after grms)

    // K1: in_proj (both dirs), N=4256, K=1024 (+ fp32 dt spill)
    gemm_k<0><<<dim3((DPROJ + 63) / 64, MROWS / 128, 2), 256, 0, stream>>>(
        (const void*)x, f_inw, b_inw, (void*)zx, nullptr, nullptr, dtr, DPROJ, DMODEL);

    // K2: conv + activations + dt/dA (dt/dA transposed)
    conv_k<<<dim3(2 * MROWS), 256, 0, stream>>>(
        zx, dtr, f_cw, f_cb, b_cw, b_cb, f_dtb, f_al, b_dtb, b_al,
        xs, Bq, Cq, dtq, daq);

    // K3a: chunk-local end states
    chunkstate_k<<<dim3(128, 4, NCHUNK), 256, 0, stream>>>(Bq, dtq, daq, xs, cs);

    // K3b: stitch chunk states -> chunk-start states (in place)
    stitch_k<<<dim3(128), 256, 0, stream>>>(daq, cs);

    // K3c: per-chunk scan with seeded state; writes y bf16 into zx cols 2048..
    scan_k<<<dim3(128, 4, NCHUNK), 256, 0, stream>>>(
        Bq, Cq, dtq, daq, xs, cs, f_Dp, b_Dp, zx);

    // K4: gated RMSNorm
    grms_k<<<dim3(2 * MROWS), 256, 0, stream>>>(zx, f_rw, b_rw, yn);

    // K5: out_proj (both dirs), N=1024, K=2048
    gemm_k<1><<<dim3(DMODEL / 64, MROWS / 128, 2), 256, 0, stream>>>(
        (const void*)yn, f_ow, b_ow, (void*)dou, nullptr, nullptr, nullptr, DMODEL, DINNER);

    // K6: final proj + residual + bias, N=1024, K=2048 (fp32 out)
    gemm_k<2><<<dim3(DMODEL / 64, MROWS / 128, 1), 256, 0, stream>>>(
        (const void*)dou, projw, projw, (void*)hb, x, projb, nullptr, DMODEL, DINNER);

    // K7: LayerNorm -> fp32 out
    ln_k<<<dim3(MROWS), 256, 0, stream>>>(hb, lnw, lnb, (float*)d_out);
}

// Round 6
// 667.299 us; speedup vs baseline: 1.5552x; 1.1132x over previous
//
#include <hip/hip_runtime.h>
#include <hip/hip_bf16.h>

#define DEV __device__ __forceinline__

typedef short bf16x8 __attribute__((ext_vector_type(8)));
typedef float f32x4 __attribute__((ext_vector_type(4)));

static constexpr int BATCH  = 2;
static constexpr int SEQ    = 1024;
static constexpr int DMODEL = 1024;
static constexpr int DINNER = 2048;
static constexpr int DSTATE = 64;
static constexpr int NH     = 32;
static constexpr int HD     = 64;
static constexpr int CONVD  = 2176;
static constexpr int DPROJ  = 4256;
static constexpr int MROWS  = BATCH * SEQ;   // 2048
static constexpr int NCHUNK = 16;            // 16 chunks x 64 steps
static constexpr int QC     = 64;            // chunk length

// ---- workspace layout (bytes) ---- peak ~72.8 MB
static constexpr size_t OFF_ZX = 0;
static constexpr size_t OFF_XS = OFF_ZX + (size_t)2*MROWS*DPROJ*2;   // bf16 [4096][2048]; reused as yn
static constexpr size_t OFF_BB = OFF_XS + (size_t)2*MROWS*DINNER*2;  // f32 [4096][64]
static constexpr size_t OFF_CC = OFF_BB + (size_t)2*MROWS*DSTATE*4;  // f32 [4096][64]
static constexpr size_t OFF_DT = OFF_CC + (size_t)2*MROWS*DSTATE*4;  // f32 [4][32][1024] (transposed)
static constexpr size_t OFF_DA = OFF_DT + (size_t)2*MROWS*NH*4;      // f32 [4][32][1024] (transposed)
static constexpr size_t OFF_DR = OFF_DA + (size_t)2*MROWS*NH*4;      // f32 [4096][32] raw dt spill
// CS region, time-shared: (a) bf16 in_proj weights [2][4256][1024] before scan
//                         (b) bf16 chunk states [128][16][64][64] after
static constexpr size_t OFF_CS = OFF_DR + (size_t)2*MROWS*NH*4;
static constexpr size_t OFF_DO = 0;                                  // bf16 [4096][1024] (aliases zx)
static constexpr size_t OFF_H  = OFF_DO + (size_t)2*MROWS*DMODEL*2;  // f32  [2048][1024] (aliases zx)

DEV float b2f(ushort u) {
    union { unsigned int i; float f; } v;
    v.i = ((unsigned int)u) << 16;
    return v.f;
}
DEV ushort f2b(float f) {
    union { float f; unsigned int u; } v;
    v.f = f;
    unsigned int r = 0x7FFFu + ((v.u >> 16) & 1u);
    return (ushort)((v.u + r) >> 16);
}

// ---------------------------------------------------------------------------
// wconv: fp32 in_proj weights -> bf16, [2][4256][1024]. grid (4256, 2).
// ---------------------------------------------------------------------------
__global__ __launch_bounds__(256) void wconv_k(
    const float* __restrict__ w0, const float* __restrict__ w1,
    ushort* __restrict__ out)
{
    int row = blockIdx.x, dir = blockIdx.y;
    const float* src = (dir ? w1 : w0) + (size_t)row * DMODEL;
    ushort* dst = out + ((size_t)dir * DPROJ + row) * DMODEL;
    int tid = threadIdx.x;
    float4 f = *(const float4*)(src + tid * 4);
    ushort4 u;
    u.x = f2b(f.x); u.y = f2b(f.y); u.z = f2b(f.z); u.w = f2b(f.w);
    *(ushort4*)(dst + tid * 4) = u;
}

// ---------------------------------------------------------------------------
// GEMM: C[m][n] = sum_k A[m][k] * W[n][k]
// MODE 0: A = x (fp32, per-dir flip), W bf16 pre-converted; out bf16 +dt spill
// MODE 1: A = ynorm[dir] (bf16), W fp32;   out bf16
// MODE 2: A = concat(dou0, flip(dou1)) (bf16), W fp32; out fp32 +resid +bias
// ---------------------------------------------------------------------------
template<int MODE>
__global__ __launch_bounds__(256) void gemm_k(
    const void* __restrict__ asrc_,
    const void* __restrict__ w0, const void* __restrict__ w1,
    void* __restrict__ outp,
    const float* __restrict__ resid, const float* __restrict__ bias,
    float* __restrict__ dtraw, int N, int K)
{
    constexpr int BM = 128, BN = 64, BK = 32;
    __shared__ ushort As[BM][BK + 8];
    __shared__ ushort Bs[BN][BK + 8];
    const int tid  = threadIdx.x;
    const int wave = tid >> 6, lane = tid & 63;
    const int bn = blockIdx.x * BN, bm = blockIdx.y * BM;
    const int dir = blockIdx.z;

    f32x4 acc[2][4] = {};

    for (int k0 = 0; k0 < K; k0 += BK) {
        if (MODE == 0) {
            const float* xf = (const float*)asrc_;
            #pragma unroll
            for (int pass = 0; pass < 4; pass++) {
                int idx = pass * 256 + tid;
                int row = idx >> 3, cg = (idx & 7) * 4;
                int m = bm + row, k = k0 + cg;
                int b = m >> 10, l = m & 1023;
                int ls = dir ? (1023 - l) : l;
                float4 f = *(const float4*)(xf + (size_t)(b * SEQ + ls) * DMODEL + k);
                ushort4 u;
                u.x = f2b(f.x); u.y = f2b(f.y); u.z = f2b(f.z); u.w = f2b(f.w);
                *(ushort4*)&As[row][cg] = u;
            }
        } else {
            const ushort* ab = (const ushort*)asrc_;
            #pragma unroll
            for (int pass = 0; pass < 2; pass++) {
                int idx = pass * 256 + tid;
                int row = idx >> 2, cg = (idx & 3) * 8;
                int m = bm + row, k = k0 + cg;
                const ushort* src;
                if (MODE == 1) {
                    src = ab + ((size_t)(dir * MROWS + m) * DINNER + k);
                } else {
                    if (k < DMODEL) {
                        src = ab + ((size_t)m * DMODEL + k);
                    } else {
                        int l = m & 1023;
                        int m2 = (m & ~1023) | (1023 - l);
                        src = ab + ((size_t)(MROWS + m2) * DMODEL + (k - DMODEL));
                    }
                }
                *(uint4*)&As[row][cg] = *(const uint4*)src;
            }
        }
        if (MODE == 0) {
            // bf16 weight stage: one pass, 64 rows x 32 cols
            const ushort* wb = (const ushort*)(dir ? w1 : w0);
            int row = tid >> 2, cg = (tid & 3) * 8;
            int n = bn + row, k = k0 + cg;
            uint4 v = {0u, 0u, 0u, 0u};
            if (n < N) v = *(const uint4*)(wb + (size_t)n * K + k);
            *(uint4*)&Bs[row][cg] = v;
        } else {
            const float* w = (const float*)(dir ? w1 : w0);
            #pragma unroll
            for (int pass = 0; pass < 2; pass++) {
                int idx = pass * 256 + tid;
                int row = idx >> 3, cg = (idx & 7) * 4;
                int n = bn + row, k = k0 + cg;
                float4 f = {0.f, 0.f, 0.f, 0.f};
                if (n < N) f = *(const float4*)(w + (size_t)n * K + k);
                ushort4 u;
                u.x = f2b(f.x); u.y = f2b(f.y); u.z = f2b(f.z); u.w = f2b(f.w);
                *(ushort4*)&Bs[row][cg] = u;
            }
        }
        __syncthreads();

        const int ar = wave * 32 + (lane & 15);
        const int ko = (lane >> 4) * 8;
        bf16x8 a0 = *(const bf16x8*)&As[ar][ko];
        bf16x8 a1 = *(const bf16x8*)&As[ar + 16][ko];
        #pragma unroll
        for (int ni = 0; ni < 4; ni++) {
            bf16x8 bfr = *(const bf16x8*)&Bs[ni * 16 + (lane & 15)][ko];
            acc[0][ni] = __builtin_amdgcn_mfma_f32_16x16x32_bf16(a0, bfr, acc[0][ni], 0, 0, 0);
            acc[1][ni] = __builtin_amdgcn_mfma_f32_16x16x32_bf16(a1, bfr, acc[1][ni], 0, 0, 0);
        }
        __syncthreads();
    }

    #pragma unroll
    for (int mi = 0; mi < 2; mi++) {
        #pragma unroll
        for (int ni = 0; ni < 4; ni++) {
            #pragma unroll
            for (int j = 0; j < 4; j++) {
                int row = bm + wave * 32 + mi * 16 + (lane >> 4) * 4 + j;
                int col = bn + ni * 16 + (lane & 15);
                if (col >= N) continue;
                float v = acc[mi][ni][j];
                if (MODE == 0) {
                    ((ushort*)outp)[(size_t)(dir * MROWS + row) * DPROJ + col] = f2b(v);
                    if (col >= 4224)
                        dtraw[(size_t)(dir * MROWS + row) * NH + (col - 4224)] = v;
                } else if (MODE == 1) {
                    ((ushort*)outp)[(size_t)(dir * MROWS + row) * DMODEL + col] = f2b(v);
                } else {
                    float r = resid[(size_t)row * DMODEL + col] + bias[col];
                    ((float*)outp)[(size_t)row * DMODEL + col] = v + r;
                }
            }
        }
    }
}

// ---------------------------------------------------------------------------
// causal depthwise conv(width 4) + bias + SiLU; dt = softplus(raw+bias); dA
// dt/dA written TRANSPOSED: [dirb*32+h][l]
// ---------------------------------------------------------------------------
__global__ __launch_bounds__(256) void conv_k(
    const ushort* __restrict__ zx, const float* __restrict__ dtr,
    const float* __restrict__ cw0, const float* __restrict__ cb0,
    const float* __restrict__ cw1, const float* __restrict__ cb1,
    const float* __restrict__ dtb0, const float* __restrict__ al0,
    const float* __restrict__ dtb1, const float* __restrict__ al1,
    ushort* __restrict__ xs, float* __restrict__ Bq, float* __restrict__ Cq,
    float* __restrict__ dtq, float* __restrict__ daq)
{
    int id = blockIdx.x;
    int dir = id >> 11;
    int m = id & 2047;
    int l = m & 1023;
    const float* cw = dir ? cw1 : cw0;
    const float* cb = dir ? cb1 : cb0;
    int tid = threadIdx.x;

    for (int c = tid; c < CONVD; c += 256) {
        float acc = cb[c];
        #pragma unroll
        for (int t = 0; t < 4; t++) {
            int ls = l - 3 + t;
            if (ls >= 0) {
                acc += cw[t * CONVD + c] *
                       b2f(zx[(size_t)(id - l + ls) * DPROJ + 2048 + c]);
            }
        }
        float v = acc / (1.f + expf(-acc));   // SiLU
        if (c < DINNER) {
            xs[(size_t)id * DINNER + c] = f2b(v);
        } else if (c < DINNER + DSTATE) {
            Bq[(size_t)id * DSTATE + (c - DINNER)] = v;
        } else {
            Cq[(size_t)id * DSTATE + (c - DINNER - DSTATE)] = v;
        }
    }
    if (tid < NH) {
        const float* dtb = dir ? dtb1 : dtb0;
        const float* al  = dir ? al1 : al0;
        float raw = dtr[(size_t)id * NH + tid] + dtb[tid];
        float dt = raw > 20.f ? raw : log1pf(expf(raw));
        float dA = expf(-expf(al[tid]) * dt);
        int dirb = id >> 10;
        dtq[(size_t)(dirb * NH + tid) * SEQ + l] = dt;
        daq[(size_t)(dirb * NH + tid) * SEQ + l] = dA;
    }
}

// ---------------------------------------------------------------------------
// Chunked scan (single data pass): per-chunk from ZERO state -> writes
// y_local (+D*x) bf16 into zx cols 2048.., and chunk end-state S_c to cs.
// grid (128 ids, 4 ps, 16 chunks), 256 thr. thread: p = ps*16+(tid>>4),
// n = (tid&15)*4..+4. Shuffle reductions batched 4-wide.
// ---------------------------------------------------------------------------
__global__ __launch_bounds__(256) void scan_k(
    const float* __restrict__ Bq, const float* __restrict__ Cq,
    const float* __restrict__ dtT, const float* __restrict__ daT,
    const ushort* __restrict__ xsq,
    const float* __restrict__ D0, const float* __restrict__ D1,
    ushort* __restrict__ yout, ushort* __restrict__ cs)
{
    int id = blockIdx.x;                 // dirb*32 + h
    int dir = id >> 6, h = id & 31;
    int ps = blockIdx.y, c = blockIdx.z;
    int tid = threadIdx.x;
    int p  = ps * 16 + (tid >> 4);
    int nb = (tid & 15) * 4;
    bool lead = (tid & 15) == 0;
    float Dv = (dir ? D1 : D0)[h];
    int base = (id >> 5) << 10;          // dirb * 1024

    const float*  Bp  = Bq  + (size_t)base * DSTATE + nb;
    const float*  Cp  = Cq  + (size_t)base * DSTATE + nb;
    const float*  dap = daT + (size_t)id * SEQ;
    const float*  dtp = dtT + (size_t)id * SEQ;
    const ushort* xp  = xsq + (size_t)base * DINNER + h * HD + p;
    ushort*       yo  = yout + (size_t)base * DPROJ + 2048 + h * HD + p;
    int l0 = c * QC;

    float s0 = 0.f, s1 = 0.f, s2 = 0.f, s3 = 0.f;
    for (int jo = 0; jo < QC / 4; jo++) {
        int l = l0 + jo * 4;
        float4 da4 = *(const float4*)(dap + l);
        float4 dt4 = *(const float4*)(dtp + l);
        float da[4] = { da4.x, da4.y, da4.z, da4.w };
        float dt[4] = { dt4.x, dt4.y, dt4.z, dt4.w };
        float part[4], xv4[4];
        #pragma unroll
        for (int j = 0; j < 4; j++) {
            float4 Bv = *(const float4*)(Bp + (size_t)(l + j) * DSTATE);
            float4 Cv = *(const float4*)(Cp + (size_t)(l + j) * DSTATE);
            float xv = b2f(xp[(size_t)(l + j) * DINNER]);
            float cf = dt[j] * xv;
            s0 = fmaf(s0, da[j], cf * Bv.x);
            s1 = fmaf(s1, da[j], cf * Bv.y);
            s2 = fmaf(s2, da[j], cf * Bv.z);
            s3 = fmaf(s3, da[j], cf * Bv.w);
            part[j] = (s0 * Cv.x + s1 * Cv.y) + (s2 * Cv.z + s3 * Cv.w);
            xv4[j] = xv;
        }
        #pragma unroll
        for (int st = 1; st < 16; st <<= 1) {
            part[0] += __shfl_xor(part[0], st);
            part[1] += __shfl_xor(part[1], st);
            part[2] += __shfl_xor(part[2], st);
            part[3] += __shfl_xor(part[3], st);
        }
        if (lead) {
            #pragma unroll
            for (int j = 0; j < 4; j++)
                yo[(size_t)(l + j) * DPROJ] = f2b(part[j] + Dv * xv4[j]);
        }
    }
    ushort4 u;
    u.x = f2b(s0); u.y = f2b(s1); u.z = f2b(s2); u.w = f2b(s3);
    *(ushort4*)&cs[(((size_t)id * NCHUNK + c) * HD + p) * DSTATE + nb] = u;
}

// ---------------------------------------------------------------------------
// Stitch: H_{c+1} = S_c + D_c * H_c, rewriting cs[id][c] in place with the
// chunk-START state H_c (H_0 = 0). 128 blocks.
// ---------------------------------------------------------------------------
__global__ __launch_bounds__(256) void stitch_k(
    const float* __restrict__ daT, ushort* __restrict__ cs)
{
    int id = blockIdx.x;
    int tid = threadIdx.x;
    __shared__ float red[256];
    __shared__ float dec[NCHUNK];

    float4 d4 = *(const float4*)(daT + (size_t)id * SEQ + tid * 4);
    red[tid] = d4.x * d4.y * d4.z * d4.w;
    __syncthreads();
    if (tid < NCHUNK) {
        float d = 1.f;
        #pragma unroll
        for (int i = 0; i < 16; i++) d *= red[tid * 16 + i];
        dec[tid] = d;
    }
    __syncthreads();

    int p = tid >> 2, n0 = (tid & 3) * 16;
    ushort* ptr = cs + (size_t)id * NCHUNK * HD * DSTATE + p * DSTATE + n0;

    float st[16];
    #pragma unroll
    for (int i = 0; i < 16; i++) st[i] = 0.f;

    for (int c = 0; c < NCHUNK; c++) {
        ushort* row = ptr + (size_t)c * HD * DSTATE;
        float tmp[16];
        #pragma unroll
        for (int i = 0; i < 16; i++) tmp[i] = b2f(row[i]);
        #pragma unroll
        for (int i = 0; i < 16; i++) row[i] = f2b(st[i]);     // H_c
        float d = dec[c];
        #pragma unroll
        for (int i = 0; i < 16; i++) st[i] = fmaf(d, st[i], tmp[i]);
    }
}

// ---------------------------------------------------------------------------
// Seed correction via MFMA: y[l,p] += cum[l] * sum_n C[l,n] * H_c[p,n].
// grid (128 ids, 16 chunks), 256 thr (4 waves, wave w owns l-rows w*16..+16).
// cum[l] = prod_{i<=l within chunk} dA_i  (inclusive), shfl_up scan.
// ---------------------------------------------------------------------------
__global__ __launch_bounds__(256) void corr_k(
    const float* __restrict__ Cq, const float* __restrict__ daT,
    const ushort* __restrict__ cs, ushort* __restrict__ yout)
{
    int id = blockIdx.x;                 // dirb*32 + h
    int h = id & 31;
    int c = blockIdx.y;
    int tid = threadIdx.x;
    int wave = tid >> 6, lane = tid & 63;
    int base = (id >> 5) << 10;
    int l0 = c * QC;

    __shared__ float cum[QC];
    if (tid < 64) {
        float d = daT[(size_t)id * SEQ + l0 + tid];
        #pragma unroll
        for (int st = 1; st < 64; st <<= 1) {
            float o = __shfl_up(d, st);
            if (tid >= st) d *= o;
        }
        cum[tid] = d;
    }
    __syncthreads();

    const ushort* Hrow = cs + ((size_t)id * NCHUNK + c) * HD * DSTATE;
    f32x4 acc[4] = {};
    #pragma unroll
    for (int kt = 0; kt < 2; kt++) {
        int k = kt * 32 + (lane >> 4) * 8;
        // A-frag: C[l][k..k+8) fp32 -> bf16
        int l = wave * 16 + (lane & 15);
        const float* cp = Cq + (size_t)(base + l0 + l) * DSTATE + k;
        float4 c0 = *(const float4*)cp;
        float4 c1 = *(const float4*)(cp + 4);
        bf16x8 af;
        af[0] = (short)f2b(c0.x); af[1] = (short)f2b(c0.y);
        af[2] = (short)f2b(c0.z); af[3] = (short)f2b(c0.w);
        af[4] = (short)f2b(c1.x); af[5] = (short)f2b(c1.y);
        af[6] = (short)f2b(c1.z); af[7] = (short)f2b(c1.w);
        #pragma unroll
        for (int ni = 0; ni < 4; ni++) {
            int p = ni * 16 + (lane & 15);
            bf16x8 bf = *(const bf16x8*)(Hrow + (size_t)p * DSTATE + k);
            acc[ni] = __builtin_amdgcn_mfma_f32_16x16x32_bf16(af, bf, acc[ni], 0, 0, 0);
        }
    }

    #pragma unroll
    for (int ni = 0; ni < 4; ni++) {
        #pragma unroll
        for (int j = 0; j < 4; j++) {
            int l = wave * 16 + (lane >> 4) * 4 + j;
            int p = ni * 16 + (lane & 15);
            ushort* yp = yout + (size_t)(base + l0 + l) * DPROJ + 2048 + h * HD + p;
            float v = b2f(*yp) + acc[ni][j] * cum[l];
            *yp = f2b(v);
        }
    }
}

// ---------------------------------------------------------------------------
// gated RMSNorm: g = y * silu(z); g * rsqrt(mean(g^2)+eps) * rms_w -> bf16
// ---------------------------------------------------------------------------
__global__ __launch_bounds__(256) void grms_k(
    const ushort* __restrict__ zx,
    const float* __restrict__ rw0, const float* __restrict__ rw1,
    ushort* __restrict__ yn)
{
    int id = blockIdx.x;
    int dir = id >> 11;
    const float* rw = dir ? rw1 : rw0;
    int tid = threadIdx.x;
    float g[8];
    float ss = 0.f;
    #pragma unroll
    for (int i = 0; i < 8; i++) {
        int c = i * 256 + tid;
        float z  = b2f(zx[(size_t)id * DPROJ + c]);
        float yv = b2f(zx[(size_t)id * DPROJ + 2048 + c]);
        float v = yv * (z / (1.f + expf(-z)));
        g[i] = v;
        ss += v * v;
    }
    for (int o = 32; o; o >>= 1) ss += __shfl_down(ss, o);
    __shared__ float t4[4];
    if ((tid & 63) == 0) t4[tid >> 6] = ss;
    __syncthreads();
    ss = t4[0] + t4[1] + t4[2] + t4[3];
    float sc = rsqrtf(ss * (1.f / DINNER) + 1e-5f);
    #pragma unroll
    for (int i = 0; i < 8; i++) {
        int c = i * 256 + tid;
        yn[(size_t)id * DINNER + c] = f2b(g[i] * sc * rw[c]);
    }
}

// ---------------------------------------------------------------------------
// LayerNorm over 1024 + affine -> fp32 out
// ---------------------------------------------------------------------------
__global__ __launch_bounds__(256) void ln_k(
    const float* __restrict__ h, const float* __restrict__ lw,
    const float* __restrict__ lb, float* __restrict__ out)
{
    int m = blockIdx.x;
    int tid = threadIdx.x;
    float v[4];
    float s = 0.f, s2 = 0.f;
    #pragma unroll
    for (int i = 0; i < 4; i++) {
        int c = i * 256 + tid;
        v[i] = h[(size_t)m * DMODEL + c];
        s += v[i];
        s2 += v[i] * v[i];
    }
    for (int o = 32; o; o >>= 1) { s += __shfl_down(s, o); s2 += __shfl_down(s2, o); }
    __shared__ float ts[4], ts2[4];
    if ((tid & 63) == 0) { ts[tid >> 6] = s; ts2[tid >> 6] = s2; }
    __syncthreads();
    s  = ts[0] + ts[1] + ts[2] + ts[3];
    s2 = ts2[0] + ts2[1] + ts2[2] + ts2[3];
    float mu  = s * (1.f / DMODEL);
    float var = s2 * (1.f / DMODEL) - mu * mu;
    float sc  = rsqrtf(var + 1e-5f);
    #pragma unroll
    for (int i = 0; i < 4; i++) {
        int c = i * 256 + tid;
        out[(size_t)m * DMODEL + c] = (v[i] - mu) * sc * lw[c] + lb[c];
    }
}

extern "C" void kernel_launch(void* const* d_in, const int* in_sizes, int n_in,
                              void* d_out, int out_size, void* d_ws, size_t ws_size,
                              hipStream_t stream)
{
    const float* x     = (const float*)d_in[0];
    const float* f_inw = (const float*)d_in[1];
    const float* f_cw  = (const float*)d_in[2];
    const float* f_cb  = (const float*)d_in[3];
    const float* f_dtb = (const float*)d_in[4];
    const float* f_al  = (const float*)d_in[5];
    const float* f_Dp  = (const float*)d_in[6];
    const float* f_rw  = (const float*)d_in[7];
    const float* f_ow  = (const float*)d_in[8];
    const float* b_inw = (const float*)d_in[9];
    const float* b_cw  = (const float*)d_in[10];
    const float* b_cb  = (const float*)d_in[11];
    const float* b_dtb = (const float*)d_in[12];
    const float* b_al  = (const float*)d_in[13];
    const float* b_Dp  = (const float*)d_in[14];
    const float* b_rw  = (const float*)d_in[15];
    const float* b_ow  = (const float*)d_in[16];
    const float* projw = (const float*)d_in[17];
    const float* projb = (const float*)d_in[18];
    const float* lnw   = (const float*)d_in[19];
    const float* lnb   = (const float*)d_in[20];

    char* ws = (char*)d_ws;
    ushort* zx  = (ushort*)(ws + OFF_ZX);
    ushort* xs  = (ushort*)(ws + OFF_XS);
    float*  Bq  = (float*)(ws + OFF_BB);
    float*  Cq  = (float*)(ws + OFF_CC);
    float*  dtq = (float*)(ws + OFF_DT);
    float*  daq = (float*)(ws + OFF_DA);
    float*  dtr = (float*)(ws + OFF_DR);
    ushort* wbf = (ushort*)(ws + OFF_CS);   // bf16 in_proj weights (pre-scan)
    ushort* cs  = (ushort*)(ws + OFF_CS);   // chunk states (post-gemm0)
    ushort* yn  = (ushort*)(ws + OFF_XS);   // aliases xs (dead after scan)
    ushort* dou = (ushort*)(ws + OFF_DO);   // aliases zx (dead after grms)
    float*  hb  = (float*)(ws + OFF_H);     // aliases zx (dead after grms)

    // K0: in_proj weights fp32 -> bf16
    wconv_k<<<dim3(DPROJ, 2), 256, 0, stream>>>(f_inw, b_inw, wbf);

    // K1: in_proj (both dirs), N=4256, K=1024 (+ fp32 dt spill)
    gemm_k<0><<<dim3((DPROJ + 63) / 64, MROWS / 128, 2), 256, 0, stream>>>(
        (const void*)x, (const void*)wbf, (const void*)(wbf + (size_t)DPROJ * DMODEL),
        (void*)zx, nullptr, nullptr, dtr, DPROJ, DMODEL);

    // K2: conv + activations + dt/dA (dt/dA transposed)
    conv_k<<<dim3(2 * MROWS), 256, 0, stream>>>(
        zx, dtr, f_cw, f_cb, b_cw, b_cb, f_dtb, f_al, b_dtb, b_al,
        xs, Bq, Cq, dtq, daq);

    // K3a: chunk-local scan from zero; writes y_local + S_c (overwrites wbf)
    scan_k<<<dim3(128, 4, NCHUNK), 256, 0, stream>>>(
        Bq, Cq, dtq, daq, xs, f_Dp, b_Dp, zx, cs);

    // K3b: stitch chunk states -> chunk-start states (in place)
    stitch_k<<<dim3(128), 256, 0, stream>>>(daq, cs);

    // K3c: seed correction via MFMA: y += cum * C.H^T
    corr_k<<<dim3(128, NCHUNK), 256, 0, stream>>>(Cq, daq, cs, zx);

    // K4: gated RMSNorm
    grms_k<<<dim3(2 * MROWS), 256, 0, stream>>>(zx, f_rw, b_rw, yn);

    // K5: out_proj (both dirs), N=1024, K=2048
    gemm_k<1><<<dim3(DMODEL / 64, MROWS / 128, 2), 256, 0, stream>>>(
        (const void*)yn, (const void*)f_ow, (const void*)b_ow,
        (void*)dou, nullptr, nullptr, nullptr, DMODEL, DINNER);

    // K6: final proj + residual + bias, N=1024, K=2048 (fp32 out)
    gemm_k<2><<<dim3(DMODEL / 64, MROWS / 128, 1), 256, 0, stream>>>(
        (const void*)dou, (const void*)projw, (const void*)projw,
        (void*)hb, x, projb, nullptr, DMODEL, DINNER);

    // K7: LayerNorm -> fp32 out
    ln_k<<<dim3(MROWS), 256, 0, stream>>>(hb, lnw, lnb, (float*)d_out);
}

// Round 7
// 518.751 us; speedup vs baseline: 2.0006x; 1.2864x over previous
//
#include <hip/hip_runtime.h>
#include <hip/hip_bf16.h>

#define DEV __device__ __forceinline__

typedef short bf16x8 __attribute__((ext_vector_type(8)));
typedef float f32x4 __attribute__((ext_vector_type(4)));

static constexpr int BATCH  = 2;
static constexpr int SEQ    = 1024;
static constexpr int DMODEL = 1024;
static constexpr int DINNER = 2048;
static constexpr int DSTATE = 64;
static constexpr int NH     = 32;
static constexpr int HD     = 64;
static constexpr int CONVD  = 2176;
static constexpr int DPROJ  = 4256;
static constexpr int MROWS  = BATCH * SEQ;   // 2048
static constexpr int NCHUNK = 16;            // 16 chunks x 64 steps
static constexpr int QC     = 64;            // chunk length

// ---- workspace layout (bytes) ---- peak ~72.8 MB
static constexpr size_t OFF_ZX = 0;
static constexpr size_t OFF_XS = OFF_ZX + (size_t)2*MROWS*DPROJ*2;   // bf16 [4096][2048]; reused as yn
static constexpr size_t OFF_BB = OFF_XS + (size_t)2*MROWS*DINNER*2;  // f32 [4096][64]
static constexpr size_t OFF_CC = OFF_BB + (size_t)2*MROWS*DSTATE*4;  // f32 [4096][64]
static constexpr size_t OFF_DT = OFF_CC + (size_t)2*MROWS*DSTATE*4;  // f32 [4][32][1024] dt (transposed)
static constexpr size_t OFF_DA = OFF_DT + (size_t)2*MROWS*NH*4;      // f32 [4][32][1024] ldA=A*dt (transposed)
static constexpr size_t OFF_DR = OFF_DA + (size_t)2*MROWS*NH*4;      // f32 [4096][32] raw dt spill
// CS region, time-shared: (a) bf16 in_proj weights [2][4256][1024] before states_k
//                         (b) bf16 chunk states [128][16][64][64] after
static constexpr size_t OFF_CS = OFF_DR + (size_t)2*MROWS*NH*4;
static constexpr size_t OFF_DO = 0;                                  // bf16 [4096][1024] (aliases zx)
static constexpr size_t OFF_H  = OFF_DO + (size_t)2*MROWS*DMODEL*2;  // f32  [2048][1024] (aliases zx)

DEV float b2f(ushort u) {
    union { unsigned int i; float f; } v;
    v.i = ((unsigned int)u) << 16;
    return v.f;
}
DEV ushort f2b(float f) {
    union { float f; unsigned int u; } v;
    v.f = f;
    unsigned int r = 0x7FFFu + ((v.u >> 16) & 1u);
    return (ushort)((v.u + r) >> 16);
}
DEV bf16x8 pack8(float4 a, float4 b) {
    bf16x8 r;
    r[0] = (short)f2b(a.x); r[1] = (short)f2b(a.y);
    r[2] = (short)f2b(a.z); r[3] = (short)f2b(a.w);
    r[4] = (short)f2b(b.x); r[5] = (short)f2b(b.y);
    r[6] = (short)f2b(b.z); r[7] = (short)f2b(b.w);
    return r;
}

// ---------------------------------------------------------------------------
// wconv: fp32 in_proj weights -> bf16, [2][4256][1024]. grid (4256, 2).
// ---------------------------------------------------------------------------
__global__ __launch_bounds__(256) void wconv_k(
    const float* __restrict__ w0, const float* __restrict__ w1,
    ushort* __restrict__ out)
{
    int row = blockIdx.x, dir = blockIdx.y;
    const float* src = (dir ? w1 : w0) + (size_t)row * DMODEL;
    ushort* dst = out + ((size_t)dir * DPROJ + row) * DMODEL;
    int tid = threadIdx.x;
    float4 f = *(const float4*)(src + tid * 4);
    ushort4 u;
    u.x = f2b(f.x); u.y = f2b(f.y); u.z = f2b(f.z); u.w = f2b(f.w);
    *(ushort4*)(dst + tid * 4) = u;
}

// ---------------------------------------------------------------------------
// GEMM: C[m][n] = sum_k A[m][k] * W[n][k]
// MODE 0: A = x (fp32, per-dir flip), W bf16 pre-converted; out bf16 +dt spill
// MODE 1: A = ynorm[dir] (bf16), W fp32;   out bf16
// MODE 2: A = concat(dou0, flip(dou1)) (bf16), W fp32; out fp32 +resid +bias
// ---------------------------------------------------------------------------
template<int MODE>
__global__ __launch_bounds__(256) void gemm_k(
    const void* __restrict__ asrc_,
    const void* __restrict__ w0, const void* __restrict__ w1,
    void* __restrict__ outp,
    const float* __restrict__ resid, const float* __restrict__ bias,
    float* __restrict__ dtraw, int N, int K)
{
    constexpr int BM = 128, BN = 64, BK = 32;
    __shared__ ushort As[BM][BK + 8];
    __shared__ ushort Bs[BN][BK + 8];
    const int tid  = threadIdx.x;
    const int wave = tid >> 6, lane = tid & 63;
    const int bn = blockIdx.x * BN, bm = blockIdx.y * BM;
    const int dir = blockIdx.z;

    f32x4 acc[2][4] = {};

    for (int k0 = 0; k0 < K; k0 += BK) {
        if (MODE == 0) {
            const float* xf = (const float*)asrc_;
            #pragma unroll
            for (int pass = 0; pass < 4; pass++) {
                int idx = pass * 256 + tid;
                int row = idx >> 3, cg = (idx & 7) * 4;
                int m = bm + row, k = k0 + cg;
                int b = m >> 10, l = m & 1023;
                int ls = dir ? (1023 - l) : l;
                float4 f = *(const float4*)(xf + (size_t)(b * SEQ + ls) * DMODEL + k);
                ushort4 u;
                u.x = f2b(f.x); u.y = f2b(f.y); u.z = f2b(f.z); u.w = f2b(f.w);
                *(ushort4*)&As[row][cg] = u;
            }
        } else {
            const ushort* ab = (const ushort*)asrc_;
            #pragma unroll
            for (int pass = 0; pass < 2; pass++) {
                int idx = pass * 256 + tid;
                int row = idx >> 2, cg = (idx & 3) * 8;
                int m = bm + row, k = k0 + cg;
                const ushort* src;
                if (MODE == 1) {
                    src = ab + ((size_t)(dir * MROWS + m) * DINNER + k);
                } else {
                    if (k < DMODEL) {
                        src = ab + ((size_t)m * DMODEL + k);
                    } else {
                        int l = m & 1023;
                        int m2 = (m & ~1023) | (1023 - l);
                        src = ab + ((size_t)(MROWS + m2) * DMODEL + (k - DMODEL));
                    }
                }
                *(uint4*)&As[row][cg] = *(const uint4*)src;
            }
        }
        if (MODE == 0) {
            const ushort* wb = (const ushort*)(dir ? w1 : w0);
            int row = tid >> 2, cg = (tid & 3) * 8;
            int n = bn + row, k = k0 + cg;
            uint4 v = {0u, 0u, 0u, 0u};
            if (n < N) v = *(const uint4*)(wb + (size_t)n * K + k);
            *(uint4*)&Bs[row][cg] = v;
        } else {
            const float* w = (const float*)(dir ? w1 : w0);
            #pragma unroll
            for (int pass = 0; pass < 2; pass++) {
                int idx = pass * 256 + tid;
                int row = idx >> 3, cg = (idx & 7) * 4;
                int n = bn + row, k = k0 + cg;
                float4 f = {0.f, 0.f, 0.f, 0.f};
                if (n < N) f = *(const float4*)(w + (size_t)n * K + k);
                ushort4 u;
                u.x = f2b(f.x); u.y = f2b(f.y); u.z = f2b(f.z); u.w = f2b(f.w);
                *(ushort4*)&Bs[row][cg] = u;
            }
        }
        __syncthreads();

        const int ar = wave * 32 + (lane & 15);
        const int ko = (lane >> 4) * 8;
        bf16x8 a0 = *(const bf16x8*)&As[ar][ko];
        bf16x8 a1 = *(const bf16x8*)&As[ar + 16][ko];
        #pragma unroll
        for (int ni = 0; ni < 4; ni++) {
            bf16x8 bfr = *(const bf16x8*)&Bs[ni * 16 + (lane & 15)][ko];
            acc[0][ni] = __builtin_amdgcn_mfma_f32_16x16x32_bf16(a0, bfr, acc[0][ni], 0, 0, 0);
            acc[1][ni] = __builtin_amdgcn_mfma_f32_16x16x32_bf16(a1, bfr, acc[1][ni], 0, 0, 0);
        }
        __syncthreads();
    }

    #pragma unroll
    for (int mi = 0; mi < 2; mi++) {
        #pragma unroll
        for (int ni = 0; ni < 4; ni++) {
            #pragma unroll
            for (int j = 0; j < 4; j++) {
                int row = bm + wave * 32 + mi * 16 + (lane >> 4) * 4 + j;
                int col = bn + ni * 16 + (lane & 15);
                if (col >= N) continue;
                float v = acc[mi][ni][j];
                if (MODE == 0) {
                    ((ushort*)outp)[(size_t)(dir * MROWS + row) * DPROJ + col] = f2b(v);
                    if (col >= 4224)
                        dtraw[(size_t)(dir * MROWS + row) * NH + (col - 4224)] = v;
                } else if (MODE == 1) {
                    ((ushort*)outp)[(size_t)(dir * MROWS + row) * DMODEL + col] = f2b(v);
                } else {
                    float r = resid[(size_t)row * DMODEL + col] + bias[col];
                    ((float*)outp)[(size_t)row * DMODEL + col] = v + r;
                }
            }
        }
    }
}

// ---------------------------------------------------------------------------
// causal depthwise conv(width 4) + bias + SiLU; dt = softplus(raw+bias);
// ldA = A*dt (LOG decay, exact). dt/ldA written TRANSPOSED: [dirb*32+h][l]
// ---------------------------------------------------------------------------
__global__ __launch_bounds__(256) void conv_k(
    const ushort* __restrict__ zx, const float* __restrict__ dtr,
    const float* __restrict__ cw0, const float* __restrict__ cb0,
    const float* __restrict__ cw1, const float* __restrict__ cb1,
    const float* __restrict__ dtb0, const float* __restrict__ al0,
    const float* __restrict__ dtb1, const float* __restrict__ al1,
    ushort* __restrict__ xs, float* __restrict__ Bq, float* __restrict__ Cq,
    float* __restrict__ dtq, float* __restrict__ ldq)
{
    int id = blockIdx.x;
    int dir = id >> 11;
    int m = id & 2047;
    int l = m & 1023;
    const float* cw = dir ? cw1 : cw0;
    const float* cb = dir ? cb1 : cb0;
    int tid = threadIdx.x;

    for (int c = tid; c < CONVD; c += 256) {
        float acc = cb[c];
        #pragma unroll
        for (int t = 0; t < 4; t++) {
            int ls = l - 3 + t;
            if (ls >= 0) {
                acc += cw[t * CONVD + c] *
                       b2f(zx[(size_t)(id - l + ls) * DPROJ + 2048 + c]);
            }
        }
        float v = acc / (1.f + expf(-acc));   // SiLU
        if (c < DINNER) {
            xs[(size_t)id * DINNER + c] = f2b(v);
        } else if (c < DINNER + DSTATE) {
            Bq[(size_t)id * DSTATE + (c - DINNER)] = v;
        } else {
            Cq[(size_t)id * DSTATE + (c - DINNER - DSTATE)] = v;
        }
    }
    if (tid < NH) {
        const float* dtb = dir ? dtb1 : dtb0;
        const float* al  = dir ? al1 : al0;
        float raw = dtr[(size_t)id * NH + tid] + dtb[tid];
        float dt = raw > 20.f ? raw : log1pf(expf(raw));
        float ldA = -expf(al[tid]) * dt;      // ln(dA), exact
        int dirb = id >> 10;
        dtq[(size_t)(dirb * NH + tid) * SEQ + l] = dt;
        ldq[(size_t)(dirb * NH + tid) * SEQ + l] = ldA;
    }
}

// ---------------------------------------------------------------------------
// states_k: chunk-local end state via MFMA.
// S_c[p][n] = sum_j (dt_j * exp(cum63-cum_j) * x[j,p]) * B[j,n]
// grid (128 ids, 16 chunks), 256 thr (4 waves; wave owns p-rows w*16..+16).
// ---------------------------------------------------------------------------
__global__ __launch_bounds__(256) void states_k(
    const float* __restrict__ Bq, const float* __restrict__ dtT,
    const float* __restrict__ ldT, const ushort* __restrict__ xsq,
    ushort* __restrict__ cs)
{
    int id = blockIdx.x;                 // dirb*32 + h
    int h = id & 31;
    int c = blockIdx.y;
    int tid = threadIdx.x;
    int wave = tid >> 6, lane = tid & 63;
    int quad = lane >> 4;
    int base = (id >> 5) << 10;
    int l0 = c * QC;

    __shared__ float wsh[QC];
    __shared__ ushort Xw[64][80];        // A: [p][j] = w_j * x[j,p]
    __shared__ ushort Bt[64][72];        // B: [n][j] = B[j,n]

    if (tid < 64) {
        float ld = ldT[(size_t)id * SEQ + l0 + tid];
        #pragma unroll
        for (int st = 1; st < 64; st <<= 1) {
            float o = __shfl_up(ld, st);
            if (tid >= st) ld += o;
        }
        float tot = __shfl(ld, 63);
        wsh[tid] = dtT[(size_t)id * SEQ + l0 + tid] * expf(tot - ld);
    }
    __syncthreads();

    {
        int j = tid >> 2, p0 = (tid & 3) * 16;
        float wj = wsh[j];
        const ushort* xrow = xsq + (size_t)(base + l0 + j) * DINNER + h * HD + p0;
        #pragma unroll
        for (int q = 0; q < 4; q++) {
            ushort4 xv = *(const ushort4*)(xrow + q * 4);
            Xw[p0 + q * 4 + 0][j] = f2b(b2f(xv.x) * wj);
            Xw[p0 + q * 4 + 1][j] = f2b(b2f(xv.y) * wj);
            Xw[p0 + q * 4 + 2][j] = f2b(b2f(xv.z) * wj);
            Xw[p0 + q * 4 + 3][j] = f2b(b2f(xv.w) * wj);
        }
        int j2 = lane, ng = wave * 16;
        const float* brow = Bq + (size_t)(base + l0 + j2) * DSTATE + ng;
        #pragma unroll
        for (int q = 0; q < 4; q++) {
            float4 f = *(const float4*)(brow + q * 4);
            Bt[ng + q * 4 + 0][j2] = f2b(f.x);
            Bt[ng + q * 4 + 1][j2] = f2b(f.y);
            Bt[ng + q * 4 + 2][j2] = f2b(f.z);
            Bt[ng + q * 4 + 3][j2] = f2b(f.w);
        }
    }
    __syncthreads();

    f32x4 acc[4] = {};
    #pragma unroll
    for (int kt = 0; kt < 2; kt++) {
        int k = kt * 32 + quad * 8;
        bf16x8 af = *(const bf16x8*)&Xw[wave * 16 + (lane & 15)][k];
        #pragma unroll
        for (int ni = 0; ni < 4; ni++) {
            bf16x8 bf = *(const bf16x8*)&Bt[ni * 16 + (lane & 15)][k];
            acc[ni] = __builtin_amdgcn_mfma_f32_16x16x32_bf16(af, bf, acc[ni], 0, 0, 0);
        }
    }

    ushort* out = cs + ((size_t)id * NCHUNK + c) * HD * DSTATE;
    #pragma unroll
    for (int ni = 0; ni < 4; ni++) {
        #pragma unroll
        for (int j = 0; j < 4; j++) {
            int p = wave * 16 + quad * 4 + j;
            int n = ni * 16 + (lane & 15);
            out[(size_t)p * DSTATE + n] = f2b(acc[ni][j]);
        }
    }
}

// ---------------------------------------------------------------------------
// Stitch: H_{c+1} = S_c + exp(sum ldA over chunk) * H_c, rewriting cs[id][c]
// in place with the chunk-START state H_c (H_0 = 0). 128 blocks.
// ---------------------------------------------------------------------------
__global__ __launch_bounds__(256) void stitch_k(
    const float* __restrict__ ldT, ushort* __restrict__ cs)
{
    int id = blockIdx.x;
    int tid = threadIdx.x;
    __shared__ float red[256];
    __shared__ float dec[NCHUNK];

    float4 d4 = *(const float4*)(ldT + (size_t)id * SEQ + tid * 4);
    red[tid] = d4.x + d4.y + d4.z + d4.w;
    __syncthreads();
    if (tid < NCHUNK) {
        float s = 0.f;
        #pragma unroll
        for (int i = 0; i < 16; i++) s += red[tid * 16 + i];
        dec[tid] = expf(s);
    }
    __syncthreads();

    int p = tid >> 2, n0 = (tid & 3) * 16;
    ushort* ptr = cs + (size_t)id * NCHUNK * HD * DSTATE + p * DSTATE + n0;

    float st[16];
    #pragma unroll
    for (int i = 0; i < 16; i++) st[i] = 0.f;

    for (int c = 0; c < NCHUNK; c++) {
        ushort* row = ptr + (size_t)c * HD * DSTATE;
        float tmp[16];
        #pragma unroll
        for (int i = 0; i < 16; i++) tmp[i] = b2f(row[i]);
        #pragma unroll
        for (int i = 0; i < 16; i++) row[i] = f2b(st[i]);     // H_c
        float d = dec[c];
        #pragma unroll
        for (int i = 0; i < 16; i++) st[i] = fmaf(d, st[i], tmp[i]);
    }
}

// ---------------------------------------------------------------------------
// ssd_k: full intra-chunk output via MFMA + seed term.
//   S = C.B^T (64x64, k=n); M[l][j] = (l>=j) ? exp(cum_l-cum_j)*dt_j*S : 0
//   Y = M.X^T (k=j) + (exp(cum_l)*C).H^T (k=n) + D*x
// grid (128 ids, 16 chunks), 256 thr (4 waves; wave owns l-rows w*16..+16).
// ---------------------------------------------------------------------------
__global__ __launch_bounds__(256) void ssd_k(
    const float* __restrict__ Bq, const float* __restrict__ Cq,
    const float* __restrict__ dtT, const float* __restrict__ ldT,
    const ushort* __restrict__ xsq, const ushort* __restrict__ cs,
    const float* __restrict__ D0, const float* __restrict__ D1,
    ushort* __restrict__ yout)
{
    int id = blockIdx.x;                 // dirb*32 + h
    int dir = id >> 6, h = id & 31;
    int c = blockIdx.y;
    int tid = threadIdx.x;
    int wave = tid >> 6, lane = tid & 63;
    int quad = lane >> 4;
    int base = (id >> 5) << 10;
    int l0 = c * QC;

    __shared__ float cum[QC], dts[QC];
    __shared__ ushort Ms[64][72];        // M[l][j] bf16
    __shared__ ushort Xb[64][80];        // X^T [p][j] bf16

    // stage Xb (transpose of x chunk)
    {
        int j = tid >> 2, p0 = (tid & 3) * 16;
        const ushort* xrow = xsq + (size_t)(base + l0 + j) * DINNER + h * HD + p0;
        #pragma unroll
        for (int q = 0; q < 4; q++) {
            ushort4 xv = *(const ushort4*)(xrow + q * 4);
            Xb[p0 + q * 4 + 0][j] = xv.x;
            Xb[p0 + q * 4 + 1][j] = xv.y;
            Xb[p0 + q * 4 + 2][j] = xv.z;
            Xb[p0 + q * 4 + 3][j] = xv.w;
        }
    }
    if (tid < 64) {
        float ld = ldT[(size_t)id * SEQ + l0 + tid];
        #pragma unroll
        for (int st = 1; st < 64; st <<= 1) {
            float o = __shfl_up(ld, st);
            if (tid >= st) ld += o;
        }
        cum[tid] = ld;
        dts[tid] = dtT[(size_t)id * SEQ + l0 + tid];
    }

    // GEMM1: S[l][j] = sum_n C[l,n]*B[j,n]  (global fp32 -> bf16 frags)
    f32x4 sacc[4] = {};
    #pragma unroll
    for (int kt = 0; kt < 2; kt++) {
        int k = kt * 32 + quad * 8;
        const float* cp = Cq + (size_t)(base + l0 + wave * 16 + (lane & 15)) * DSTATE + k;
        bf16x8 af = pack8(*(const float4*)cp, *(const float4*)(cp + 4));
        #pragma unroll
        for (int ni = 0; ni < 4; ni++) {
            const float* bp = Bq + (size_t)(base + l0 + ni * 16 + (lane & 15)) * DSTATE + k;
            bf16x8 bf = pack8(*(const float4*)bp, *(const float4*)(bp + 4));
            sacc[ni] = __builtin_amdgcn_mfma_f32_16x16x32_bf16(af, bf, sacc[ni], 0, 0, 0);
        }
    }
    __syncthreads();   // cum/dts/Xb ready

    // mask + decay + dt, write M to LDS (C-layout scatter)
    #pragma unroll
    for (int ni = 0; ni < 4; ni++) {
        int j = ni * 16 + (lane & 15);
        float cj = cum[j], dj = dts[j];
        #pragma unroll
        for (int r = 0; r < 4; r++) {
            int l = wave * 16 + quad * 4 + r;
            float v = 0.f;
            if (l >= j) v = expf(cum[l] - cj) * dj * sacc[ni][r];
            Ms[l][j] = f2b(v);
        }
    }
    __syncthreads();

    // GEMM2: Y[l][p] = M.X^T + (exp(cum_l)*C).H^T
    f32x4 acc[4] = {};
    #pragma unroll
    for (int kt = 0; kt < 2; kt++) {
        int k = kt * 32 + quad * 8;
        bf16x8 af = *(const bf16x8*)&Ms[wave * 16 + (lane & 15)][k];
        #pragma unroll
        for (int ni = 0; ni < 4; ni++) {
            bf16x8 bf = *(const bf16x8*)&Xb[ni * 16 + (lane & 15)][k];
            acc[ni] = __builtin_amdgcn_mfma_f32_16x16x32_bf16(af, bf, acc[ni], 0, 0, 0);
        }
    }
    const ushort* Hrow = cs + ((size_t)id * NCHUNK + c) * HD * DSTATE;
    {
        float cl = expf(cum[wave * 16 + (lane & 15)]);
        #pragma unroll
        for (int kt = 0; kt < 2; kt++) {
            int k = kt * 32 + quad * 8;
            const float* cp = Cq + (size_t)(base + l0 + wave * 16 + (lane & 15)) * DSTATE + k;
            float4 c0 = *(const float4*)cp;
            float4 c1 = *(const float4*)(cp + 4);
            float4 s0 = {c0.x * cl, c0.y * cl, c0.z * cl, c0.w * cl};
            float4 s1 = {c1.x * cl, c1.y * cl, c1.z * cl, c1.w * cl};
            bf16x8 af = pack8(s0, s1);
            #pragma unroll
            for (int ni = 0; ni < 4; ni++) {
                bf16x8 bf = *(const bf16x8*)(Hrow + (size_t)(ni * 16 + (lane & 15)) * DSTATE + k);
                acc[ni] = __builtin_amdgcn_mfma_f32_16x16x32_bf16(af, bf, acc[ni], 0, 0, 0);
            }
        }
    }

    // epilogue: y = acc + D*x
    float Dv = (dir ? D1 : D0)[h];
    int lb = wave * 16 + quad * 4;
    #pragma unroll
    for (int ni = 0; ni < 4; ni++) {
        int p = ni * 16 + (lane & 15);
        ushort4 x4 = *(const ushort4*)&Xb[p][lb];
        float xv[4] = { b2f(x4.x), b2f(x4.y), b2f(x4.z), b2f(x4.w) };
        #pragma unroll
        for (int r = 0; r < 4; r++) {
            int l = lb + r;
            yout[(size_t)(base + l0 + l) * DPROJ + 2048 + h * HD + p] =
                f2b(acc[ni][r] + Dv * xv[r]);
        }
    }
}

// ---------------------------------------------------------------------------
// gated RMSNorm: g = y * silu(z); g * rsqrt(mean(g^2)+eps) * rms_w -> bf16
// ---------------------------------------------------------------------------
__global__ __launch_bounds__(256) void grms_k(
    const ushort* __restrict__ zx,
    const float* __restrict__ rw0, const float* __restrict__ rw1,
    ushort* __restrict__ yn)
{
    int id = blockIdx.x;
    int dir = id >> 11;
    const float* rw = dir ? rw1 : rw0;
    int tid = threadIdx.x;
    float g[8];
    float ss = 0.f;
    #pragma unroll
    for (int i = 0; i < 8; i++) {
        int c = i * 256 + tid;
        float z  = b2f(zx[(size_t)id * DPROJ + c]);
        float yv = b2f(zx[(size_t)id * DPROJ + 2048 + c]);
        float v = yv * (z / (1.f + expf(-z)));
        g[i] = v;
        ss += v * v;
    }
    for (int o = 32; o; o >>= 1) ss += __shfl_down(ss, o);
    __shared__ float t4[4];
    if ((tid & 63) == 0) t4[tid >> 6] = ss;
    __syncthreads();
    ss = t4[0] + t4[1] + t4[2] + t4[3];
    float sc = rsqrtf(ss * (1.f / DINNER) + 1e-5f);
    #pragma unroll
    for (int i = 0; i < 8; i++) {
        int c = i * 256 + tid;
        yn[(size_t)id * DINNER + c] = f2b(g[i] * sc * rw[c]);
    }
}

// ---------------------------------------------------------------------------
// LayerNorm over 1024 + affine -> fp32 out
// ---------------------------------------------------------------------------
__global__ __launch_bounds__(256) void ln_k(
    const float* __restrict__ h, const float* __restrict__ lw,
    const float* __restrict__ lb, float* __restrict__ out)
{
    int m = blockIdx.x;
    int tid = threadIdx.x;
    float v[4];
    float s = 0.f, s2 = 0.f;
    #pragma unroll
    for (int i = 0; i < 4; i++) {
        int c = i * 256 + tid;
        v[i] = h[(size_t)m * DMODEL + c];
        s += v[i];
        s2 += v[i] * v[i];
    }
    for (int o = 32; o; o >>= 1) { s += __shfl_down(s, o); s2 += __shfl_down(s2, o); }
    __shared__ float ts[4], ts2[4];
    if ((tid & 63) == 0) { ts[tid >> 6] = s; ts2[tid >> 6] = s2; }
    __syncthreads();
    s  = ts[0] + ts[1] + ts[2] + ts[3];
    s2 = ts2[0] + ts2[1] + ts2[2] + ts2[3];
    float mu  = s * (1.f / DMODEL);
    float var = s2 * (1.f / DMODEL) - mu * mu;
    float sc  = rsqrtf(var + 1e-5f);
    #pragma unroll
    for (int i = 0; i < 4; i++) {
        int c = i * 256 + tid;
        out[(size_t)m * DMODEL + c] = (v[i] - mu) * sc * lw[c] + lb[c];
    }
}

extern "C" void kernel_launch(void* const* d_in, const int* in_sizes, int n_in,
                              void* d_out, int out_size, void* d_ws, size_t ws_size,
                              hipStream_t stream)
{
    const float* x     = (const float*)d_in[0];
    const float* f_inw = (const float*)d_in[1];
    const float* f_cw  = (const float*)d_in[2];
    const float* f_cb  = (const float*)d_in[3];
    const float* f_dtb = (const float*)d_in[4];
    const float* f_al  = (const float*)d_in[5];
    const float* f_Dp  = (const float*)d_in[6];
    const float* f_rw  = (const float*)d_in[7];
    const float* f_ow  = (const float*)d_in[8];
    const float* b_inw = (const float*)d_in[9];
    const float* b_cw  = (const float*)d_in[10];
    const float* b_cb  = (const float*)d_in[11];
    const float* b_dtb = (const float*)d_in[12];
    const float* b_al  = (const float*)d_in[13];
    const float* b_Dp  = (const float*)d_in[14];
    const float* b_rw  = (const float*)d_in[15];
    const float* b_ow  = (const float*)d_in[16];
    const float* projw = (const float*)d_in[17];
    const float* projb = (const float*)d_in[18];
    const float* lnw   = (const float*)d_in[19];
    const float* lnb   = (const float*)d_in[20];

    char* ws = (char*)d_ws;
    ushort* zx  = (ushort*)(ws + OFF_ZX);
    ushort* xs  = (ushort*)(ws + OFF_XS);
    float*  Bq  = (float*)(ws + OFF_BB);
    float*  Cq  = (float*)(ws + OFF_CC);
    float*  dtq = (float*)(ws + OFF_DT);
    float*  ldq = (float*)(ws + OFF_DA);
    float*  dtr = (float*)(ws + OFF_DR);
    ushort* wbf = (ushort*)(ws + OFF_CS);   // bf16 in_proj weights (pre-states)
    ushort* cs  = (ushort*)(ws + OFF_CS);   // chunk states (post-gemm0)
    ushort* yn  = (ushort*)(ws + OFF_XS);   // aliases xs (dead after ssd)
    ushort* dou = (ushort*)(ws + OFF_DO);   // aliases zx (dead after grms)
    float*  hb  = (float*)(ws + OFF_H);     // aliases zx (dead after grms)

    // K0: in_proj weights fp32 -> bf16
    wconv_k<<<dim3(DPROJ, 2), 256, 0, stream>>>(f_inw, b_inw, wbf);

    // K1: in_proj (both dirs), N=4256, K=1024 (+ fp32 dt spill)
    gemm_k<0><<<dim3((DPROJ + 63) / 64, MROWS / 128, 2), 256, 0, stream>>>(
        (const void*)x, (const void*)wbf, (const void*)(wbf + (size_t)DPROJ * DMODEL),
        (void*)zx, nullptr, nullptr, dtr, DPROJ, DMODEL);

    // K2: conv + activations + dt/ldA (transposed)
    conv_k<<<dim3(2 * MROWS), 256, 0, stream>>>(
        zx, dtr, f_cw, f_cb, b_cw, b_cb, f_dtb, f_al, b_dtb, b_al,
        xs, Bq, Cq, dtq, ldq);

    // K3a: chunk-local end states via MFMA (overwrites wbf)
    states_k<<<dim3(128, NCHUNK), 256, 0, stream>>>(Bq, dtq, ldq, xs, cs);

    // K3b: stitch chunk states -> chunk-start states (in place)
    stitch_k<<<dim3(128), 256, 0, stream>>>(ldq, cs);

    // K3c: intra-chunk SSD matmul + seed + D*x; writes y bf16 into zx cols 2048..
    ssd_k<<<dim3(128, NCHUNK), 256, 0, stream>>>(
        Bq, Cq, dtq, ldq, xs, cs, f_Dp, b_Dp, zx);

    // K4: gated RMSNorm
    grms_k<<<dim3(2 * MROWS), 256, 0, stream>>>(zx, f_rw, b_rw, yn);

    // K5: out_proj (both dirs), N=1024, K=2048
    gemm_k<1><<<dim3(DMODEL / 64, MROWS / 128, 2), 256, 0, stream>>>(
        (const void*)yn, (const void*)f_ow, (const void*)b_ow,
        (void*)dou, nullptr, nullptr, nullptr, DMODEL, DINNER);

    // K6: final proj + residual + bias, N=1024, K=2048 (fp32 out)
    gemm_k<2><<<dim3(DMODEL / 64, MROWS / 128, 1), 256, 0, stream>>>(
        (const void*)dou, (const void*)projw, (const void*)projw,
        (void*)hb, x, projb, nullptr, DMODEL, DINNER);

    // K7: LayerNorm -> fp32 out
    ln_k<<<dim3(MROWS), 256, 0, stream>>>(hb, lnw, lnb, (float*)d_out);
}

// Round 9
// 395.897 us; speedup vs baseline: 2.6214x; 1.3103x over previous
//
#include <hip/hip_runtime.h>
#include <hip/hip_bf16.h>

#define DEV __device__ __forceinline__

typedef short bf16x8 __attribute__((ext_vector_type(8)));
typedef float f32x4 __attribute__((ext_vector_type(4)));

static constexpr int BATCH  = 2;
static constexpr int SEQ    = 1024;
static constexpr int DMODEL = 1024;
static constexpr int DINNER = 2048;
static constexpr int DSTATE = 64;
static constexpr int NH     = 32;
static constexpr int HD     = 64;
static constexpr int CONVD  = 2176;
static constexpr int DPROJ  = 4256;
static constexpr int MROWS  = BATCH * SEQ;   // 2048
static constexpr int NCHUNK = 16;
static constexpr int QC     = 64;

// ---- workspace layout (bytes) ---- peak 74.8 MB (same as proven R6/R7)
static constexpr size_t OFF_ZX = 0;                                  // bf16 [4096][4256]
static constexpr size_t OFF_XS = OFF_ZX + (size_t)2*MROWS*DPROJ*2;   // bf16 [4096][2048]; xbf pre-conv, xs after, yn after ssd
static constexpr size_t OFF_BB = OFF_XS + (size_t)2*MROWS*DINNER*2;  // f32 [4096][64]
static constexpr size_t OFF_CC = OFF_BB + (size_t)2*MROWS*DSTATE*4;  // f32 [4096][64]
static constexpr size_t OFF_DT = OFF_CC + (size_t)2*MROWS*DSTATE*4;  // f32 [4][32][1024] dt
static constexpr size_t OFF_DA = OFF_DT + (size_t)2*MROWS*NH*4;      // f32 [4][32][1024] ldA
static constexpr size_t OFF_DR = OFF_DA + (size_t)2*MROWS*NH*4;      // f32 [4096][32] raw dt spill
// CS: time-shared (a) bf16 in_proj weights [2][4256][1024]  (b) chunk states
static constexpr size_t OFF_CS = OFF_DR + (size_t)2*MROWS*NH*4;
// aliased into zx (dead after grms):
static constexpr size_t OFF_DD = 0;                                  // bf16 [2048][2048] packed dir outs
static constexpr size_t OFF_H  = OFF_DD + (size_t)MROWS*2*DMODEL;    // f32 [2048][1024]
static constexpr size_t OFF_WO = OFF_H  + (size_t)MROWS*DMODEL*4;    // bf16 [2][1024][2048]
static constexpr size_t OFF_WP = OFF_WO + (size_t)2*DMODEL*DINNER*2; // bf16 [1024][2048]
// xbf lives at OFF_XS until conv_k runs (gemm<0> completes first)

DEV float b2f(ushort u) {
    union { unsigned int i; float f; } v;
    v.i = ((unsigned int)u) << 16;
    return v.f;
}
DEV ushort f2b(float f) {
    union { float f; unsigned int u; } v;
    v.f = f;
    unsigned int r = 0x7FFFu + ((v.u >> 16) & 1u);
    return (ushort)((v.u + r) >> 16);
}
DEV bf16x8 pack8(float4 a, float4 b) {
    bf16x8 r;
    r[0] = (short)f2b(a.x); r[1] = (short)f2b(a.y);
    r[2] = (short)f2b(a.z); r[3] = (short)f2b(a.w);
    r[4] = (short)f2b(b.x); r[5] = (short)f2b(b.y);
    r[6] = (short)f2b(b.z); r[7] = (short)f2b(b.w);
    return r;
}
DEV void gll16(const ushort* g, ushort* l) {
    __builtin_amdgcn_global_load_lds(
        (const __attribute__((address_space(1))) unsigned int*)g,
        (__attribute__((address_space(3))) unsigned int*)l, 16, 0, 0);
}

// ---------------------------------------------------------------------------
// cvt: fp32 -> bf16, n multiple of 1024. grid = n/1024.
// ---------------------------------------------------------------------------
__global__ __launch_bounds__(256) void cvt_k(
    const float* __restrict__ src, ushort* __restrict__ dst)
{
    size_t i = ((size_t)blockIdx.x * 256 + threadIdx.x) * 4;
    float4 f = *(const float4*)(src + i);
    ushort4 u;
    u.x = f2b(f.x); u.y = f2b(f.y); u.z = f2b(f.z); u.w = f2b(f.w);
    *(ushort4*)(dst + i) = u;
}

// ---------------------------------------------------------------------------
// GEMM (m97-style): C[m][n] = sum_k A[m][k]*W[n][k], all bf16 inputs,
// global_load_lds width-16 staging, BM=128, BK=32, BN=128 or 64.
// W per-dir base = W + dir*wstride   (R8 bug: this offset was missing)
// MODE 0: A = xbf with per-dir flip; out zx bf16 + fp32 dt spill (N=4256)
// MODE 1: A = yn[dir]; out dd[m'][dir*1024+col] bf16, dir1 rows pre-flipped
// MODE 2: A = dd; out hb fp32 + resid + bias
// ---------------------------------------------------------------------------
template<int MODE, int BN>
__global__ __launch_bounds__(256) void gemm_k(
    const ushort* __restrict__ A, const ushort* __restrict__ W,
    size_t wstride, void* __restrict__ outp, const float* __restrict__ resid,
    const float* __restrict__ bias, float* __restrict__ dtraw,
    int N, int K)
{
    constexpr int BM = 128, BK = 32;
    constexpr int MT = (BN == 128) ? 4 : 2;
    constexpr int NBL = (BN == 128) ? 2 : 1;
    __shared__ ushort As[BM * BK];
    __shared__ ushort Bs[BN * BK];
    const int tid = threadIdx.x;
    const int wave = tid >> 6, lane = tid & 63;
    const int quad = lane >> 4, l16 = lane & 15;
    const int bn = blockIdx.x * BN, bm = blockIdx.y * BM;
    const int dir = blockIdx.z;
    const ushort* Wd = W + (size_t)dir * wstride;
    const int wmoff = (BN == 128) ? (wave >> 1) * 64 : wave * 32;
    const int wnoff = (BN == 128) ? (wave & 1) * 64 : 0;

    // per-lane global source (row li*16 + (lane>>2), col (lane&3)*8);
    // LDS dest is wave-uniform base (HW adds lane*16B).
    const ushort* aga[2];
    ushort* ald[2];
    #pragma unroll
    for (int t = 0; t < 2; t++) {
        int li = wave * 2 + t;
        int r = li * 16 + (lane >> 2);
        int m = bm + r;
        size_t rowidx;
        if (MODE == 0) {
            int b = m >> 10, l = m & 1023;
            int ls = dir ? (1023 - l) : l;
            rowidx = (size_t)((b << 10) + ls);
        } else if (MODE == 1) {
            rowidx = (size_t)(dir * MROWS + m);
        } else {
            rowidx = (size_t)m;
        }
        aga[t] = A + rowidx * K + (lane & 3) * 8;
        ald[t] = &As[li * 512];
    }
    const ushort* bga[NBL];
    ushort* bld[NBL];
    #pragma unroll
    for (int t = 0; t < NBL; t++) {
        int li = wave * NBL + t;
        int n = bn + li * 16 + (lane >> 2);
        if (n >= N) n = N - 1;            // clamp; cols >= N discarded
        bga[t] = Wd + (size_t)n * K + (lane & 3) * 8;
        bld[t] = &Bs[li * 512];
    }

    f32x4 acc[MT][4] = {};

    for (int k0 = 0; k0 < K; k0 += BK) {
        #pragma unroll
        for (int t = 0; t < 2; t++) gll16(aga[t] + k0, ald[t]);
        #pragma unroll
        for (int t = 0; t < NBL; t++) gll16(bga[t] + k0, bld[t]);
        __syncthreads();

        bf16x8 af[MT], bfr[4];
        #pragma unroll
        for (int mt = 0; mt < MT; mt++)
            af[mt] = *(const bf16x8*)&As[(wmoff + mt * 16 + l16) * BK + quad * 8];
        #pragma unroll
        for (int nt = 0; nt < 4; nt++)
            bfr[nt] = *(const bf16x8*)&Bs[(wnoff + nt * 16 + l16) * BK + quad * 8];
        #pragma unroll
        for (int mt = 0; mt < MT; mt++)
            #pragma unroll
            for (int nt = 0; nt < 4; nt++)
                acc[mt][nt] = __builtin_amdgcn_mfma_f32_16x16x32_bf16(
                    af[mt], bfr[nt], acc[mt][nt], 0, 0, 0);
        __syncthreads();
    }

    // epilogue: C/D layout row=quad*4+j, col=l16
    #pragma unroll
    for (int mt = 0; mt < MT; mt++) {
        #pragma unroll
        for (int nt = 0; nt < 4; nt++) {
            #pragma unroll
            for (int j = 0; j < 4; j++) {
                int row = bm + wmoff + mt * 16 + quad * 4 + j;
                int col = bn + wnoff + nt * 16 + l16;
                if (col >= N) continue;
                float v = acc[mt][nt][j];
                if (MODE == 0) {
                    ((ushort*)outp)[(size_t)(dir * MROWS + row) * DPROJ + col] = f2b(v);
                    if (col >= 4224)
                        dtraw[(size_t)(dir * MROWS + row) * NH + (col - 4224)] = v;
                } else if (MODE == 1) {
                    int mr = dir ? ((row & 1024) | (1023 - (row & 1023))) : row;
                    ((ushort*)outp)[(size_t)mr * (2 * DMODEL) + dir * DMODEL + col] = f2b(v);
                } else {
                    float r = resid[(size_t)row * DMODEL + col] + bias[col];
                    ((float*)outp)[(size_t)row * DMODEL + col] = v + r;
                }
            }
        }
    }
}

// ---------------------------------------------------------------------------
// causal depthwise conv(width 4) + bias + SiLU; dt = softplus(raw+bias);
// ldA = A*dt (log decay). dt/ldA TRANSPOSED: [dirb*32+h][l]
// ---------------------------------------------------------------------------
__global__ __launch_bounds__(256) void conv_k(
    const ushort* __restrict__ zx, const float* __restrict__ dtr,
    const float* __restrict__ cw0, const float* __restrict__ cb0,
    const float* __restrict__ cw1, const float* __restrict__ cb1,
    const float* __restrict__ dtb0, const float* __restrict__ al0,
    const float* __restrict__ dtb1, const float* __restrict__ al1,
    ushort* __restrict__ xs, float* __restrict__ Bq, float* __restrict__ Cq,
    float* __restrict__ dtq, float* __restrict__ ldq)
{
    int id = blockIdx.x;
    int dir = id >> 11;
    int m = id & 2047;
    int l = m & 1023;
    const float* cw = dir ? cw1 : cw0;
    const float* cb = dir ? cb1 : cb0;
    int tid = threadIdx.x;

    for (int c = tid; c < CONVD; c += 256) {
        float acc = cb[c];
        #pragma unroll
        for (int t = 0; t < 4; t++) {
            int ls = l - 3 + t;
            if (ls >= 0) {
                acc += cw[t * CONVD + c] *
                       b2f(zx[(size_t)(id - l + ls) * DPROJ + 2048 + c]);
            }
        }
        float v = acc / (1.f + expf(-acc));   // SiLU
        if (c < DINNER) {
            xs[(size_t)id * DINNER + c] = f2b(v);
        } else if (c < DINNER + DSTATE) {
            Bq[(size_t)id * DSTATE + (c - DINNER)] = v;
        } else {
            Cq[(size_t)id * DSTATE + (c - DINNER - DSTATE)] = v;
        }
    }
    if (tid < NH) {
        const float* dtb = dir ? dtb1 : dtb0;
        const float* al  = dir ? al1 : al0;
        float raw = dtr[(size_t)id * NH + tid] + dtb[tid];
        float dt = raw > 20.f ? raw : log1pf(expf(raw));
        float ldA = -expf(al[tid]) * dt;
        int dirb = id >> 10;
        dtq[(size_t)(dirb * NH + tid) * SEQ + l] = dt;
        ldq[(size_t)(dirb * NH + tid) * SEQ + l] = ldA;
    }
}

// ---------------------------------------------------------------------------
// states_k: chunk-local end state via MFMA.
// ---------------------------------------------------------------------------
__global__ __launch_bounds__(256) void states_k(
    const float* __restrict__ Bq, const float* __restrict__ dtT,
    const float* __restrict__ ldT, const ushort* __restrict__ xsq,
    ushort* __restrict__ cs)
{
    int id = blockIdx.x;
    int h = id & 31;
    int c = blockIdx.y;
    int tid = threadIdx.x;
    int wave = tid >> 6, lane = tid & 63;
    int quad = lane >> 4;
    int base = (id >> 5) << 10;
    int l0 = c * QC;

    __shared__ float wsh[QC];
    __shared__ ushort Xw[64][80];
    __shared__ ushort Bt[64][72];

    if (tid < 64) {
        float ld = ldT[(size_t)id * SEQ + l0 + tid];
        #pragma unroll
        for (int st = 1; st < 64; st <<= 1) {
            float o = __shfl_up(ld, st);
            if (tid >= st) ld += o;
        }
        float tot = __shfl(ld, 63);
        wsh[tid] = dtT[(size_t)id * SEQ + l0 + tid] * expf(tot - ld);
    }
    __syncthreads();

    {
        int j = tid >> 2, p0 = (tid & 3) * 16;
        float wj = wsh[j];
        const ushort* xrow = xsq + (size_t)(base + l0 + j) * DINNER + h * HD + p0;
        #pragma unroll
        for (int q = 0; q < 4; q++) {
            ushort4 xv = *(const ushort4*)(xrow + q * 4);
            Xw[p0 + q * 4 + 0][j] = f2b(b2f(xv.x) * wj);
            Xw[p0 + q * 4 + 1][j] = f2b(b2f(xv.y) * wj);
            Xw[p0 + q * 4 + 2][j] = f2b(b2f(xv.z) * wj);
            Xw[p0 + q * 4 + 3][j] = f2b(b2f(xv.w) * wj);
        }
        int j2 = lane, ng = wave * 16;
        const float* brow = Bq + (size_t)(base + l0 + j2) * DSTATE + ng;
        #pragma unroll
        for (int q = 0; q < 4; q++) {
            float4 f = *(const float4*)(brow + q * 4);
            Bt[ng + q * 4 + 0][j2] = f2b(f.x);
            Bt[ng + q * 4 + 1][j2] = f2b(f.y);
            Bt[ng + q * 4 + 2][j2] = f2b(f.z);
            Bt[ng + q * 4 + 3][j2] = f2b(f.w);
        }
    }
    __syncthreads();

    f32x4 acc[4] = {};
    #pragma unroll
    for (int kt = 0; kt < 2; kt++) {
        int k = kt * 32 + quad * 8;
        bf16x8 af = *(const bf16x8*)&Xw[wave * 16 + (lane & 15)][k];
        #pragma unroll
        for (int ni = 0; ni < 4; ni++) {
            bf16x8 bf = *(const bf16x8*)&Bt[ni * 16 + (lane & 15)][k];
            acc[ni] = __builtin_amdgcn_mfma_f32_16x16x32_bf16(af, bf, acc[ni], 0, 0, 0);
        }
    }

    ushort* out = cs + ((size_t)id * NCHUNK + c) * HD * DSTATE;
    #pragma unroll
    for (int ni = 0; ni < 4; ni++) {
        #pragma unroll
        for (int j = 0; j < 4; j++) {
            int p = wave * 16 + quad * 4 + j;
            int n = ni * 16 + (lane & 15);
            out[(size_t)p * DSTATE + n] = f2b(acc[ni][j]);
        }
    }
}

// ---------------------------------------------------------------------------
// Stitch: H_{c+1} = S_c + exp(sum ldA) * H_c (in place -> chunk-start H_c)
// ---------------------------------------------------------------------------
__global__ __launch_bounds__(256) void stitch_k(
    const float* __restrict__ ldT, ushort* __restrict__ cs)
{
    int id = blockIdx.x;
    int tid = threadIdx.x;
    __shared__ float red[256];
    __shared__ float dec[NCHUNK];

    float4 d4 = *(const float4*)(ldT + (size_t)id * SEQ + tid * 4);
    red[tid] = d4.x + d4.y + d4.z + d4.w;
    __syncthreads();
    if (tid < NCHUNK) {
        float s = 0.f;
        #pragma unroll
        for (int i = 0; i < 16; i++) s += red[tid * 16 + i];
        dec[tid] = expf(s);
    }
    __syncthreads();

    int p = tid >> 2, n0 = (tid & 3) * 16;
    ushort* ptr = cs + (size_t)id * NCHUNK * HD * DSTATE + p * DSTATE + n0;

    float st[16];
    #pragma unroll
    for (int i = 0; i < 16; i++) st[i] = 0.f;

    for (int c = 0; c < NCHUNK; c++) {
        ushort* row = ptr + (size_t)c * HD * DSTATE;
        float tmp[16];
        #pragma unroll
        for (int i = 0; i < 16; i++) tmp[i] = b2f(row[i]);
        #pragma unroll
        for (int i = 0; i < 16; i++) row[i] = f2b(st[i]);
        float d = dec[c];
        #pragma unroll
        for (int i = 0; i < 16; i++) st[i] = fmaf(d, st[i], tmp[i]);
    }
}

// ---------------------------------------------------------------------------
// ssd_k: intra-chunk SSD matmul + seed + D*x
// ---------------------------------------------------------------------------
__global__ __launch_bounds__(256) void ssd_k(
    const float* __restrict__ Bq, const float* __restrict__ Cq,
    const float* __restrict__ dtT, const float* __restrict__ ldT,
    const ushort* __restrict__ xsq, const ushort* __restrict__ cs,
    const float* __restrict__ D0, const float* __restrict__ D1,
    ushort* __restrict__ yout)
{
    int id = blockIdx.x;
    int dir = id >> 6, h = id & 31;
    int c = blockIdx.y;
    int tid = threadIdx.x;
    int wave = tid >> 6, lane = tid & 63;
    int quad = lane >> 4;
    int base = (id >> 5) << 10;
    int l0 = c * QC;

    __shared__ float cum[QC], dts[QC];
    __shared__ ushort Ms[64][72];
    __shared__ ushort Xb[64][80];

    {
        int j = tid >> 2, p0 = (tid & 3) * 16;
        const ushort* xrow = xsq + (size_t)(base + l0 + j) * DINNER + h * HD + p0;
        #pragma unroll
        for (int q = 0; q < 4; q++) {
            ushort4 xv = *(const ushort4*)(xrow + q * 4);
            Xb[p0 + q * 4 + 0][j] = xv.x;
            Xb[p0 + q * 4 + 1][j] = xv.y;
            Xb[p0 + q * 4 + 2][j] = xv.z;
            Xb[p0 + q * 4 + 3][j] = xv.w;
        }
    }
    if (tid < 64) {
        float ld = ldT[(size_t)id * SEQ + l0 + tid];
        #pragma unroll
        for (int st = 1; st < 64; st <<= 1) {
            float o = __shfl_up(ld, st);
            if (tid >= st) ld += o;
        }
        cum[tid] = ld;
        dts[tid] = dtT[(size_t)id * SEQ + l0 + tid];
    }

    f32x4 sacc[4] = {};
    #pragma unroll
    for (int kt = 0; kt < 2; kt++) {
        int k = kt * 32 + quad * 8;
        const float* cp = Cq + (size_t)(base + l0 + wave * 16 + (lane & 15)) * DSTATE + k;
        bf16x8 af = pack8(*(const float4*)cp, *(const float4*)(cp + 4));
        #pragma unroll
        for (int ni = 0; ni < 4; ni++) {
            const float* bp = Bq + (size_t)(base + l0 + ni * 16 + (lane & 15)) * DSTATE + k;
            bf16x8 bf = pack8(*(const float4*)bp, *(const float4*)(bp + 4));
            sacc[ni] = __builtin_amdgcn_mfma_f32_16x16x32_bf16(af, bf, sacc[ni], 0, 0, 0);
        }
    }
    __syncthreads();

    #pragma unroll
    for (int ni = 0; ni < 4; ni++) {
        int j = ni * 16 + (lane & 15);
        float cj = cum[j], dj = dts[j];
        #pragma unroll
        for (int r = 0; r < 4; r++) {
            int l = wave * 16 + quad * 4 + r;
            float v = 0.f;
            if (l >= j) v = expf(cum[l] - cj) * dj * sacc[ni][r];
            Ms[l][j] = f2b(v);
        }
    }
    __syncthreads();

    f32x4 acc[4] = {};
    #pragma unroll
    for (int kt = 0; kt < 2; kt++) {
        int k = kt * 32 + quad * 8;
        bf16x8 af = *(const bf16x8*)&Ms[wave * 16 + (lane & 15)][k];
        #pragma unroll
        for (int ni = 0; ni < 4; ni++) {
            bf16x8 bf = *(const bf16x8*)&Xb[ni * 16 + (lane & 15)][k];
            acc[ni] = __builtin_amdgcn_mfma_f32_16x16x32_bf16(af, bf, acc[ni], 0, 0, 0);
        }
    }
    const ushort* Hrow = cs + ((size_t)id * NCHUNK + c) * HD * DSTATE;
    {
        float cl = expf(cum[wave * 16 + (lane & 15)]);
        #pragma unroll
        for (int kt = 0; kt < 2; kt++) {
            int k = kt * 32 + quad * 8;
            const float* cp = Cq + (size_t)(base + l0 + wave * 16 + (lane & 15)) * DSTATE + k;
            float4 c0 = *(const float4*)cp;
            float4 c1 = *(const float4*)(cp + 4);
            float4 s0 = {c0.x * cl, c0.y * cl, c0.z * cl, c0.w * cl};
            float4 s1 = {c1.x * cl, c1.y * cl, c1.z * cl, c1.w * cl};
            bf16x8 af = pack8(s0, s1);
            #pragma unroll
            for (int ni = 0; ni < 4; ni++) {
                bf16x8 bf = *(const bf16x8*)(Hrow + (size_t)(ni * 16 + (lane & 15)) * DSTATE + k);
                acc[ni] = __builtin_amdgcn_mfma_f32_16x16x32_bf16(af, bf, acc[ni], 0, 0, 0);
            }
        }
    }

    float Dv = (dir ? D1 : D0)[h];
    int lb = wave * 16 + quad * 4;
    #pragma unroll
    for (int ni = 0; ni < 4; ni++) {
        int p = ni * 16 + (lane & 15);
        ushort4 x4 = *(const ushort4*)&Xb[p][lb];
        float xv[4] = { b2f(x4.x), b2f(x4.y), b2f(x4.z), b2f(x4.w) };
        #pragma unroll
        for (int r = 0; r < 4; r++) {
            int l = lb + r;
            yout[(size_t)(base + l0 + l) * DPROJ + 2048 + h * HD + p] =
                f2b(acc[ni][r] + Dv * xv[r]);
        }
    }
}

// ---------------------------------------------------------------------------
// gated RMSNorm
// ---------------------------------------------------------------------------
__global__ __launch_bounds__(256) void grms_k(
    const ushort* __restrict__ zx,
    const float* __restrict__ rw0, const float* __restrict__ rw1,
    ushort* __restrict__ yn)
{
    int id = blockIdx.x;
    int dir = id >> 11;
    const float* rw = dir ? rw1 : rw0;
    int tid = threadIdx.x;
    float g[8];
    float ss = 0.f;
    #pragma unroll
    for (int i = 0; i < 8; i++) {
        int c = i * 256 + tid;
        float z  = b2f(zx[(size_t)id * DPROJ + c]);
        float yv = b2f(zx[(size_t)id * DPROJ + 2048 + c]);
        float v = yv * (z / (1.f + expf(-z)));
        g[i] = v;
        ss += v * v;
    }
    for (int o = 32; o; o >>= 1) ss += __shfl_down(ss, o);
    __shared__ float t4[4];
    if ((tid & 63) == 0) t4[tid >> 6] = ss;
    __syncthreads();
    ss = t4[0] + t4[1] + t4[2] + t4[3];
    float sc = rsqrtf(ss * (1.f / DINNER) + 1e-5f);
    #pragma unroll
    for (int i = 0; i < 8; i++) {
        int c = i * 256 + tid;
        yn[(size_t)id * DINNER + c] = f2b(g[i] * sc * rw[c]);
    }
}

// ---------------------------------------------------------------------------
// LayerNorm -> fp32 out
// ---------------------------------------------------------------------------
__global__ __launch_bounds__(256) void ln_k(
    const float* __restrict__ h, const float* __restrict__ lw,
    const float* __restrict__ lb, float* __restrict__ out)
{
    int m = blockIdx.x;
    int tid = threadIdx.x;
    float v[4];
    float s = 0.f, s2 = 0.f;
    #pragma unroll
    for (int i = 0; i < 4; i++) {
        int c = i * 256 + tid;
        v[i] = h[(size_t)m * DMODEL + c];
        s += v[i];
        s2 += v[i] * v[i];
    }
    for (int o = 32; o; o >>= 1) { s += __shfl_down(s, o); s2 += __shfl_down(s2, o); }
    __shared__ float ts[4], ts2[4];
    if ((tid & 63) == 0) { ts[tid >> 6] = s; ts2[tid >> 6] = s2; }
    __syncthreads();
    s  = ts[0] + ts[1] + ts[2] + ts[3];
    s2 = ts2[0] + ts2[1] + ts2[2] + ts2[3];
    float mu  = s * (1.f / DMODEL);
    float var = s2 * (1.f / DMODEL) - mu * mu;
    float sc  = rsqrtf(var + 1e-5f);
    #pragma unroll
    for (int i = 0; i < 4; i++) {
        int c = i * 256 + tid;
        out[(size_t)m * DMODEL + c] = (v[i] - mu) * sc * lw[c] + lb[c];
    }
}

extern "C" void kernel_launch(void* const* d_in, const int* in_sizes, int n_in,
                              void* d_out, int out_size, void* d_ws, size_t ws_size,
                              hipStream_t stream)
{
    const float* x     = (const float*)d_in[0];
    const float* f_inw = (const float*)d_in[1];
    const float* f_cw  = (const float*)d_in[2];
    const float* f_cb  = (const float*)d_in[3];
    const float* f_dtb = (const float*)d_in[4];
    const float* f_al  = (const float*)d_in[5];
    const float* f_Dp  = (const float*)d_in[6];
    const float* f_rw  = (const float*)d_in[7];
    const float* f_ow  = (const float*)d_in[8];
    const float* b_inw = (const float*)d_in[9];
    const float* b_cw  = (const float*)d_in[10];
    const float* b_cb  = (const float*)d_in[11];
    const float* b_dtb = (const float*)d_in[12];
    const float* b_al  = (const float*)d_in[13];
    const float* b_Dp  = (const float*)d_in[14];
    const float* b_rw  = (const float*)d_in[15];
    const float* b_ow  = (const float*)d_in[16];
    const float* projw = (const float*)d_in[17];
    const float* projb = (const float*)d_in[18];
    const float* lnw   = (const float*)d_in[19];
    const float* lnb   = (const float*)d_in[20];

    char* ws = (char*)d_ws;
    ushort* zx  = (ushort*)(ws + OFF_ZX);
    ushort* xs  = (ushort*)(ws + OFF_XS);
    float*  Bq  = (float*)(ws + OFF_BB);
    float*  Cq  = (float*)(ws + OFF_CC);
    float*  dtq = (float*)(ws + OFF_DT);
    float*  ldq = (float*)(ws + OFF_DA);
    float*  dtr = (float*)(ws + OFF_DR);
    ushort* wbf = (ushort*)(ws + OFF_CS);
    ushort* cs  = (ushort*)(ws + OFF_CS);
    ushort* xbf = (ushort*)(ws + OFF_XS);   // x bf16, dead once conv_k writes xs
    ushort* yn  = (ushort*)(ws + OFF_XS);   // aliases xs (dead after ssd)
    ushort* dd  = (ushort*)(ws + OFF_DD);   // aliases zx (dead after grms)
    float*  hb  = (float*)(ws + OFF_H);
    ushort* wo  = (ushort*)(ws + OFF_WO);
    ushort* wp  = (ushort*)(ws + OFF_WP);

    // K0: bf16 conversions needed before in_proj
    cvt_k<<<dim3(DPROJ), 256, 0, stream>>>(f_inw, wbf);
    cvt_k<<<dim3(DPROJ), 256, 0, stream>>>(b_inw, wbf + (size_t)DPROJ * DMODEL);
    cvt_k<<<dim3(MROWS), 256, 0, stream>>>(x, xbf);

    // K1: in_proj, N=4256, K=1024, BN=128
    gemm_k<0, 128><<<dim3((DPROJ + 127) / 128, MROWS / 128, 2), 256, 0, stream>>>(
        xbf, wbf, (size_t)DPROJ * DMODEL, (void*)zx, nullptr, nullptr, dtr,
        DPROJ, DMODEL);

    // K2: conv + activations (overwrites xbf region with xs)
    conv_k<<<dim3(2 * MROWS), 256, 0, stream>>>(
        zx, dtr, f_cw, f_cb, b_cw, b_cb, f_dtb, f_al, b_dtb, b_al,
        xs, Bq, Cq, dtq, ldq);

    // K3: chunked SSD (states / stitch / intra-chunk matmul)
    states_k<<<dim3(128, NCHUNK), 256, 0, stream>>>(Bq, dtq, ldq, xs, cs);
    stitch_k<<<dim3(128), 256, 0, stream>>>(ldq, cs);
    ssd_k<<<dim3(128, NCHUNK), 256, 0, stream>>>(
        Bq, Cq, dtq, ldq, xs, cs, f_Dp, b_Dp, zx);

    // K4: gated RMSNorm (last reader of zx)
    grms_k<<<dim3(2 * MROWS), 256, 0, stream>>>(zx, f_rw, b_rw, yn);

    // K4b: convert out_proj/final weights into dead zx region
    cvt_k<<<dim3(MROWS), 256, 0, stream>>>(f_ow, wo);
    cvt_k<<<dim3(MROWS), 256, 0, stream>>>(b_ow, wo + (size_t)DMODEL * DINNER);
    cvt_k<<<dim3(MROWS), 256, 0, stream>>>(projw, wp);

    // K5: out_proj, N=1024, K=2048, BN=64; packs [dou0 | flip(dou1)] into dd
    gemm_k<1, 64><<<dim3(DMODEL / 64, MROWS / 128, 2), 256, 0, stream>>>(
        yn, wo, (size_t)DMODEL * DINNER, (void*)dd, nullptr, nullptr, nullptr,
        DMODEL, DINNER);

    // K6: final proj + residual + bias, N=1024, K=2048 (fp32 out)
    gemm_k<2, 64><<<dim3(DMODEL / 64, MROWS / 128, 1), 256, 0, stream>>>(
        dd, wp, 0, (void*)hb, x, projb, nullptr, DMODEL, DINNER);

    // K7: LayerNorm -> fp32 out
    ln_k<<<dim3(MROWS), 256, 0, stream>>>(hb, lnw, lnb, (float*)d_out);
}

// Round 10
// 389.125 us; speedup vs baseline: 2.6670x; 1.0174x over previous
//
#include <hip/hip_runtime.h>
#include <hip/hip_bf16.h>

#define DEV __device__ __forceinline__

typedef short bf16x8 __attribute__((ext_vector_type(8)));
typedef float f32x4 __attribute__((ext_vector_type(4)));

static constexpr int BATCH  = 2;
static constexpr int SEQ    = 1024;
static constexpr int DMODEL = 1024;
static constexpr int DINNER = 2048;
static constexpr int DSTATE = 64;
static constexpr int NH     = 32;
static constexpr int HD     = 64;
static constexpr int CONVD  = 2176;
static constexpr int DPROJ  = 4256;
static constexpr int MROWS  = BATCH * SEQ;   // 2048
static constexpr int NCHUNK = 16;
static constexpr int QC     = 64;

// ---- workspace layout (bytes) ---- peak 74.8 MB (proven)
static constexpr size_t OFF_ZX = 0;                                  // bf16 [4096][4256]
static constexpr size_t OFF_XS = OFF_ZX + (size_t)2*MROWS*DPROJ*2;   // bf16 [4096][2048]; xbf pre-conv, xs after, yn after ssd
static constexpr size_t OFF_BB = OFF_XS + (size_t)2*MROWS*DINNER*2;  // f32 [4096][64]
static constexpr size_t OFF_CC = OFF_BB + (size_t)2*MROWS*DSTATE*4;  // f32 [4096][64]
static constexpr size_t OFF_DT = OFF_CC + (size_t)2*MROWS*DSTATE*4;  // f32 [4][32][1024] dt
static constexpr size_t OFF_DA = OFF_DT + (size_t)2*MROWS*NH*4;      // f32 [4][32][1024] ldA
static constexpr size_t OFF_DR = OFF_DA + (size_t)2*MROWS*NH*4;      // f32 [4096][32] raw dt spill
// CS: time-shared (a) bf16 in_proj weights [2][4256][1024]  (b) chunk states
static constexpr size_t OFF_CS = OFF_DR + (size_t)2*MROWS*NH*4;
// aliased into zx (dead after grms):
static constexpr size_t OFF_DD = 0;                                  // bf16 [2048][2048] packed dir outs
static constexpr size_t OFF_H  = OFF_DD + (size_t)MROWS*2*DMODEL;    // f32 [2048][1024]
static constexpr size_t OFF_WO = OFF_H  + (size_t)MROWS*DMODEL*4;    // bf16 [2][1024][2048]
static constexpr size_t OFF_WP = OFF_WO + (size_t)2*DMODEL*DINNER*2; // bf16 [1024][2048]

DEV float b2f(ushort u) {
    union { unsigned int i; float f; } v;
    v.i = ((unsigned int)u) << 16;
    return v.f;
}
DEV ushort f2b(float f) {
    union { float f; unsigned int u; } v;
    v.f = f;
    unsigned int r = 0x7FFFu + ((v.u >> 16) & 1u);
    return (ushort)((v.u + r) >> 16);
}
DEV bf16x8 pack8(float4 a, float4 b) {
    bf16x8 r;
    r[0] = (short)f2b(a.x); r[1] = (short)f2b(a.y);
    r[2] = (short)f2b(a.z); r[3] = (short)f2b(a.w);
    r[4] = (short)f2b(b.x); r[5] = (short)f2b(b.y);
    r[6] = (short)f2b(b.z); r[7] = (short)f2b(b.w);
    return r;
}
DEV void gll16(const ushort* g, ushort* l) {
    __builtin_amdgcn_global_load_lds(
        (const __attribute__((address_space(1))) unsigned int*)g,
        (__attribute__((address_space(3))) unsigned int*)l, 16, 0, 0);
}

// ---------------------------------------------------------------------------
// cvt3: three fp32->bf16 conversions in one launch (rows of 1024 floats).
// ---------------------------------------------------------------------------
__global__ __launch_bounds__(256) void cvt3_k(
    const float* __restrict__ s0, const float* __restrict__ s1,
    const float* __restrict__ s2,
    ushort* __restrict__ d0, ushort* __restrict__ d1, ushort* __restrict__ d2,
    int b0, int b1)
{
    int blk = blockIdx.x;
    const float* s; ushort* d; size_t off;
    if (blk < b0)            { s = s0; d = d0; off = (size_t)blk * 1024; }
    else if (blk < b0 + b1)  { s = s1; d = d1; off = (size_t)(blk - b0) * 1024; }
    else                     { s = s2; d = d2; off = (size_t)(blk - b0 - b1) * 1024; }
    size_t i = off + threadIdx.x * 4;
    float4 f = *(const float4*)(s + i);
    ushort4 u;
    u.x = f2b(f.x); u.y = f2b(f.y); u.z = f2b(f.z); u.w = f2b(f.w);
    *(ushort4*)(d + i) = u;
}

// ---------------------------------------------------------------------------
// GEMM (m97-style): C[m][n] = sum_k A[m][k]*W[n][k], all bf16,
// global_load_lds width-16 staging + XOR bank swizzle, BM=128, BK=32.
// MODE 0: bn tiles remapped (bx+2*by)%gridX for XCD-stable W partition.
// ---------------------------------------------------------------------------
template<int MODE, int BN>
__global__ __launch_bounds__(256) void gemm_k(
    const ushort* __restrict__ A, const ushort* __restrict__ W,
    size_t wstride, void* __restrict__ outp, const float* __restrict__ resid,
    const float* __restrict__ bias, float* __restrict__ dtraw,
    int N, int K)
{
    constexpr int BM = 128, BK = 32;
    constexpr int MT = (BN == 128) ? 4 : 2;
    constexpr int NBL = (BN == 128) ? 2 : 1;
    __shared__ ushort As[BM * BK];
    __shared__ ushort Bs[BN * BK];
    const int tid = threadIdx.x;
    const int wave = tid >> 6, lane = tid & 63;
    const int quad = lane >> 4, l16 = lane & 15;
    // MODE0: keep each XCD's bn set constant across bm rows (34 ≡ 2 mod 8)
    const int bxu = (MODE == 0)
        ? (int)((blockIdx.x + 2 * blockIdx.y) % gridDim.x) : (int)blockIdx.x;
    const int bn = bxu * BN, bm = blockIdx.y * BM;
    const int dir = blockIdx.z;
    const ushort* Wd = W + (size_t)dir * wstride;
    const int wmoff = (BN == 128) ? (wave >> 1) * 64 : wave * 32;
    const int wnoff = (BN == 128) ? (wave & 1) * 64 : 0;

    // staging: lane -> row li*16 + (lane>>2), global colgroup XOR-swizzled so
    // LDS slot (r, lane&3) holds cg = (lane&3)^(r&3)^((r>>2)&3). LDS dest is
    // wave-uniform base (HW adds lane*16B).
    const int scg = ((lane & 3) ^ ((lane >> 2) & 3) ^ ((lane >> 4) & 3)) * 8;
    const ushort* aga[2];
    ushort* ald[2];
    #pragma unroll
    for (int t = 0; t < 2; t++) {
        int li = wave * 2 + t;
        int r = li * 16 + (lane >> 2);
        int m = bm + r;
        size_t rowidx;
        if (MODE == 0) {
            int b = m >> 10, l = m & 1023;
            int ls = dir ? (1023 - l) : l;
            rowidx = (size_t)((b << 10) + ls);
        } else if (MODE == 1) {
            rowidx = (size_t)(dir * MROWS + m);
        } else {
            rowidx = (size_t)m;
        }
        aga[t] = A + rowidx * K + scg;
        ald[t] = &As[li * 512];
    }
    const ushort* bga[NBL];
    ushort* bld[NBL];
    #pragma unroll
    for (int t = 0; t < NBL; t++) {
        int li = wave * NBL + t;
        int n = bn + li * 16 + (lane >> 2);
        if (n >= N) n = N - 1;            // clamp; cols >= N discarded
        bga[t] = Wd + (size_t)n * K + scg;
        bld[t] = &Bs[li * 512];
    }

    // read-side swizzled column slot: s = quad ^ (l16&3) ^ ((l16>>2)&3)
    const int rs = (quad ^ (l16 & 3) ^ ((l16 >> 2) & 3)) * 8;

    f32x4 acc[MT][4] = {};

    for (int k0 = 0; k0 < K; k0 += BK) {
        #pragma unroll
        for (int t = 0; t < 2; t++) gll16(aga[t] + k0, ald[t]);
        #pragma unroll
        for (int t = 0; t < NBL; t++) gll16(bga[t] + k0, bld[t]);
        __syncthreads();

        bf16x8 af[MT], bfr[4];
        #pragma unroll
        for (int mt = 0; mt < MT; mt++)
            af[mt] = *(const bf16x8*)&As[(wmoff + mt * 16 + l16) * BK + rs];
        #pragma unroll
        for (int nt = 0; nt < 4; nt++)
            bfr[nt] = *(const bf16x8*)&Bs[(wnoff + nt * 16 + l16) * BK + rs];
        #pragma unroll
        for (int mt = 0; mt < MT; mt++)
            #pragma unroll
            for (int nt = 0; nt < 4; nt++)
                acc[mt][nt] = __builtin_amdgcn_mfma_f32_16x16x32_bf16(
                    af[mt], bfr[nt], acc[mt][nt], 0, 0, 0);
        __syncthreads();
    }

    // epilogue: C/D layout row=quad*4+j, col=l16
    #pragma unroll
    for (int mt = 0; mt < MT; mt++) {
        #pragma unroll
        for (int nt = 0; nt < 4; nt++) {
            #pragma unroll
            for (int j = 0; j < 4; j++) {
                int row = bm + wmoff + mt * 16 + quad * 4 + j;
                int col = bn + wnoff + nt * 16 + l16;
                if (col >= N) continue;
                float v = acc[mt][nt][j];
                if (MODE == 0) {
                    ((ushort*)outp)[(size_t)(dir * MROWS + row) * DPROJ + col] = f2b(v);
                    if (col >= 4224)
                        dtraw[(size_t)(dir * MROWS + row) * NH + (col - 4224)] = v;
                } else if (MODE == 1) {
                    int mr = dir ? ((row & 1024) | (1023 - (row & 1023))) : row;
                    ((ushort*)outp)[(size_t)mr * (2 * DMODEL) + dir * DMODEL + col] = f2b(v);
                } else {
                    float r = resid[(size_t)row * DMODEL + col] + bias[col];
                    ((float*)outp)[(size_t)row * DMODEL + col] = v + r;
                }
            }
        }
    }
}

// ---------------------------------------------------------------------------
// causal depthwise conv(width 4) + bias + SiLU; dt = softplus(raw+bias);
// ldA = A*dt (log decay). dt/ldA TRANSPOSED: [dirb*32+h][l]
// ---------------------------------------------------------------------------
__global__ __launch_bounds__(256) void conv_k(
    const ushort* __restrict__ zx, const float* __restrict__ dtr,
    const float* __restrict__ cw0, const float* __restrict__ cb0,
    const float* __restrict__ cw1, const float* __restrict__ cb1,
    const float* __restrict__ dtb0, const float* __restrict__ al0,
    const float* __restrict__ dtb1, const float* __restrict__ al1,
    ushort* __restrict__ xs, float* __restrict__ Bq, float* __restrict__ Cq,
    float* __restrict__ dtq, float* __restrict__ ldq)
{
    int id = blockIdx.x;
    int dir = id >> 11;
    int m = id & 2047;
    int l = m & 1023;
    const float* cw = dir ? cw1 : cw0;
    const float* cb = dir ? cb1 : cb0;
    int tid = threadIdx.x;

    for (int c = tid; c < CONVD; c += 256) {
        float acc = cb[c];
        #pragma unroll
        for (int t = 0; t < 4; t++) {
            int ls = l - 3 + t;
            if (ls >= 0) {
                acc += cw[t * CONVD + c] *
                       b2f(zx[(size_t)(id - l + ls) * DPROJ + 2048 + c]);
            }
        }
        float v = acc / (1.f + expf(-acc));   // SiLU
        if (c < DINNER) {
            xs[(size_t)id * DINNER + c] = f2b(v);
        } else if (c < DINNER + DSTATE) {
            Bq[(size_t)id * DSTATE + (c - DINNER)] = v;
        } else {
            Cq[(size_t)id * DSTATE + (c - DINNER - DSTATE)] = v;
        }
    }
    if (tid < NH) {
        const float* dtb = dir ? dtb1 : dtb0;
        const float* al  = dir ? al1 : al0;
        float raw = dtr[(size_t)id * NH + tid] + dtb[tid];
        float dt = raw > 20.f ? raw : log1pf(expf(raw));
        float ldA = -expf(al[tid]) * dt;
        int dirb = id >> 10;
        dtq[(size_t)(dirb * NH + tid) * SEQ + l] = dt;
        ldq[(size_t)(dirb * NH + tid) * SEQ + l] = ldA;
    }
}

// ---------------------------------------------------------------------------
// states_k: chunk-local end state via MFMA.
// ---------------------------------------------------------------------------
__global__ __launch_bounds__(256) void states_k(
    const float* __restrict__ Bq, const float* __restrict__ dtT,
    const float* __restrict__ ldT, const ushort* __restrict__ xsq,
    ushort* __restrict__ cs)
{
    int id = blockIdx.x;
    int h = id & 31;
    int c = blockIdx.y;
    int tid = threadIdx.x;
    int wave = tid >> 6, lane = tid & 63;
    int quad = lane >> 4;
    int base = (id >> 5) << 10;
    int l0 = c * QC;

    __shared__ float wsh[QC];
    __shared__ ushort Xw[64][80];
    __shared__ ushort Bt[64][72];

    if (tid < 64) {
        float ld = ldT[(size_t)id * SEQ + l0 + tid];
        #pragma unroll
        for (int st = 1; st < 64; st <<= 1) {
            float o = __shfl_up(ld, st);
            if (tid >= st) ld += o;
        }
        float tot = __shfl(ld, 63);
        wsh[tid] = dtT[(size_t)id * SEQ + l0 + tid] * expf(tot - ld);
    }
    __syncthreads();

    {
        int j = tid >> 2, p0 = (tid & 3) * 16;
        float wj = wsh[j];
        const ushort* xrow = xsq + (size_t)(base + l0 + j) * DINNER + h * HD + p0;
        #pragma unroll
        for (int q = 0; q < 4; q++) {
            ushort4 xv = *(const ushort4*)(xrow + q * 4);
            Xw[p0 + q * 4 + 0][j] = f2b(b2f(xv.x) * wj);
            Xw[p0 + q * 4 + 1][j] = f2b(b2f(xv.y) * wj);
            Xw[p0 + q * 4 + 2][j] = f2b(b2f(xv.z) * wj);
            Xw[p0 + q * 4 + 3][j] = f2b(b2f(xv.w) * wj);
        }
        int j2 = lane, ng = wave * 16;
        const float* brow = Bq + (size_t)(base + l0 + j2) * DSTATE + ng;
        #pragma unroll
        for (int q = 0; q < 4; q++) {
            float4 f = *(const float4*)(brow + q * 4);
            Bt[ng + q * 4 + 0][j2] = f2b(f.x);
            Bt[ng + q * 4 + 1][j2] = f2b(f.y);
            Bt[ng + q * 4 + 2][j2] = f2b(f.z);
            Bt[ng + q * 4 + 3][j2] = f2b(f.w);
        }
    }
    __syncthreads();

    f32x4 acc[4] = {};
    #pragma unroll
    for (int kt = 0; kt < 2; kt++) {
        int k = kt * 32 + quad * 8;
        bf16x8 af = *(const bf16x8*)&Xw[wave * 16 + (lane & 15)][k];
        #pragma unroll
        for (int ni = 0; ni < 4; ni++) {
            bf16x8 bf = *(const bf16x8*)&Bt[ni * 16 + (lane & 15)][k];
            acc[ni] = __builtin_amdgcn_mfma_f32_16x16x32_bf16(af, bf, acc[ni], 0, 0, 0);
        }
    }

    ushort* out = cs + ((size_t)id * NCHUNK + c) * HD * DSTATE;
    #pragma unroll
    for (int ni = 0; ni < 4; ni++) {
        #pragma unroll
        for (int j = 0; j < 4; j++) {
            int p = wave * 16 + quad * 4 + j;
            int n = ni * 16 + (lane & 15);
            out[(size_t)p * DSTATE + n] = f2b(acc[ni][j]);
        }
    }
}

// ---------------------------------------------------------------------------
// Stitch: H_{c+1} = S_c + exp(sum ldA) * H_c (in place -> chunk-start H_c)
// ---------------------------------------------------------------------------
__global__ __launch_bounds__(256) void stitch_k(
    const float* __restrict__ ldT, ushort* __restrict__ cs)
{
    int id = blockIdx.x;
    int tid = threadIdx.x;
    __shared__ float red[256];
    __shared__ float dec[NCHUNK];

    float4 d4 = *(const float4*)(ldT + (size_t)id * SEQ + tid * 4);
    red[tid] = d4.x + d4.y + d4.z + d4.w;
    __syncthreads();
    if (tid < NCHUNK) {
        float s = 0.f;
        #pragma unroll
        for (int i = 0; i < 16; i++) s += red[tid * 16 + i];
        dec[tid] = expf(s);
    }
    __syncthreads();

    int p = tid >> 2, n0 = (tid & 3) * 16;
    ushort* ptr = cs + (size_t)id * NCHUNK * HD * DSTATE + p * DSTATE + n0;

    float st[16];
    #pragma unroll
    for (int i = 0; i < 16; i++) st[i] = 0.f;

    for (int c = 0; c < NCHUNK; c++) {
        ushort* row = ptr + (size_t)c * HD * DSTATE;
        float tmp[16];
        #pragma unroll
        for (int i = 0; i < 16; i++) tmp[i] = b2f(row[i]);
        #pragma unroll
        for (int i = 0; i < 16; i++) row[i] = f2b(st[i]);
        float d = dec[c];
        #pragma unroll
        for (int i = 0; i < 16; i++) st[i] = fmaf(d, st[i], tmp[i]);
    }
}

// ---------------------------------------------------------------------------
// ssd_k: intra-chunk SSD matmul + seed + D*x
// ---------------------------------------------------------------------------
__global__ __launch_bounds__(256) void ssd_k(
    const float* __restrict__ Bq, const float* __restrict__ Cq,
    const float* __restrict__ dtT, const float* __restrict__ ldT,
    const ushort* __restrict__ xsq, const ushort* __restrict__ cs,
    const float* __restrict__ D0, const float* __restrict__ D1,
    ushort* __restrict__ yout)
{
    int id = blockIdx.x;
    int dir = id >> 6, h = id & 31;
    int c = blockIdx.y;
    int tid = threadIdx.x;
    int wave = tid >> 6, lane = tid & 63;
    int quad = lane >> 4;
    int base = (id >> 5) << 10;
    int l0 = c * QC;

    __shared__ float cum[QC], dts[QC];
    __shared__ ushort Ms[64][72];
    __shared__ ushort Xb[64][80];

    {
        int j = tid >> 2, p0 = (tid & 3) * 16;
        const ushort* xrow = xsq + (size_t)(base + l0 + j) * DINNER + h * HD + p0;
        #pragma unroll
        for (int q = 0; q < 4; q++) {
            ushort4 xv = *(const ushort4*)(xrow + q * 4);
            Xb[p0 + q * 4 + 0][j] = xv.x;
            Xb[p0 + q * 4 + 1][j] = xv.y;
            Xb[p0 + q * 4 + 2][j] = xv.z;
            Xb[p0 + q * 4 + 3][j] = xv.w;
        }
    }
    if (tid < 64) {
        float ld = ldT[(size_t)id * SEQ + l0 + tid];
        #pragma unroll
        for (int st = 1; st < 64; st <<= 1) {
            float o = __shfl_up(ld, st);
            if (tid >= st) ld += o;
        }
        cum[tid] = ld;
        dts[tid] = dtT[(size_t)id * SEQ + l0 + tid];
    }

    f32x4 sacc[4] = {};
    #pragma unroll
    for (int kt = 0; kt < 2; kt++) {
        int k = kt * 32 + quad * 8;
        const float* cp = Cq + (size_t)(base + l0 + wave * 16 + (lane & 15)) * DSTATE + k;
        bf16x8 af = pack8(*(const float4*)cp, *(const float4*)(cp + 4));
        #pragma unroll
        for (int ni = 0; ni < 4; ni++) {
            const float* bp = Bq + (size_t)(base + l0 + ni * 16 + (lane & 15)) * DSTATE + k;
            bf16x8 bf = pack8(*(const float4*)bp, *(const float4*)(bp + 4));
            sacc[ni] = __builtin_amdgcn_mfma_f32_16x16x32_bf16(af, bf, sacc[ni], 0, 0, 0);
        }
    }
    __syncthreads();

    #pragma unroll
    for (int ni = 0; ni < 4; ni++) {
        int j = ni * 16 + (lane & 15);
        float cj = cum[j], dj = dts[j];
        #pragma unroll
        for (int r = 0; r < 4; r++) {
            int l = wave * 16 + quad * 4 + r;
            float v = 0.f;
            if (l >= j) v = expf(cum[l] - cj) * dj * sacc[ni][r];
            Ms[l][j] = f2b(v);
        }
    }
    __syncthreads();

    f32x4 acc[4] = {};
    #pragma unroll
    for (int kt = 0; kt < 2; kt++) {
        int k = kt * 32 + quad * 8;
        bf16x8 af = *(const bf16x8*)&Ms[wave * 16 + (lane & 15)][k];
        #pragma unroll
        for (int ni = 0; ni < 4; ni++) {
            bf16x8 bf = *(const bf16x8*)&Xb[ni * 16 + (lane & 15)][k];
            acc[ni] = __builtin_amdgcn_mfma_f32_16x16x32_bf16(af, bf, acc[ni], 0, 0, 0);
        }
    }
    const ushort* Hrow = cs + ((size_t)id * NCHUNK + c) * HD * DSTATE;
    {
        float cl = expf(cum[wave * 16 + (lane & 15)]);
        #pragma unroll
        for (int kt = 0; kt < 2; kt++) {
            int k = kt * 32 + quad * 8;
            const float* cp = Cq + (size_t)(base + l0 + wave * 16 + (lane & 15)) * DSTATE + k;
            float4 c0 = *(const float4*)cp;
            float4 c1 = *(const float4*)(cp + 4);
            float4 s0 = {c0.x * cl, c0.y * cl, c0.z * cl, c0.w * cl};
            float4 s1 = {c1.x * cl, c1.y * cl, c1.z * cl, c1.w * cl};
            bf16x8 af = pack8(s0, s1);
            #pragma unroll
            for (int ni = 0; ni < 4; ni++) {
                bf16x8 bf = *(const bf16x8*)(Hrow + (size_t)(ni * 16 + (lane & 15)) * DSTATE + k);
                acc[ni] = __builtin_amdgcn_mfma_f32_16x16x32_bf16(af, bf, acc[ni], 0, 0, 0);
            }
        }
    }

    float Dv = (dir ? D1 : D0)[h];
    int lb = wave * 16 + quad * 4;
    #pragma unroll
    for (int ni = 0; ni < 4; ni++) {
        int p = ni * 16 + (lane & 15);
        ushort4 x4 = *(const ushort4*)&Xb[p][lb];
        float xv[4] = { b2f(x4.x), b2f(x4.y), b2f(x4.z), b2f(x4.w) };
        #pragma unroll
        for (int r = 0; r < 4; r++) {
            int l = lb + r;
            yout[(size_t)(base + l0 + l) * DPROJ + 2048 + h * HD + p] =
                f2b(acc[ni][r] + Dv * xv[r]);
        }
    }
}

// ---------------------------------------------------------------------------
// gated RMSNorm
// ---------------------------------------------------------------------------
__global__ __launch_bounds__(256) void grms_k(
    const ushort* __restrict__ zx,
    const float* __restrict__ rw0, const float* __restrict__ rw1,
    ushort* __restrict__ yn)
{
    int id = blockIdx.x;
    int dir = id >> 11;
    const float* rw = dir ? rw1 : rw0;
    int tid = threadIdx.x;
    float g[8];
    float ss = 0.f;
    #pragma unroll
    for (int i = 0; i < 8; i++) {
        int c = i * 256 + tid;
        float z  = b2f(zx[(size_t)id * DPROJ + c]);
        float yv = b2f(zx[(size_t)id * DPROJ + 2048 + c]);
        float v = yv * (z / (1.f + expf(-z)));
        g[i] = v;
        ss += v * v;
    }
    for (int o = 32; o; o >>= 1) ss += __shfl_down(ss, o);
    __shared__ float t4[4];
    if ((tid & 63) == 0) t4[tid >> 6] = ss;
    __syncthreads();
    ss = t4[0] + t4[1] + t4[2] + t4[3];
    float sc = rsqrtf(ss * (1.f / DINNER) + 1e-5f);
    #pragma unroll
    for (int i = 0; i < 8; i++) {
        int c = i * 256 + tid;
        yn[(size_t)id * DINNER + c] = f2b(g[i] * sc * rw[c]);
    }
}

// ---------------------------------------------------------------------------
// LayerNorm -> fp32 out
// ---------------------------------------------------------------------------
__global__ __launch_bounds__(256) void ln_k(
    const float* __restrict__ h, const float* __restrict__ lw,
    const float* __restrict__ lb, float* __restrict__ out)
{
    int m = blockIdx.x;
    int tid = threadIdx.x;
    float v[4];
    float s = 0.f, s2 = 0.f;
    #pragma unroll
    for (int i = 0; i < 4; i++) {
        int c = i * 256 + tid;
        v[i] = h[(size_t)m * DMODEL + c];
        s += v[i];
        s2 += v[i] * v[i];
    }
    for (int o = 32; o; o >>= 1) { s += __shfl_down(s, o); s2 += __shfl_down(s2, o); }
    __shared__ float ts[4], ts2[4];
    if ((tid & 63) == 0) { ts[tid >> 6] = s; ts2[tid >> 6] = s2; }
    __syncthreads();
    s  = ts[0] + ts[1] + ts[2] + ts[3];
    s2 = ts2[0] + ts2[1] + ts2[2] + ts2[3];
    float mu  = s * (1.f / DMODEL);
    float var = s2 * (1.f / DMODEL) - mu * mu;
    float sc  = rsqrtf(var + 1e-5f);
    #pragma unroll
    for (int i = 0; i < 4; i++) {
        int c = i * 256 + tid;
        out[(size_t)m * DMODEL + c] = (v[i] - mu) * sc * lw[c] + lb[c];
    }
}

extern "C" void kernel_launch(void* const* d_in, const int* in_sizes, int n_in,
                              void* d_out, int out_size, void* d_ws, size_t ws_size,
                              hipStream_t stream)
{
    const float* x     = (const float*)d_in[0];
    const float* f_inw = (const float*)d_in[1];
    const float* f_cw  = (const float*)d_in[2];
    const float* f_cb  = (const float*)d_in[3];
    const float* f_dtb = (const float*)d_in[4];
    const float* f_al  = (const float*)d_in[5];
    const float* f_Dp  = (const float*)d_in[6];
    const float* f_rw  = (const float*)d_in[7];
    const float* f_ow  = (const float*)d_in[8];
    const float* b_inw = (const float*)d_in[9];
    const float* b_cw  = (const float*)d_in[10];
    const float* b_cb  = (const float*)d_in[11];
    const float* b_dtb = (const float*)d_in[12];
    const float* b_al  = (const float*)d_in[13];
    const float* b_Dp  = (const float*)d_in[14];
    const float* b_rw  = (const float*)d_in[15];
    const float* b_ow  = (const float*)d_in[16];
    const float* projw = (const float*)d_in[17];
    const float* projb = (const float*)d_in[18];
    const float* lnw   = (const float*)d_in[19];
    const float* lnb   = (const float*)d_in[20];

    char* ws = (char*)d_ws;
    ushort* zx  = (ushort*)(ws + OFF_ZX);
    ushort* xs  = (ushort*)(ws + OFF_XS);
    float*  Bq  = (float*)(ws + OFF_BB);
    float*  Cq  = (float*)(ws + OFF_CC);
    float*  dtq = (float*)(ws + OFF_DT);
    float*  ldq = (float*)(ws + OFF_DA);
    float*  dtr = (float*)(ws + OFF_DR);
    ushort* wbf = (ushort*)(ws + OFF_CS);
    ushort* cs  = (ushort*)(ws + OFF_CS);
    ushort* xbf = (ushort*)(ws + OFF_XS);   // x bf16, dead once conv_k writes xs
    ushort* yn  = (ushort*)(ws + OFF_XS);   // aliases xs (dead after ssd)
    ushort* dd  = (ushort*)(ws + OFF_DD);   // aliases zx (dead after grms)
    float*  hb  = (float*)(ws + OFF_H);
    ushort* wo  = (ushort*)(ws + OFF_WO);
    ushort* wp  = (ushort*)(ws + OFF_WP);

    // K0: bf16 conversions needed before in_proj (one launch)
    cvt3_k<<<dim3(2 * DPROJ + MROWS), 256, 0, stream>>>(
        f_inw, b_inw, x, wbf, wbf + (size_t)DPROJ * DMODEL, xbf, DPROJ, DPROJ);

    // K1: in_proj, N=4256, K=1024, BN=128
    gemm_k<0, 128><<<dim3((DPROJ + 127) / 128, MROWS / 128, 2), 256, 0, stream>>>(
        xbf, wbf, (size_t)DPROJ * DMODEL, (void*)zx, nullptr, nullptr, dtr,
        DPROJ, DMODEL);

    // K2: conv + activations (overwrites xbf region with xs)
    conv_k<<<dim3(2 * MROWS), 256, 0, stream>>>(
        zx, dtr, f_cw, f_cb, b_cw, b_cb, f_dtb, f_al, b_dtb, b_al,
        xs, Bq, Cq, dtq, ldq);

    // K3: chunked SSD (states / stitch / intra-chunk matmul)
    states_k<<<dim3(128, NCHUNK), 256, 0, stream>>>(Bq, dtq, ldq, xs, cs);
    stitch_k<<<dim3(128), 256, 0, stream>>>(ldq, cs);
    ssd_k<<<dim3(128, NCHUNK), 256, 0, stream>>>(
        Bq, Cq, dtq, ldq, xs, cs, f_Dp, b_Dp, zx);

    // K4: gated RMSNorm (last reader of zx)
    grms_k<<<dim3(2 * MROWS), 256, 0, stream>>>(zx, f_rw, b_rw, yn);

    // K4b: convert out_proj/final weights into dead zx region (one launch)
    cvt3_k<<<dim3(3 * MROWS), 256, 0, stream>>>(
        f_ow, b_ow, projw, wo, wo + (size_t)DMODEL * DINNER, wp, MROWS, MROWS);

    // K5: out_proj, N=1024, K=2048, BN=64; packs [dou0 | flip(dou1)] into dd
    gemm_k<1, 64><<<dim3(DMODEL / 64, MROWS / 128, 2), 256, 0, stream>>>(
        yn, wo, (size_t)DMODEL * DINNER, (void*)dd, nullptr, nullptr, nullptr,
        DMODEL, DINNER);

    // K6: final proj + residual + bias, N=1024, K=2048 (fp32 out)
    gemm_k<2, 64><<<dim3(DMODEL / 64, MROWS / 128, 1), 256, 0, stream>>>(
        dd, wp, 0, (void*)hb, x, projb, nullptr, DMODEL, DINNER);

    // K7: LayerNorm -> fp32 out
    ln_k<<<dim3(MROWS), 256, 0, stream>>>(hb, lnw, lnb, (float*)d_out);
}

// Round 11
// 371.325 us; speedup vs baseline: 2.7948x; 1.0479x over previous
//
#include <hip/hip_runtime.h>
#include <hip/hip_bf16.h>

#define DEV __device__ __forceinline__

typedef short bf16x8 __attribute__((ext_vector_type(8)));
typedef float f32x4 __attribute__((ext_vector_type(4)));

static constexpr int BATCH  = 2;
static constexpr int SEQ    = 1024;
static constexpr int DMODEL = 1024;
static constexpr int DINNER = 2048;
static constexpr int DSTATE = 64;
static constexpr int NH     = 32;
static constexpr int HD     = 64;
static constexpr int CONVD  = 2176;
static constexpr int DPROJ  = 4256;
static constexpr int MROWS  = BATCH * SEQ;   // 2048
static constexpr int NCHUNK = 16;
static constexpr int QC     = 64;

// ---- workspace layout (bytes) ---- peak 74.8 MB (proven)
static constexpr size_t OFF_ZX = 0;                                  // bf16 [4096][4256]
static constexpr size_t OFF_XS = OFF_ZX + (size_t)2*MROWS*DPROJ*2;   // bf16 [4096][2048]; xbf pre-conv, xs after, yn after ssd
static constexpr size_t OFF_BB = OFF_XS + (size_t)2*MROWS*DINNER*2;  // f32 [4096][64]
static constexpr size_t OFF_CC = OFF_BB + (size_t)2*MROWS*DSTATE*4;  // f32 [4096][64]
static constexpr size_t OFF_DT = OFF_CC + (size_t)2*MROWS*DSTATE*4;  // f32 [4][32][1024] dt
static constexpr size_t OFF_DA = OFF_DT + (size_t)2*MROWS*NH*4;      // f32 [4][32][1024] ldA
static constexpr size_t OFF_DR = OFF_DA + (size_t)2*MROWS*NH*4;      // f32 [4096][32] raw dt spill
// CS: time-shared (a) bf16 in_proj weights [2][4256][1024]  (b) chunk states
static constexpr size_t OFF_CS = OFF_DR + (size_t)2*MROWS*NH*4;
// aliased into zx (dead after grms):
static constexpr size_t OFF_DD = 0;                                  // bf16 [2048][2048] packed dir outs
static constexpr size_t OFF_H  = OFF_DD + (size_t)MROWS*2*DMODEL;    // f32 [2048][1024]
static constexpr size_t OFF_WO = OFF_H  + (size_t)MROWS*DMODEL*4;    // bf16 [2][1024][2048]
static constexpr size_t OFF_WP = OFF_WO + (size_t)2*DMODEL*DINNER*2; // bf16 [1024][2048]

DEV float b2f(ushort u) {
    union { unsigned int i; float f; } v;
    v.i = ((unsigned int)u) << 16;
    return v.f;
}
DEV ushort f2b(float f) {
    union { float f; unsigned int u; } v;
    v.f = f;
    unsigned int r = 0x7FFFu + ((v.u >> 16) & 1u);
    return (ushort)((v.u + r) >> 16);
}
DEV bf16x8 pack8(float4 a, float4 b) {
    bf16x8 r;
    r[0] = (short)f2b(a.x); r[1] = (short)f2b(a.y);
    r[2] = (short)f2b(a.z); r[3] = (short)f2b(a.w);
    r[4] = (short)f2b(b.x); r[5] = (short)f2b(b.y);
    r[6] = (short)f2b(b.z); r[7] = (short)f2b(b.w);
    return r;
}
DEV void gll16(const ushort* g, ushort* l) {
    __builtin_amdgcn_global_load_lds(
        (const __attribute__((address_space(1))) unsigned int*)g,
        (__attribute__((address_space(3))) unsigned int*)l, 16, 0, 0);
}

// ---------------------------------------------------------------------------
// cvt3: three fp32->bf16 conversions in one launch (rows of 1024 floats).
// ---------------------------------------------------------------------------
__global__ __launch_bounds__(256) void cvt3_k(
    const float* __restrict__ s0, const float* __restrict__ s1,
    const float* __restrict__ s2,
    ushort* __restrict__ d0, ushort* __restrict__ d1, ushort* __restrict__ d2,
    int b0, int b1)
{
    int blk = blockIdx.x;
    const float* s; ushort* d; size_t off;
    if (blk < b0)            { s = s0; d = d0; off = (size_t)blk * 1024; }
    else if (blk < b0 + b1)  { s = s1; d = d1; off = (size_t)(blk - b0) * 1024; }
    else                     { s = s2; d = d2; off = (size_t)(blk - b0 - b1) * 1024; }
    size_t i = off + threadIdx.x * 4;
    float4 f = *(const float4*)(s + i);
    ushort4 u;
    u.x = f2b(f.x); u.y = f2b(f.y); u.z = f2b(f.z); u.w = f2b(f.w);
    *(ushort4*)(d + i) = u;
}

// ---------------------------------------------------------------------------
// GEMM: C[m][n] = sum_k A[m][k]*W[n][k], all bf16, global_load_lds width-16
// staging, BM=128, BK=64 (2 MFMA k-windows per barrier pair), BN=128 or 64.
// LDS row = 64 elems = 128 B = 8 lanes/gll-row; XOR row-swizzle:
// LDS[row][slot] holds global colgroup slot^(row&7)  (16B groups).
// MODE 0: bn tiles remapped (bx+2*by)%gridX for XCD-stable W partition.
// ---------------------------------------------------------------------------
template<int MODE, int BN>
__global__ __launch_bounds__(256) void gemm_k(
    const ushort* __restrict__ A, const ushort* __restrict__ W,
    size_t wstride, void* __restrict__ outp, const float* __restrict__ resid,
    const float* __restrict__ bias, float* __restrict__ dtraw,
    int N, int K)
{
    constexpr int BM = 128, BK = 64;
    constexpr int MT = (BN == 128) ? 4 : 2;
    constexpr int NBLB = (BN == 128) ? 4 : 2;   // B gll groups per wave
    __shared__ ushort As[BM * BK];
    __shared__ ushort Bs[BN * BK];
    const int tid = threadIdx.x;
    const int wave = tid >> 6, lane = tid & 63;
    const int quad = lane >> 4, l16 = lane & 15;
    const int bxu = (MODE == 0)
        ? (int)((blockIdx.x + 2 * blockIdx.y) % gridDim.x) : (int)blockIdx.x;
    const int bn = bxu * BN, bm = blockIdx.y * BM;
    const int dir = blockIdx.z;
    const ushort* Wd = W + (size_t)dir * wstride;
    const int wmoff = (BN == 128) ? (wave >> 1) * 64 : wave * 32;
    const int wnoff = (BN == 128) ? (wave & 1) * 64 : 0;

    // staging: lane -> row li*8 + (lane>>3); global colgroup XOR-swizzled:
    // cg = (lane&7) ^ ((lane>>3)&7)  (row&7 == (lane>>3)&7 since li*8 ≡ 0 mod 8)
    const int scg = ((lane & 7) ^ ((lane >> 3) & 7)) * 8;
    const ushort* aga[4];
    ushort* ald[4];
    #pragma unroll
    for (int t = 0; t < 4; t++) {
        int li = wave * 4 + t;            // 16 groups of 8 rows
        int r = li * 8 + (lane >> 3);
        int m = bm + r;
        size_t rowidx;
        if (MODE == 0) {
            int b = m >> 10, l = m & 1023;
            int ls = dir ? (1023 - l) : l;
            rowidx = (size_t)((b << 10) + ls);
        } else if (MODE == 1) {
            rowidx = (size_t)(dir * MROWS + m);
        } else {
            rowidx = (size_t)m;
        }
        aga[t] = A + rowidx * K + scg;
        ald[t] = &As[li * 512];           // 8 rows * 64 elems
    }
    const ushort* bga[NBLB];
    ushort* bld[NBLB];
    #pragma unroll
    for (int t = 0; t < NBLB; t++) {
        int li = wave * NBLB + t;
        int n = bn + li * 8 + (lane >> 3);
        if (n >= N) n = N - 1;            // clamp; cols >= N discarded
        bga[t] = Wd + (size_t)n * K + scg;
        bld[t] = &Bs[li * 512];
    }

    f32x4 acc[MT][4] = {};

    for (int k0 = 0; k0 < K; k0 += BK) {
        #pragma unroll
        for (int t = 0; t < 4; t++) gll16(aga[t] + k0, ald[t]);
        #pragma unroll
        for (int t = 0; t < NBLB; t++) gll16(bga[t] + k0, bld[t]);
        __syncthreads();

        #pragma unroll
        for (int kt = 0; kt < 2; kt++) {
            // read slot for colgroup (kt*4+quad) at row l16 (mod 8): XOR swizzle
            const int rs = (((kt * 4 + quad) ^ (l16 & 7))) * 8;
            bf16x8 af[MT], bfr[4];
            #pragma unroll
            for (int mt = 0; mt < MT; mt++)
                af[mt] = *(const bf16x8*)&As[(wmoff + mt * 16 + l16) * BK + rs];
            #pragma unroll
            for (int nt = 0; nt < 4; nt++)
                bfr[nt] = *(const bf16x8*)&Bs[(wnoff + nt * 16 + l16) * BK + rs];
            #pragma unroll
            for (int mt = 0; mt < MT; mt++)
                #pragma unroll
                for (int nt = 0; nt < 4; nt++)
                    acc[mt][nt] = __builtin_amdgcn_mfma_f32_16x16x32_bf16(
                        af[mt], bfr[nt], acc[mt][nt], 0, 0, 0);
        }
        __syncthreads();
    }

    // epilogue: C/D layout row=quad*4+j, col=l16
    #pragma unroll
    for (int mt = 0; mt < MT; mt++) {
        #pragma unroll
        for (int nt = 0; nt < 4; nt++) {
            #pragma unroll
            for (int j = 0; j < 4; j++) {
                int row = bm + wmoff + mt * 16 + quad * 4 + j;
                int col = bn + wnoff + nt * 16 + l16;
                if (col >= N) continue;
                float v = acc[mt][nt][j];
                if (MODE == 0) {
                    ((ushort*)outp)[(size_t)(dir * MROWS + row) * DPROJ + col] = f2b(v);
                    if (col >= 4224)
                        dtraw[(size_t)(dir * MROWS + row) * NH + (col - 4224)] = v;
                } else if (MODE == 1) {
                    int mr = dir ? ((row & 1024) | (1023 - (row & 1023))) : row;
                    ((ushort*)outp)[(size_t)mr * (2 * DMODEL) + dir * DMODEL + col] = f2b(v);
                } else {
                    float r = resid[(size_t)row * DMODEL + col] + bias[col];
                    ((float*)outp)[(size_t)row * DMODEL + col] = v + r;
                }
            }
        }
    }
}

// ---------------------------------------------------------------------------
// causal depthwise conv(width 4) + bias + SiLU; dt = softplus(raw+bias);
// ldA = A*dt (log decay). dt/ldA TRANSPOSED: [dirb*32+h][l]
// ---------------------------------------------------------------------------
__global__ __launch_bounds__(256) void conv_k(
    const ushort* __restrict__ zx, const float* __restrict__ dtr,
    const float* __restrict__ cw0, const float* __restrict__ cb0,
    const float* __restrict__ cw1, const float* __restrict__ cb1,
    const float* __restrict__ dtb0, const float* __restrict__ al0,
    const float* __restrict__ dtb1, const float* __restrict__ al1,
    ushort* __restrict__ xs, float* __restrict__ Bq, float* __restrict__ Cq,
    float* __restrict__ dtq, float* __restrict__ ldq)
{
    int id = blockIdx.x;
    int dir = id >> 11;
    int m = id & 2047;
    int l = m & 1023;
    const float* cw = dir ? cw1 : cw0;
    const float* cb = dir ? cb1 : cb0;
    int tid = threadIdx.x;

    for (int c = tid; c < CONVD; c += 256) {
        float acc = cb[c];
        #pragma unroll
        for (int t = 0; t < 4; t++) {
            int ls = l - 3 + t;
            if (ls >= 0) {
                acc += cw[t * CONVD + c] *
                       b2f(zx[(size_t)(id - l + ls) * DPROJ + 2048 + c]);
            }
        }
        float v = acc / (1.f + expf(-acc));   // SiLU
        if (c < DINNER) {
            xs[(size_t)id * DINNER + c] = f2b(v);
        } else if (c < DINNER + DSTATE) {
            Bq[(size_t)id * DSTATE + (c - DINNER)] = v;
        } else {
            Cq[(size_t)id * DSTATE + (c - DINNER - DSTATE)] = v;
        }
    }
    if (tid < NH) {
        const float* dtb = dir ? dtb1 : dtb0;
        const float* al  = dir ? al1 : al0;
        float raw = dtr[(size_t)id * NH + tid] + dtb[tid];
        float dt = raw > 20.f ? raw : log1pf(expf(raw));
        float ldA = -expf(al[tid]) * dt;
        int dirb = id >> 10;
        dtq[(size_t)(dirb * NH + tid) * SEQ + l] = dt;
        ldq[(size_t)(dirb * NH + tid) * SEQ + l] = ldA;
    }
}

// ---------------------------------------------------------------------------
// states_k: chunk-local end state via MFMA.
// ---------------------------------------------------------------------------
__global__ __launch_bounds__(256) void states_k(
    const float* __restrict__ Bq, const float* __restrict__ dtT,
    const float* __restrict__ ldT, const ushort* __restrict__ xsq,
    ushort* __restrict__ cs)
{
    int id = blockIdx.x;
    int h = id & 31;
    int c = blockIdx.y;
    int tid = threadIdx.x;
    int wave = tid >> 6, lane = tid & 63;
    int quad = lane >> 4;
    int base = (id >> 5) << 10;
    int l0 = c * QC;

    __shared__ float wsh[QC];
    __shared__ ushort Xw[64][80];
    __shared__ ushort Bt[64][72];

    if (tid < 64) {
        float ld = ldT[(size_t)id * SEQ + l0 + tid];
        #pragma unroll
        for (int st = 1; st < 64; st <<= 1) {
            float o = __shfl_up(ld, st);
            if (tid >= st) ld += o;
        }
        float tot = __shfl(ld, 63);
        wsh[tid] = dtT[(size_t)id * SEQ + l0 + tid] * expf(tot - ld);
    }
    __syncthreads();

    {
        int j = tid >> 2, p0 = (tid & 3) * 16;
        float wj = wsh[j];
        const ushort* xrow = xsq + (size_t)(base + l0 + j) * DINNER + h * HD + p0;
        #pragma unroll
        for (int q = 0; q < 4; q++) {
            ushort4 xv = *(const ushort4*)(xrow + q * 4);
            Xw[p0 + q * 4 + 0][j] = f2b(b2f(xv.x) * wj);
            Xw[p0 + q * 4 + 1][j] = f2b(b2f(xv.y) * wj);
            Xw[p0 + q * 4 + 2][j] = f2b(b2f(xv.z) * wj);
            Xw[p0 + q * 4 + 3][j] = f2b(b2f(xv.w) * wj);
        }
        int j2 = lane, ng = wave * 16;
        const float* brow = Bq + (size_t)(base + l0 + j2) * DSTATE + ng;
        #pragma unroll
        for (int q = 0; q < 4; q++) {
            float4 f = *(const float4*)(brow + q * 4);
            Bt[ng + q * 4 + 0][j2] = f2b(f.x);
            Bt[ng + q * 4 + 1][j2] = f2b(f.y);
            Bt[ng + q * 4 + 2][j2] = f2b(f.z);
            Bt[ng + q * 4 + 3][j2] = f2b(f.w);
        }
    }
    __syncthreads();

    f32x4 acc[4] = {};
    #pragma unroll
    for (int kt = 0; kt < 2; kt++) {
        int k = kt * 32 + quad * 8;
        bf16x8 af = *(const bf16x8*)&Xw[wave * 16 + (lane & 15)][k];
        #pragma unroll
        for (int ni = 0; ni < 4; ni++) {
            bf16x8 bf = *(const bf16x8*)&Bt[ni * 16 + (lane & 15)][k];
            acc[ni] = __builtin_amdgcn_mfma_f32_16x16x32_bf16(af, bf, acc[ni], 0, 0, 0);
        }
    }

    ushort* out = cs + ((size_t)id * NCHUNK + c) * HD * DSTATE;
    #pragma unroll
    for (int ni = 0; ni < 4; ni++) {
        #pragma unroll
        for (int j = 0; j < 4; j++) {
            int p = wave * 16 + quad * 4 + j;
            int n = ni * 16 + (lane & 15);
            out[(size_t)p * DSTATE + n] = f2b(acc[ni][j]);
        }
    }
}

// ---------------------------------------------------------------------------
// Stitch: H_{c+1} = S_c + exp(sum ldA) * H_c (in place -> chunk-start H_c)
// ---------------------------------------------------------------------------
__global__ __launch_bounds__(256) void stitch_k(
    const float* __restrict__ ldT, ushort* __restrict__ cs)
{
    int id = blockIdx.x;
    int tid = threadIdx.x;
    __shared__ float red[256];
    __shared__ float dec[NCHUNK];

    float4 d4 = *(const float4*)(ldT + (size_t)id * SEQ + tid * 4);
    red[tid] = d4.x + d4.y + d4.z + d4.w;
    __syncthreads();
    if (tid < NCHUNK) {
        float s = 0.f;
        #pragma unroll
        for (int i = 0; i < 16; i++) s += red[tid * 16 + i];
        dec[tid] = expf(s);
    }
    __syncthreads();

    int p = tid >> 2, n0 = (tid & 3) * 16;
    ushort* ptr = cs + (size_t)id * NCHUNK * HD * DSTATE + p * DSTATE + n0;

    float st[16];
    #pragma unroll
    for (int i = 0; i < 16; i++) st[i] = 0.f;

    for (int c = 0; c < NCHUNK; c++) {
        ushort* row = ptr + (size_t)c * HD * DSTATE;
        float tmp[16];
        #pragma unroll
        for (int i = 0; i < 16; i++) tmp[i] = b2f(row[i]);
        #pragma unroll
        for (int i = 0; i < 16; i++) row[i] = f2b(st[i]);
        float d = dec[c];
        #pragma unroll
        for (int i = 0; i < 16; i++) st[i] = fmaf(d, st[i], tmp[i]);
    }
}

// ---------------------------------------------------------------------------
// ssd_k: intra-chunk SSD matmul + seed + D*x
// ---------------------------------------------------------------------------
__global__ __launch_bounds__(256) void ssd_k(
    const float* __restrict__ Bq, const float* __restrict__ Cq,
    const float* __restrict__ dtT, const float* __restrict__ ldT,
    const ushort* __restrict__ xsq, const ushort* __restrict__ cs,
    const float* __restrict__ D0, const float* __restrict__ D1,
    ushort* __restrict__ yout)
{
    int id = blockIdx.x;
    int dir = id >> 6, h = id & 31;
    int c = blockIdx.y;
    int tid = threadIdx.x;
    int wave = tid >> 6, lane = tid & 63;
    int quad = lane >> 4;
    int base = (id >> 5) << 10;
    int l0 = c * QC;

    __shared__ float cum[QC], dts[QC];
    __shared__ ushort Ms[64][72];
    __shared__ ushort Xb[64][80];

    {
        int j = tid >> 2, p0 = (tid & 3) * 16;
        const ushort* xrow = xsq + (size_t)(base + l0 + j) * DINNER + h * HD + p0;
        #pragma unroll
        for (int q = 0; q < 4; q++) {
            ushort4 xv = *(const ushort4*)(xrow + q * 4);
            Xb[p0 + q * 4 + 0][j] = xv.x;
            Xb[p0 + q * 4 + 1][j] = xv.y;
            Xb[p0 + q * 4 + 2][j] = xv.z;
            Xb[p0 + q * 4 + 3][j] = xv.w;
        }
    }
    if (tid < 64) {
        float ld = ldT[(size_t)id * SEQ + l0 + tid];
        #pragma unroll
        for (int st = 1; st < 64; st <<= 1) {
            float o = __shfl_up(ld, st);
            if (tid >= st) ld += o;
        }
        cum[tid] = ld;
        dts[tid] = dtT[(size_t)id * SEQ + l0 + tid];
    }

    f32x4 sacc[4] = {};
    #pragma unroll
    for (int kt = 0; kt < 2; kt++) {
        int k = kt * 32 + quad * 8;
        const float* cp = Cq + (size_t)(base + l0 + wave * 16 + (lane & 15)) * DSTATE + k;
        bf16x8 af = pack8(*(const float4*)cp, *(const float4*)(cp + 4));
        #pragma unroll
        for (int ni = 0; ni < 4; ni++) {
            const float* bp = Bq + (size_t)(base + l0 + ni * 16 + (lane & 15)) * DSTATE + k;
            bf16x8 bf = pack8(*(const float4*)bp, *(const float4*)(bp + 4));
            sacc[ni] = __builtin_amdgcn_mfma_f32_16x16x32_bf16(af, bf, sacc[ni], 0, 0, 0);
        }
    }
    __syncthreads();

    #pragma unroll
    for (int ni = 0; ni < 4; ni++) {
        int j = ni * 16 + (lane & 15);
        float cj = cum[j], dj = dts[j];
        #pragma unroll
        for (int r = 0; r < 4; r++) {
            int l = wave * 16 + quad * 4 + r;
            float v = 0.f;
            if (l >= j) v = expf(cum[l] - cj) * dj * sacc[ni][r];
            Ms[l][j] = f2b(v);
        }
    }
    __syncthreads();

    f32x4 acc[4] = {};
    #pragma unroll
    for (int kt = 0; kt < 2; kt++) {
        int k = kt * 32 + quad * 8;
        bf16x8 af = *(const bf16x8*)&Ms[wave * 16 + (lane & 15)][k];
        #pragma unroll
        for (int ni = 0; ni < 4; ni++) {
            bf16x8 bf = *(const bf16x8*)&Xb[ni * 16 + (lane & 15)][k];
            acc[ni] = __builtin_amdgcn_mfma_f32_16x16x32_bf16(af, bf, acc[ni], 0, 0, 0);
        }
    }
    const ushort* Hrow = cs + ((size_t)id * NCHUNK + c) * HD * DSTATE;
    {
        float cl = expf(cum[wave * 16 + (lane & 15)]);
        #pragma unroll
        for (int kt = 0; kt < 2; kt++) {
            int k = kt * 32 + quad * 8;
            const float* cp = Cq + (size_t)(base + l0 + wave * 16 + (lane & 15)) * DSTATE + k;
            float4 c0 = *(const float4*)cp;
            float4 c1 = *(const float4*)(cp + 4);
            float4 s0 = {c0.x * cl, c0.y * cl, c0.z * cl, c0.w * cl};
            float4 s1 = {c1.x * cl, c1.y * cl, c1.z * cl, c1.w * cl};
            bf16x8 af = pack8(s0, s1);
            #pragma unroll
            for (int ni = 0; ni < 4; ni++) {
                bf16x8 bf = *(const bf16x8*)(Hrow + (size_t)(ni * 16 + (lane & 15)) * DSTATE + k);
                acc[ni] = __builtin_amdgcn_mfma_f32_16x16x32_bf16(af, bf, acc[ni], 0, 0, 0);
            }
        }
    }

    float Dv = (dir ? D1 : D0)[h];
    int lb = wave * 16 + quad * 4;
    #pragma unroll
    for (int ni = 0; ni < 4; ni++) {
        int p = ni * 16 + (lane & 15);
        ushort4 x4 = *(const ushort4*)&Xb[p][lb];
        float xv[4] = { b2f(x4.x), b2f(x4.y), b2f(x4.z), b2f(x4.w) };
        #pragma unroll
        for (int r = 0; r < 4; r++) {
            int l = lb + r;
            yout[(size_t)(base + l0 + l) * DPROJ + 2048 + h * HD + p] =
                f2b(acc[ni][r] + Dv * xv[r]);
        }
    }
}

// ---------------------------------------------------------------------------
// gated RMSNorm
// ---------------------------------------------------------------------------
__global__ __launch_bounds__(256) void grms_k(
    const ushort* __restrict__ zx,
    const float* __restrict__ rw0, const float* __restrict__ rw1,
    ushort* __restrict__ yn)
{
    int id = blockIdx.x;
    int dir = id >> 11;
    const float* rw = dir ? rw1 : rw0;
    int tid = threadIdx.x;
    float g[8];
    float ss = 0.f;
    #pragma unroll
    for (int i = 0; i < 8; i++) {
        int c = i * 256 + tid;
        float z  = b2f(zx[(size_t)id * DPROJ + c]);
        float yv = b2f(zx[(size_t)id * DPROJ + 2048 + c]);
        float v = yv * (z / (1.f + expf(-z)));
        g[i] = v;
        ss += v * v;
    }
    for (int o = 32; o; o >>= 1) ss += __shfl_down(ss, o);
    __shared__ float t4[4];
    if ((tid & 63) == 0) t4[tid >> 6] = ss;
    __syncthreads();
    ss = t4[0] + t4[1] + t4[2] + t4[3];
    float sc = rsqrtf(ss * (1.f / DINNER) + 1e-5f);
    #pragma unroll
    for (int i = 0; i < 8; i++) {
        int c = i * 256 + tid;
        yn[(size_t)id * DINNER + c] = f2b(g[i] * sc * rw[c]);
    }
}

// ---------------------------------------------------------------------------
// LayerNorm -> fp32 out
// ---------------------------------------------------------------------------
__global__ __launch_bounds__(256) void ln_k(
    const float* __restrict__ h, const float* __restrict__ lw,
    const float* __restrict__ lb, float* __restrict__ out)
{
    int m = blockIdx.x;
    int tid = threadIdx.x;
    float v[4];
    float s = 0.f, s2 = 0.f;
    #pragma unroll
    for (int i = 0; i < 4; i++) {
        int c = i * 256 + tid;
        v[i] = h[(size_t)m * DMODEL + c];
        s += v[i];
        s2 += v[i] * v[i];
    }
    for (int o = 32; o; o >>= 1) { s += __shfl_down(s, o); s2 += __shfl_down(s2, o); }
    __shared__ float ts[4], ts2[4];
    if ((tid & 63) == 0) { ts[tid >> 6] = s; ts2[tid >> 6] = s2; }
    __syncthreads();
    s  = ts[0] + ts[1] + ts[2] + ts[3];
    s2 = ts2[0] + ts2[1] + ts2[2] + ts2[3];
    float mu  = s * (1.f / DMODEL);
    float var = s2 * (1.f / DMODEL) - mu * mu;
    float sc  = rsqrtf(var + 1e-5f);
    #pragma unroll
    for (int i = 0; i < 4; i++) {
        int c = i * 256 + tid;
        out[(size_t)m * DMODEL + c] = (v[i] - mu) * sc * lw[c] + lb[c];
    }
}

extern "C" void kernel_launch(void* const* d_in, const int* in_sizes, int n_in,
                              void* d_out, int out_size, void* d_ws, size_t ws_size,
                              hipStream_t stream)
{
    const float* x     = (const float*)d_in[0];
    const float* f_inw = (const float*)d_in[1];
    const float* f_cw  = (const float*)d_in[2];
    const float* f_cb  = (const float*)d_in[3];
    const float* f_dtb = (const float*)d_in[4];
    const float* f_al  = (const float*)d_in[5];
    const float* f_Dp  = (const float*)d_in[6];
    const float* f_rw  = (const float*)d_in[7];
    const float* f_ow  = (const float*)d_in[8];
    const float* b_inw = (const float*)d_in[9];
    const float* b_cw  = (const float*)d_in[10];
    const float* b_cb  = (const float*)d_in[11];
    const float* b_dtb = (const float*)d_in[12];
    const float* b_al  = (const float*)d_in[13];
    const float* b_Dp  = (const float*)d_in[14];
    const float* b_rw  = (const float*)d_in[15];
    const float* b_ow  = (const float*)d_in[16];
    const float* projw = (const float*)d_in[17];
    const float* projb = (const float*)d_in[18];
    const float* lnw   = (const float*)d_in[19];
    const float* lnb   = (const float*)d_in[20];

    char* ws = (char*)d_ws;
    ushort* zx  = (ushort*)(ws + OFF_ZX);
    ushort* xs  = (ushort*)(ws + OFF_XS);
    float*  Bq  = (float*)(ws + OFF_BB);
    float*  Cq  = (float*)(ws + OFF_CC);
    float*  dtq = (float*)(ws + OFF_DT);
    float*  ldq = (float*)(ws + OFF_DA);
    float*  dtr = (float*)(ws + OFF_DR);
    ushort* wbf = (ushort*)(ws + OFF_CS);
    ushort* cs  = (ushort*)(ws + OFF_CS);
    ushort* xbf = (ushort*)(ws + OFF_XS);   // x bf16, dead once conv_k writes xs
    ushort* yn  = (ushort*)(ws + OFF_XS);   // aliases xs (dead after ssd)
    ushort* dd  = (ushort*)(ws + OFF_DD);   // aliases zx (dead after grms)
    float*  hb  = (float*)(ws + OFF_H);
    ushort* wo  = (ushort*)(ws + OFF_WO);
    ushort* wp  = (ushort*)(ws + OFF_WP);

    // K0: bf16 conversions needed before in_proj (one launch)
    cvt3_k<<<dim3(2 * DPROJ + MROWS), 256, 0, stream>>>(
        f_inw, b_inw, x, wbf, wbf + (size_t)DPROJ * DMODEL, xbf, DPROJ, DPROJ);

    // K1: in_proj, N=4256, K=1024, BN=128, BK=64
    gemm_k<0, 128><<<dim3((DPROJ + 127) / 128, MROWS / 128, 2), 256, 0, stream>>>(
        xbf, wbf, (size_t)DPROJ * DMODEL, (void*)zx, nullptr, nullptr, dtr,
        DPROJ, DMODEL);

    // K2: conv + activations (overwrites xbf region with xs)
    conv_k<<<dim3(2 * MROWS), 256, 0, stream>>>(
        zx, dtr, f_cw, f_cb, b_cw, b_cb, f_dtb, f_al, b_dtb, b_al,
        xs, Bq, Cq, dtq, ldq);

    // K3: chunked SSD (states / stitch / intra-chunk matmul)
    states_k<<<dim3(128, NCHUNK), 256, 0, stream>>>(Bq, dtq, ldq, xs, cs);
    stitch_k<<<dim3(128), 256, 0, stream>>>(ldq, cs);
    ssd_k<<<dim3(128, NCHUNK), 256, 0, stream>>>(
        Bq, Cq, dtq, ldq, xs, cs, f_Dp, b_Dp, zx);

    // K4: gated RMSNorm (last reader of zx)
    grms_k<<<dim3(2 * MROWS), 256, 0, stream>>>(zx, f_rw, b_rw, yn);

    // K4b: convert out_proj/final weights into dead zx region (one launch)
    cvt3_k<<<dim3(3 * MROWS), 256, 0, stream>>>(
        f_ow, b_ow, projw, wo, wo + (size_t)DMODEL * DINNER, wp, MROWS, MROWS);

    // K5: out_proj, N=1024, K=2048, BN=64, BK=64; packs [dou0|flip(dou1)] into dd
    gemm_k<1, 64><<<dim3(DMODEL / 64, MROWS / 128, 2), 256, 0, stream>>>(
        yn, wo, (size_t)DMODEL * DINNER, (void*)dd, nullptr, nullptr, nullptr,
        DMODEL, DINNER);

    // K6: final proj + residual + bias, N=1024, K=2048 (fp32 out)
    gemm_k<2, 64><<<dim3(DMODEL / 64, MROWS / 128, 1), 256, 0, stream>>>(
        dd, wp, 0, (void*)hb, x, projb, nullptr, DMODEL, DINNER);

    // K7: LayerNorm -> fp32 out
    ln_k<<<dim3(MROWS), 256, 0, stream>>>(hb, lnw, lnb, (float*)d_out);
}

// Round 12
// 362.374 us; speedup vs baseline: 2.8639x; 1.0247x over previous
//
#include <hip/hip_runtime.h>
#include <hip/hip_bf16.h>

#define DEV __device__ __forceinline__

typedef short bf16x8 __attribute__((ext_vector_type(8)));
typedef float f32x4 __attribute__((ext_vector_type(4)));

static constexpr int BATCH  = 2;
static constexpr int SEQ    = 1024;
static constexpr int DMODEL = 1024;
static constexpr int DINNER = 2048;
static constexpr int DSTATE = 64;
static constexpr int NH     = 32;
static constexpr int HD     = 64;
static constexpr int CONVD  = 2176;
static constexpr int DPROJ  = 4256;
static constexpr int MROWS  = BATCH * SEQ;   // 2048
static constexpr int NCHUNK = 16;
static constexpr int QC     = 64;

// ---- workspace layout (bytes) ---- peak 74.8 MB (proven)
static constexpr size_t OFF_ZX = 0;                                  // bf16 [4096][4256]
static constexpr size_t OFF_XS = OFF_ZX + (size_t)2*MROWS*DPROJ*2;   // bf16 [4096][2048]; xbf pre-conv, xs after, yn after ssd
static constexpr size_t OFF_BB = OFF_XS + (size_t)2*MROWS*DINNER*2;  // f32 [4096][64]
static constexpr size_t OFF_CC = OFF_BB + (size_t)2*MROWS*DSTATE*4;  // f32 [4096][64]
static constexpr size_t OFF_DT = OFF_CC + (size_t)2*MROWS*DSTATE*4;  // f32 [4][32][1024] dt
static constexpr size_t OFF_DA = OFF_DT + (size_t)2*MROWS*NH*4;      // f32 [4][32][1024] ldA
static constexpr size_t OFF_DR = OFF_DA + (size_t)2*MROWS*NH*4;      // f32 [4096][32] raw dt spill
// CS: time-shared (a) bf16 in_proj weights [2][4256][1024]  (b) chunk states
static constexpr size_t OFF_CS = OFF_DR + (size_t)2*MROWS*NH*4;
// aliased into zx (dead after grms):
static constexpr size_t OFF_DD = 0;                                  // bf16 [2048][2048] packed dir outs
static constexpr size_t OFF_H  = OFF_DD + (size_t)MROWS*2*DMODEL;    // f32 [2048][1024]
static constexpr size_t OFF_WO = OFF_H  + (size_t)MROWS*DMODEL*4;    // bf16 [2][1024][2048]
static constexpr size_t OFF_WP = OFF_WO + (size_t)2*DMODEL*DINNER*2; // bf16 [1024][2048]

DEV float b2f(ushort u) {
    union { unsigned int i; float f; } v;
    v.i = ((unsigned int)u) << 16;
    return v.f;
}
DEV ushort f2b(float f) {
    union { float f; unsigned int u; } v;
    v.f = f;
    unsigned int r = 0x7FFFu + ((v.u >> 16) & 1u);
    return (ushort)((v.u + r) >> 16);
}
DEV bf16x8 pack8(float4 a, float4 b) {
    bf16x8 r;
    r[0] = (short)f2b(a.x); r[1] = (short)f2b(a.y);
    r[2] = (short)f2b(a.z); r[3] = (short)f2b(a.w);
    r[4] = (short)f2b(b.x); r[5] = (short)f2b(b.y);
    r[6] = (short)f2b(b.z); r[7] = (short)f2b(b.w);
    return r;
}
DEV void gll16(const ushort* g, ushort* l) {
    __builtin_amdgcn_global_load_lds(
        (const __attribute__((address_space(1))) unsigned int*)g,
        (__attribute__((address_space(3))) unsigned int*)l, 16, 0, 0);
}

// ---------------------------------------------------------------------------
// cvt3: three fp32->bf16 conversions in one launch (rows of 1024 floats).
// ---------------------------------------------------------------------------
__global__ __launch_bounds__(256) void cvt3_k(
    const float* __restrict__ s0, const float* __restrict__ s1,
    const float* __restrict__ s2,
    ushort* __restrict__ d0, ushort* __restrict__ d1, ushort* __restrict__ d2,
    int b0, int b1)
{
    int blk = blockIdx.x;
    const float* s; ushort* d; size_t off;
    if (blk < b0)            { s = s0; d = d0; off = (size_t)blk * 1024; }
    else if (blk < b0 + b1)  { s = s1; d = d1; off = (size_t)(blk - b0) * 1024; }
    else                     { s = s2; d = d2; off = (size_t)(blk - b0 - b1) * 1024; }
    size_t i = off + threadIdx.x * 4;
    float4 f = *(const float4*)(s + i);
    ushort4 u;
    u.x = f2b(f.x); u.y = f2b(f.y); u.z = f2b(f.z); u.w = f2b(f.w);
    *(ushort4*)(d + i) = u;
}

// ---------------------------------------------------------------------------
// GEMM: C[m][n] = sum_k A[m][k]*W[n][k], all bf16, global_load_lds width-16
// staging, BM=128, BK=64 (2 MFMA k-windows per barrier pair), BN=128 or 64.
// XOR row-swizzle: LDS[row][slot] holds global colgroup slot^(row&7).
// MODE 0: bn tiles remapped (bx+2*by)%gridX for XCD-stable W partition.
// ---------------------------------------------------------------------------
template<int MODE, int BN>
__global__ __launch_bounds__(256) void gemm_k(
    const ushort* __restrict__ A, const ushort* __restrict__ W,
    size_t wstride, void* __restrict__ outp, const float* __restrict__ resid,
    const float* __restrict__ bias, float* __restrict__ dtraw,
    int N, int K)
{
    constexpr int BM = 128, BK = 64;
    constexpr int MT = (BN == 128) ? 4 : 2;
    constexpr int NBLB = (BN == 128) ? 4 : 2;
    __shared__ ushort As[BM * BK];
    __shared__ ushort Bs[BN * BK];
    const int tid = threadIdx.x;
    const int wave = tid >> 6, lane = tid & 63;
    const int quad = lane >> 4, l16 = lane & 15;
    const int bxu = (MODE == 0)
        ? (int)((blockIdx.x + 2 * blockIdx.y) % gridDim.x) : (int)blockIdx.x;
    const int bn = bxu * BN, bm = blockIdx.y * BM;
    const int dir = blockIdx.z;
    const ushort* Wd = W + (size_t)dir * wstride;
    const int wmoff = (BN == 128) ? (wave >> 1) * 64 : wave * 32;
    const int wnoff = (BN == 128) ? (wave & 1) * 64 : 0;

    const int scg = ((lane & 7) ^ ((lane >> 3) & 7)) * 8;
    const ushort* aga[4];
    ushort* ald[4];
    #pragma unroll
    for (int t = 0; t < 4; t++) {
        int li = wave * 4 + t;
        int r = li * 8 + (lane >> 3);
        int m = bm + r;
        size_t rowidx;
        if (MODE == 0) {
            int b = m >> 10, l = m & 1023;
            int ls = dir ? (1023 - l) : l;
            rowidx = (size_t)((b << 10) + ls);
        } else if (MODE == 1) {
            rowidx = (size_t)(dir * MROWS + m);
        } else {
            rowidx = (size_t)m;
        }
        aga[t] = A + rowidx * K + scg;
        ald[t] = &As[li * 512];
    }
    const ushort* bga[NBLB];
    ushort* bld[NBLB];
    #pragma unroll
    for (int t = 0; t < NBLB; t++) {
        int li = wave * NBLB + t;
        int n = bn + li * 8 + (lane >> 3);
        if (n >= N) n = N - 1;
        bga[t] = Wd + (size_t)n * K + scg;
        bld[t] = &Bs[li * 512];
    }

    f32x4 acc[MT][4] = {};

    for (int k0 = 0; k0 < K; k0 += BK) {
        #pragma unroll
        for (int t = 0; t < 4; t++) gll16(aga[t] + k0, ald[t]);
        #pragma unroll
        for (int t = 0; t < NBLB; t++) gll16(bga[t] + k0, bld[t]);
        __syncthreads();

        #pragma unroll
        for (int kt = 0; kt < 2; kt++) {
            const int rs = (((kt * 4 + quad) ^ (l16 & 7))) * 8;
            bf16x8 af[MT], bfr[4];
            #pragma unroll
            for (int mt = 0; mt < MT; mt++)
                af[mt] = *(const bf16x8*)&As[(wmoff + mt * 16 + l16) * BK + rs];
            #pragma unroll
            for (int nt = 0; nt < 4; nt++)
                bfr[nt] = *(const bf16x8*)&Bs[(wnoff + nt * 16 + l16) * BK + rs];
            #pragma unroll
            for (int mt = 0; mt < MT; mt++)
                #pragma unroll
                for (int nt = 0; nt < 4; nt++)
                    acc[mt][nt] = __builtin_amdgcn_mfma_f32_16x16x32_bf16(
                        af[mt], bfr[nt], acc[mt][nt], 0, 0, 0);
        }
        __syncthreads();
    }

    #pragma unroll
    for (int mt = 0; mt < MT; mt++) {
        #pragma unroll
        for (int nt = 0; nt < 4; nt++) {
            #pragma unroll
            for (int j = 0; j < 4; j++) {
                int row = bm + wmoff + mt * 16 + quad * 4 + j;
                int col = bn + wnoff + nt * 16 + l16;
                if (col >= N) continue;
                float v = acc[mt][nt][j];
                if (MODE == 0) {
                    ((ushort*)outp)[(size_t)(dir * MROWS + row) * DPROJ + col] = f2b(v);
                    if (col >= 4224)
                        dtraw[(size_t)(dir * MROWS + row) * NH + (col - 4224)] = v;
                } else if (MODE == 1) {
                    int mr = dir ? ((row & 1024) | (1023 - (row & 1023))) : row;
                    ((ushort*)outp)[(size_t)mr * (2 * DMODEL) + dir * DMODEL + col] = f2b(v);
                } else {
                    float r = resid[(size_t)row * DMODEL + col] + bias[col];
                    ((float*)outp)[(size_t)row * DMODEL + col] = v + r;
                }
            }
        }
    }
}

// ---------------------------------------------------------------------------
// causal depthwise conv(width 4) + bias + SiLU — vectorized 4 chans/thread.
// dt = softplus(raw+bias); ldA = A*dt. dt/ldA TRANSPOSED: [dirb*32+h][l]
// ---------------------------------------------------------------------------
__global__ __launch_bounds__(256) void conv_k(
    const ushort* __restrict__ zx, const float* __restrict__ dtr,
    const float* __restrict__ cw0, const float* __restrict__ cb0,
    const float* __restrict__ cw1, const float* __restrict__ cb1,
    const float* __restrict__ dtb0, const float* __restrict__ al0,
    const float* __restrict__ dtb1, const float* __restrict__ al1,
    ushort* __restrict__ xs, float* __restrict__ Bq, float* __restrict__ Cq,
    float* __restrict__ dtq, float* __restrict__ ldq)
{
    int id = blockIdx.x;
    int dir = id >> 11;
    int m = id & 2047;
    int l = m & 1023;
    const float* cw = dir ? cw1 : cw0;
    const float* cb = dir ? cb1 : cb0;
    int tid = threadIdx.x;

    for (int c = tid * 4; c < CONVD; c += 1024) {
        float4 cbv = *(const float4*)&cb[c];
        float acc[4] = { cbv.x, cbv.y, cbv.z, cbv.w };
        #pragma unroll
        for (int t = 0; t < 4; t++) {
            int ls = l - 3 + t;
            if (ls >= 0) {
                float4 wv = *(const float4*)&cw[t * CONVD + c];
                ushort4 xv = *(const ushort4*)&zx[(size_t)(id - l + ls) * DPROJ + 2048 + c];
                acc[0] += wv.x * b2f(xv.x);
                acc[1] += wv.y * b2f(xv.y);
                acc[2] += wv.z * b2f(xv.z);
                acc[3] += wv.w * b2f(xv.w);
            }
        }
        float v[4];
        #pragma unroll
        for (int i = 0; i < 4; i++) v[i] = acc[i] / (1.f + expf(-acc[i]));
        if (c < DINNER) {
            ushort4 u;
            u.x = f2b(v[0]); u.y = f2b(v[1]); u.z = f2b(v[2]); u.w = f2b(v[3]);
            *(ushort4*)&xs[(size_t)id * DINNER + c] = u;
        } else if (c < DINNER + DSTATE) {
            *(float4*)&Bq[(size_t)id * DSTATE + (c - DINNER)] =
                make_float4(v[0], v[1], v[2], v[3]);
        } else {
            *(float4*)&Cq[(size_t)id * DSTATE + (c - DINNER - DSTATE)] =
                make_float4(v[0], v[1], v[2], v[3]);
        }
    }
    if (tid < NH) {
        const float* dtb = dir ? dtb1 : dtb0;
        const float* al  = dir ? al1 : al0;
        float raw = dtr[(size_t)id * NH + tid] + dtb[tid];
        float dt = raw > 20.f ? raw : log1pf(expf(raw));
        float ldA = -expf(al[tid]) * dt;
        int dirb = id >> 10;
        dtq[(size_t)(dirb * NH + tid) * SEQ + l] = dt;
        ldq[(size_t)(dirb * NH + tid) * SEQ + l] = ldA;
    }
}

// ---------------------------------------------------------------------------
// states_k: chunk-local end state via MFMA.
// ---------------------------------------------------------------------------
__global__ __launch_bounds__(256) void states_k(
    const float* __restrict__ Bq, const float* __restrict__ dtT,
    const float* __restrict__ ldT, const ushort* __restrict__ xsq,
    ushort* __restrict__ cs)
{
    int id = blockIdx.x;
    int h = id & 31;
    int c = blockIdx.y;
    int tid = threadIdx.x;
    int wave = tid >> 6, lane = tid & 63;
    int quad = lane >> 4;
    int base = (id >> 5) << 10;
    int l0 = c * QC;

    __shared__ float wsh[QC];
    __shared__ ushort Xw[64][80];
    __shared__ ushort Bt[64][72];

    if (tid < 64) {
        float ld = ldT[(size_t)id * SEQ + l0 + tid];
        #pragma unroll
        for (int st = 1; st < 64; st <<= 1) {
            float o = __shfl_up(ld, st);
            if (tid >= st) ld += o;
        }
        float tot = __shfl(ld, 63);
        wsh[tid] = dtT[(size_t)id * SEQ + l0 + tid] * expf(tot - ld);
    }
    __syncthreads();

    {
        int j = tid >> 2, p0 = (tid & 3) * 16;
        float wj = wsh[j];
        const ushort* xrow = xsq + (size_t)(base + l0 + j) * DINNER + h * HD + p0;
        #pragma unroll
        for (int q = 0; q < 4; q++) {
            ushort4 xv = *(const ushort4*)(xrow + q * 4);
            Xw[p0 + q * 4 + 0][j] = f2b(b2f(xv.x) * wj);
            Xw[p0 + q * 4 + 1][j] = f2b(b2f(xv.y) * wj);
            Xw[p0 + q * 4 + 2][j] = f2b(b2f(xv.z) * wj);
            Xw[p0 + q * 4 + 3][j] = f2b(b2f(xv.w) * wj);
        }
        int j2 = lane, ng = wave * 16;
        const float* brow = Bq + (size_t)(base + l0 + j2) * DSTATE + ng;
        #pragma unroll
        for (int q = 0; q < 4; q++) {
            float4 f = *(const float4*)(brow + q * 4);
            Bt[ng + q * 4 + 0][j2] = f2b(f.x);
            Bt[ng + q * 4 + 1][j2] = f2b(f.y);
            Bt[ng + q * 4 + 2][j2] = f2b(f.z);
            Bt[ng + q * 4 + 3][j2] = f2b(f.w);
        }
    }
    __syncthreads();

    f32x4 acc[4] = {};
    #pragma unroll
    for (int kt = 0; kt < 2; kt++) {
        int k = kt * 32 + quad * 8;
        bf16x8 af = *(const bf16x8*)&Xw[wave * 16 + (lane & 15)][k];
        #pragma unroll
        for (int ni = 0; ni < 4; ni++) {
            bf16x8 bf = *(const bf16x8*)&Bt[ni * 16 + (lane & 15)][k];
            acc[ni] = __builtin_amdgcn_mfma_f32_16x16x32_bf16(af, bf, acc[ni], 0, 0, 0);
        }
    }

    ushort* out = cs + ((size_t)id * NCHUNK + c) * HD * DSTATE;
    #pragma unroll
    for (int ni = 0; ni < 4; ni++) {
        #pragma unroll
        for (int j = 0; j < 4; j++) {
            int p = wave * 16 + quad * 4 + j;
            int n = ni * 16 + (lane & 15);
            out[(size_t)p * DSTATE + n] = f2b(acc[ni][j]);
        }
    }
}

// ---------------------------------------------------------------------------
// Stitch: H_{c+1} = S_c + exp(sum ldA) * H_c (in place -> chunk-start H_c)
// ---------------------------------------------------------------------------
__global__ __launch_bounds__(256) void stitch_k(
    const float* __restrict__ ldT, ushort* __restrict__ cs)
{
    int id = blockIdx.x;
    int tid = threadIdx.x;
    __shared__ float red[256];
    __shared__ float dec[NCHUNK];

    float4 d4 = *(const float4*)(ldT + (size_t)id * SEQ + tid * 4);
    red[tid] = d4.x + d4.y + d4.z + d4.w;
    __syncthreads();
    if (tid < NCHUNK) {
        float s = 0.f;
        #pragma unroll
        for (int i = 0; i < 16; i++) s += red[tid * 16 + i];
        dec[tid] = expf(s);
    }
    __syncthreads();

    int p = tid >> 2, n0 = (tid & 3) * 16;
    ushort* ptr = cs + (size_t)id * NCHUNK * HD * DSTATE + p * DSTATE + n0;

    float st[16];
    #pragma unroll
    for (int i = 0; i < 16; i++) st[i] = 0.f;

    for (int c = 0; c < NCHUNK; c++) {
        ushort* row = ptr + (size_t)c * HD * DSTATE;
        float tmp[16];
        #pragma unroll
        for (int i = 0; i < 16; i++) tmp[i] = b2f(row[i]);
        #pragma unroll
        for (int i = 0; i < 16; i++) row[i] = f2b(st[i]);
        float d = dec[c];
        #pragma unroll
        for (int i = 0; i < 16; i++) st[i] = fmaf(d, st[i], tmp[i]);
    }
}

// ---------------------------------------------------------------------------
// ssd_k: intra-chunk SSD matmul + seed + D*x
// ---------------------------------------------------------------------------
__global__ __launch_bounds__(256) void ssd_k(
    const float* __restrict__ Bq, const float* __restrict__ Cq,
    const float* __restrict__ dtT, const float* __restrict__ ldT,
    const ushort* __restrict__ xsq, const ushort* __restrict__ cs,
    const float* __restrict__ D0, const float* __restrict__ D1,
    ushort* __restrict__ yout)
{
    int id = blockIdx.x;
    int dir = id >> 6, h = id & 31;
    int c = blockIdx.y;
    int tid = threadIdx.x;
    int wave = tid >> 6, lane = tid & 63;
    int quad = lane >> 4;
    int base = (id >> 5) << 10;
    int l0 = c * QC;

    __shared__ float cum[QC], dts[QC];
    __shared__ ushort Ms[64][72];
    __shared__ ushort Xb[64][80];

    {
        int j = tid >> 2, p0 = (tid & 3) * 16;
        const ushort* xrow = xsq + (size_t)(base + l0 + j) * DINNER + h * HD + p0;
        #pragma unroll
        for (int q = 0; q < 4; q++) {
            ushort4 xv = *(const ushort4*)(xrow + q * 4);
            Xb[p0 + q * 4 + 0][j] = xv.x;
            Xb[p0 + q * 4 + 1][j] = xv.y;
            Xb[p0 + q * 4 + 2][j] = xv.z;
            Xb[p0 + q * 4 + 3][j] = xv.w;
        }
    }
    if (tid < 64) {
        float ld = ldT[(size_t)id * SEQ + l0 + tid];
        #pragma unroll
        for (int st = 1; st < 64; st <<= 1) {
            float o = __shfl_up(ld, st);
            if (tid >= st) ld += o;
        }
        cum[tid] = ld;
        dts[tid] = dtT[(size_t)id * SEQ + l0 + tid];
    }

    f32x4 sacc[4] = {};
    #pragma unroll
    for (int kt = 0; kt < 2; kt++) {
        int k = kt * 32 + quad * 8;
        const float* cp = Cq + (size_t)(base + l0 + wave * 16 + (lane & 15)) * DSTATE + k;
        bf16x8 af = pack8(*(const float4*)cp, *(const float4*)(cp + 4));
        #pragma unroll
        for (int ni = 0; ni < 4; ni++) {
            const float* bp = Bq + (size_t)(base + l0 + ni * 16 + (lane & 15)) * DSTATE + k;
            bf16x8 bf = pack8(*(const float4*)bp, *(const float4*)(bp + 4));
            sacc[ni] = __builtin_amdgcn_mfma_f32_16x16x32_bf16(af, bf, sacc[ni], 0, 0, 0);
        }
    }
    __syncthreads();

    #pragma unroll
    for (int ni = 0; ni < 4; ni++) {
        int j = ni * 16 + (lane & 15);
        float cj = cum[j], dj = dts[j];
        #pragma unroll
        for (int r = 0; r < 4; r++) {
            int l = wave * 16 + quad * 4 + r;
            float v = 0.f;
            if (l >= j) v = expf(cum[l] - cj) * dj * sacc[ni][r];
            Ms[l][j] = f2b(v);
        }
    }
    __syncthreads();

    f32x4 acc[4] = {};
    #pragma unroll
    for (int kt = 0; kt < 2; kt++) {
        int k = kt * 32 + quad * 8;
        bf16x8 af = *(const bf16x8*)&Ms[wave * 16 + (lane & 15)][k];
        #pragma unroll
        for (int ni = 0; ni < 4; ni++) {
            bf16x8 bf = *(const bf16x8*)&Xb[ni * 16 + (lane & 15)][k];
            acc[ni] = __builtin_amdgcn_mfma_f32_16x16x32_bf16(af, bf, acc[ni], 0, 0, 0);
        }
    }
    const ushort* Hrow = cs + ((size_t)id * NCHUNK + c) * HD * DSTATE;
    {
        float cl = expf(cum[wave * 16 + (lane & 15)]);
        #pragma unroll
        for (int kt = 0; kt < 2; kt++) {
            int k = kt * 32 + quad * 8;
            const float* cp = Cq + (size_t)(base + l0 + wave * 16 + (lane & 15)) * DSTATE + k;
            float4 c0 = *(const float4*)cp;
            float4 c1 = *(const float4*)(cp + 4);
            float4 s0 = {c0.x * cl, c0.y * cl, c0.z * cl, c0.w * cl};
            float4 s1 = {c1.x * cl, c1.y * cl, c1.z * cl, c1.w * cl};
            bf16x8 af = pack8(s0, s1);
            #pragma unroll
            for (int ni = 0; ni < 4; ni++) {
                bf16x8 bf = *(const bf16x8*)(Hrow + (size_t)(ni * 16 + (lane & 15)) * DSTATE + k);
                acc[ni] = __builtin_amdgcn_mfma_f32_16x16x32_bf16(af, bf, acc[ni], 0, 0, 0);
            }
        }
    }

    float Dv = (dir ? D1 : D0)[h];
    int lb = wave * 16 + quad * 4;
    #pragma unroll
    for (int ni = 0; ni < 4; ni++) {
        int p = ni * 16 + (lane & 15);
        ushort4 x4 = *(const ushort4*)&Xb[p][lb];
        float xv[4] = { b2f(x4.x), b2f(x4.y), b2f(x4.z), b2f(x4.w) };
        #pragma unroll
        for (int r = 0; r < 4; r++) {
            int l = lb + r;
            yout[(size_t)(base + l0 + l) * DPROJ + 2048 + h * HD + p] =
                f2b(acc[ni][r] + Dv * xv[r]);
        }
    }
}

// ---------------------------------------------------------------------------
// gated RMSNorm — vectorized: exactly 8 elems/thread, 16 B loads/stores.
// ---------------------------------------------------------------------------
__global__ __launch_bounds__(256) void grms_k(
    const ushort* __restrict__ zx,
    const float* __restrict__ rw0, const float* __restrict__ rw1,
    ushort* __restrict__ yn)
{
    int id = blockIdx.x;
    int dir = id >> 11;
    const float* rw = dir ? rw1 : rw0;
    int tid = threadIdx.x;
    int c0 = tid * 8;
    ushort zv[8], yv[8];
    *(uint4*)zv = *(const uint4*)&zx[(size_t)id * DPROJ + c0];
    *(uint4*)yv = *(const uint4*)&zx[(size_t)id * DPROJ + 2048 + c0];
    float g[8];
    float ss = 0.f;
    #pragma unroll
    for (int i = 0; i < 8; i++) {
        float z = b2f(zv[i]);
        float v = b2f(yv[i]) * (z / (1.f + expf(-z)));
        g[i] = v;
        ss += v * v;
    }
    for (int o = 32; o; o >>= 1) ss += __shfl_down(ss, o);
    __shared__ float t4[4];
    if ((tid & 63) == 0) t4[tid >> 6] = ss;
    __syncthreads();
    ss = t4[0] + t4[1] + t4[2] + t4[3];
    float sc = rsqrtf(ss * (1.f / DINNER) + 1e-5f);
    ushort u[8];
    #pragma unroll
    for (int i = 0; i < 8; i++) u[i] = f2b(g[i] * sc * rw[c0 + i]);
    *(uint4*)&yn[(size_t)id * DINNER + c0] = *(uint4*)u;
}

// ---------------------------------------------------------------------------
// LayerNorm -> fp32 out — vectorized: one float4/thread.
// ---------------------------------------------------------------------------
__global__ __launch_bounds__(256) void ln_k(
    const float* __restrict__ h, const float* __restrict__ lw,
    const float* __restrict__ lb, float* __restrict__ out)
{
    int m = blockIdx.x;
    int tid = threadIdx.x;
    int c = tid * 4;
    float4 v = *(const float4*)&h[(size_t)m * DMODEL + c];
    float s  = v.x + v.y + v.z + v.w;
    float s2 = v.x * v.x + v.y * v.y + v.z * v.z + v.w * v.w;
    for (int o = 32; o; o >>= 1) { s += __shfl_down(s, o); s2 += __shfl_down(s2, o); }
    __shared__ float ts[4], ts2[4];
    if ((tid & 63) == 0) { ts[tid >> 6] = s; ts2[tid >> 6] = s2; }
    __syncthreads();
    s  = ts[0] + ts[1] + ts[2] + ts[3];
    s2 = ts2[0] + ts2[1] + ts2[2] + ts2[3];
    float mu  = s * (1.f / DMODEL);
    float var = s2 * (1.f / DMODEL) - mu * mu;
    float sc  = rsqrtf(var + 1e-5f);
    float4 w4 = *(const float4*)&lw[c];
    float4 b4 = *(const float4*)&lb[c];
    float4 o4;
    o4.x = (v.x - mu) * sc * w4.x + b4.x;
    o4.y = (v.y - mu) * sc * w4.y + b4.y;
    o4.z = (v.z - mu) * sc * w4.z + b4.z;
    o4.w = (v.w - mu) * sc * w4.w + b4.w;
    *(float4*)&out[(size_t)m * DMODEL + c] = o4;
}

extern "C" void kernel_launch(void* const* d_in, const int* in_sizes, int n_in,
                              void* d_out, int out_size, void* d_ws, size_t ws_size,
                              hipStream_t stream)
{
    const float* x     = (const float*)d_in[0];
    const float* f_inw = (const float*)d_in[1];
    const float* f_cw  = (const float*)d_in[2];
    const float* f_cb  = (const float*)d_in[3];
    const float* f_dtb = (const float*)d_in[4];
    const float* f_al  = (const float*)d_in[5];
    const float* f_Dp  = (const float*)d_in[6];
    const float* f_rw  = (const float*)d_in[7];
    const float* f_ow  = (const float*)d_in[8];
    const float* b_inw = (const float*)d_in[9];
    const float* b_cw  = (const float*)d_in[10];
    const float* b_cb  = (const float*)d_in[11];
    const float* b_dtb = (const float*)d_in[12];
    const float* b_al  = (const float*)d_in[13];
    const float* b_Dp  = (const float*)d_in[14];
    const float* b_rw  = (const float*)d_in[15];
    const float* b_ow  = (const float*)d_in[16];
    const float* projw = (const float*)d_in[17];
    const float* projb = (const float*)d_in[18];
    const float* lnw   = (const float*)d_in[19];
    const float* lnb   = (const float*)d_in[20];

    char* ws = (char*)d_ws;
    ushort* zx  = (ushort*)(ws + OFF_ZX);
    ushort* xs  = (ushort*)(ws + OFF_XS);
    float*  Bq  = (float*)(ws + OFF_BB);
    float*  Cq  = (float*)(ws + OFF_CC);
    float*  dtq = (float*)(ws + OFF_DT);
    float*  ldq = (float*)(ws + OFF_DA);
    float*  dtr = (float*)(ws + OFF_DR);
    ushort* wbf = (ushort*)(ws + OFF_CS);
    ushort* cs  = (ushort*)(ws + OFF_CS);
    ushort* xbf = (ushort*)(ws + OFF_XS);   // x bf16, dead once conv_k writes xs
    ushort* yn  = (ushort*)(ws + OFF_XS);   // aliases xs (dead after ssd)
    ushort* dd  = (ushort*)(ws + OFF_DD);   // aliases zx (dead after grms)
    float*  hb  = (float*)(ws + OFF_H);
    ushort* wo  = (ushort*)(ws + OFF_WO);
    ushort* wp  = (ushort*)(ws + OFF_WP);

    // K0: bf16 conversions needed before in_proj (one launch)
    cvt3_k<<<dim3(2 * DPROJ + MROWS), 256, 0, stream>>>(
        f_inw, b_inw, x, wbf, wbf + (size_t)DPROJ * DMODEL, xbf, DPROJ, DPROJ);

    // K1: in_proj, N=4256, K=1024, BN=128, BK=64
    gemm_k<0, 128><<<dim3((DPROJ + 127) / 128, MROWS / 128, 2), 256, 0, stream>>>(
        xbf, wbf, (size_t)DPROJ * DMODEL, (void*)zx, nullptr, nullptr, dtr,
        DPROJ, DMODEL);

    // K2: conv + activations (overwrites xbf region with xs)
    conv_k<<<dim3(2 * MROWS), 256, 0, stream>>>(
        zx, dtr, f_cw, f_cb, b_cw, b_cb, f_dtb, f_al, b_dtb, b_al,
        xs, Bq, Cq, dtq, ldq);

    // K3: chunked SSD (states / stitch / intra-chunk matmul)
    states_k<<<dim3(128, NCHUNK), 256, 0, stream>>>(Bq, dtq, ldq, xs, cs);
    stitch_k<<<dim3(128), 256, 0, stream>>>(ldq, cs);
    ssd_k<<<dim3(128, NCHUNK), 256, 0, stream>>>(
        Bq, Cq, dtq, ldq, xs, cs, f_Dp, b_Dp, zx);

    // K4: gated RMSNorm (last reader of zx)
    grms_k<<<dim3(2 * MROWS), 256, 0, stream>>>(zx, f_rw, b_rw, yn);

    // K4b: convert out_proj/final weights into dead zx region (one launch)
    cvt3_k<<<dim3(3 * MROWS), 256, 0, stream>>>(
        f_ow, b_ow, projw, wo, wo + (size_t)DMODEL * DINNER, wp, MROWS, MROWS);

    // K5: out_proj, N=1024, K=2048, BN=64, BK=64; packs [dou0|flip(dou1)] into dd
    gemm_k<1, 64><<<dim3(DMODEL / 64, MROWS / 128, 2), 256, 0, stream>>>(
        yn, wo, (size_t)DMODEL * DINNER, (void*)dd, nullptr, nullptr, nullptr,
        DMODEL, DINNER);

    // K6: final proj + residual + bias, N=1024, K=2048 (fp32 out)
    gemm_k<2, 64><<<dim3(DMODEL / 64, MROWS / 128, 1), 256, 0, stream>>>(
        dd, wp, 0, (void*)hb, x, projb, nullptr, DMODEL, DINNER);

    // K7: LayerNorm -> fp32 out
    ln_k<<<dim3(MROWS), 256, 0, stream>>>(hb, lnw, lnb, (float*)d_out);
}

// Round 13
// 350.615 us; speedup vs baseline: 2.9599x; 1.0335x over previous
//
#include <hip/hip_runtime.h>
#include <hip/hip_bf16.h>

#define DEV __device__ __forceinline__

typedef short bf16x8 __attribute__((ext_vector_type(8)));
typedef float f32x4 __attribute__((ext_vector_type(4)));

static constexpr int BATCH  = 2;
static constexpr int SEQ    = 1024;
static constexpr int DMODEL = 1024;
static constexpr int DINNER = 2048;
static constexpr int DSTATE = 64;
static constexpr int NH     = 32;
static constexpr int HD     = 64;
static constexpr int CONVD  = 2176;
static constexpr int DPROJ  = 4256;
static constexpr int MROWS  = BATCH * SEQ;   // 2048
static constexpr int NCHUNK = 16;
static constexpr int QC     = 64;

// ---- workspace layout (bytes) ---- peak 74.8 MB (proven)
static constexpr size_t OFF_ZX = 0;                                  // bf16 [4096][4256]
static constexpr size_t OFF_XS = OFF_ZX + (size_t)2*MROWS*DPROJ*2;   // bf16 [4096][2048]; xbf pre-conv, xs after, yn after ssd
static constexpr size_t OFF_BB = OFF_XS + (size_t)2*MROWS*DINNER*2;  // f32 [4096][64]
static constexpr size_t OFF_CC = OFF_BB + (size_t)2*MROWS*DSTATE*4;  // f32 [4096][64]
static constexpr size_t OFF_DT = OFF_CC + (size_t)2*MROWS*DSTATE*4;  // f32 [4][32][1024] dt
static constexpr size_t OFF_DA = OFF_DT + (size_t)2*MROWS*NH*4;      // f32 [4][32][1024] ldA
static constexpr size_t OFF_DR = OFF_DA + (size_t)2*MROWS*NH*4;      // f32 [4096][32] raw dt spill
// CS region (16.8 MB), time-shared:
//  (a) bf16 in_proj weights [2][4256][1024] until gemm0
//  (b) chunk states [128][16][64][64] until ssd
//  (c) wo (bf16 [2][1024][2048], 8.4MB) + wp (bf16 [1024][2048], 4.2MB) after ssd
static constexpr size_t OFF_CS = OFF_DR + (size_t)2*MROWS*NH*4;
static constexpr size_t OFF_WO = OFF_CS;
static constexpr size_t OFF_WP = OFF_CS + (size_t)2*DMODEL*DINNER*2;
// aliased into zx (dead after grms):
static constexpr size_t OFF_DD = 0;                                  // bf16 [2048][2048] packed dir outs
static constexpr size_t OFF_H  = OFF_DD + (size_t)MROWS*2*DMODEL;    // f32 [2048][1024]

DEV float b2f(ushort u) {
    union { unsigned int i; float f; } v;
    v.i = ((unsigned int)u) << 16;
    return v.f;
}
DEV ushort f2b(float f) {
    union { float f; unsigned int u; } v;
    v.f = f;
    unsigned int r = 0x7FFFu + ((v.u >> 16) & 1u);
    return (ushort)((v.u + r) >> 16);
}
DEV bf16x8 pack8(float4 a, float4 b) {
    bf16x8 r;
    r[0] = (short)f2b(a.x); r[1] = (short)f2b(a.y);
    r[2] = (short)f2b(a.z); r[3] = (short)f2b(a.w);
    r[4] = (short)f2b(b.x); r[5] = (short)f2b(b.y);
    r[6] = (short)f2b(b.z); r[7] = (short)f2b(b.w);
    return r;
}
DEV void gll16(const ushort* g, ushort* l) {
    __builtin_amdgcn_global_load_lds(
        (const __attribute__((address_space(1))) unsigned int*)g,
        (__attribute__((address_space(3))) unsigned int*)l, 16, 0, 0);
}

// ---------------------------------------------------------------------------
// cvt3: three fp32->bf16 conversions in one launch (rows of 1024 floats).
// ---------------------------------------------------------------------------
__global__ __launch_bounds__(256) void cvt3_k(
    const float* __restrict__ s0, const float* __restrict__ s1,
    const float* __restrict__ s2,
    ushort* __restrict__ d0, ushort* __restrict__ d1, ushort* __restrict__ d2,
    int b0, int b1)
{
    int blk = blockIdx.x;
    const float* s; ushort* d; size_t off;
    if (blk < b0)            { s = s0; d = d0; off = (size_t)blk * 1024; }
    else if (blk < b0 + b1)  { s = s1; d = d1; off = (size_t)(blk - b0) * 1024; }
    else                     { s = s2; d = d2; off = (size_t)(blk - b0 - b1) * 1024; }
    size_t i = off + threadIdx.x * 4;
    float4 f = *(const float4*)(s + i);
    ushort4 u;
    u.x = f2b(f.x); u.y = f2b(f.y); u.z = f2b(f.z); u.w = f2b(f.w);
    *(ushort4*)(d + i) = u;
}

// ---------------------------------------------------------------------------
// GEMM: C[m][n] = sum_k A[m][k]*W[n][k], all bf16, global_load_lds width-16
// staging, BM=128, BN ∈ {64,128}, BK ∈ {64,128}.
// Generalized XOR swizzle: LDS[row][slot] holds global colgroup
// slot ^ (row mod BK/8) (16 B groups) -> conflict-free ds_read_b128.
// MODE 0: bn tiles remapped (bx+2*by)%gridX for XCD-stable W partition.
// ---------------------------------------------------------------------------
template<int MODE, int BN, int BK>
__global__ __launch_bounds__(256) void gemm_k(
    const ushort* __restrict__ A, const ushort* __restrict__ W,
    size_t wstride, void* __restrict__ outp, const float* __restrict__ resid,
    const float* __restrict__ bias, float* __restrict__ dtraw,
    int N, int K)
{
    constexpr int BM = 128;
    constexpr int MT = (BN == 128) ? 4 : 2;
    constexpr int NSL = BK / 8;          // 16B slots per LDS row
    constexpr int RPG = 64 / NSL;        // rows per gll group
    constexpr int NAG = BM / RPG / 4;    // A gll groups per wave
    constexpr int NBG = BN / RPG / 4;    // B gll groups per wave
    __shared__ ushort As[BM * BK];
    __shared__ ushort Bs[BN * BK];
    const int tid = threadIdx.x;
    const int wave = tid >> 6, lane = tid & 63;
    const int quad = lane >> 4, l16 = lane & 15;
    const int bxu = (MODE == 0)
        ? (int)((blockIdx.x + 2 * blockIdx.y) % gridDim.x) : (int)blockIdx.x;
    const int bn = bxu * BN, bm = blockIdx.y * BM;
    const int dir = blockIdx.z;
    const ushort* Wd = W + (size_t)dir * wstride;
    const int wmoff = (BN == 128) ? (wave >> 1) * 64 : wave * 32;
    const int wnoff = (BN == 128) ? (wave & 1) * 64 : 0;

    const int lrow = lane / NSL, lslot = lane % NSL;
    const ushort* aga[NAG];
    ushort* ald[NAG];
    #pragma unroll
    for (int t = 0; t < NAG; t++) {
        int li = wave * NAG + t;
        int absr = li * RPG + lrow;
        int m = bm + absr;
        size_t rowidx;
        if (MODE == 0) {
            int b = m >> 10, l = m & 1023;
            int ls = dir ? (1023 - l) : l;
            rowidx = (size_t)((b << 10) + ls);
        } else if (MODE == 1) {
            rowidx = (size_t)(dir * MROWS + m);
        } else {
            rowidx = (size_t)m;
        }
        aga[t] = A + rowidx * K + (lslot ^ (absr % NSL)) * 8;
        ald[t] = &As[li * 512];
    }
    const ushort* bga[NBG];
    ushort* bld[NBG];
    #pragma unroll
    for (int t = 0; t < NBG; t++) {
        int li = wave * NBG + t;
        int absr = li * RPG + lrow;
        int n = bn + absr;
        if (n >= N) n = N - 1;            // clamp; cols >= N discarded
        bga[t] = Wd + (size_t)n * K + (lslot ^ (absr % NSL)) * 8;
        bld[t] = &Bs[li * 512];
    }

    f32x4 acc[MT][4] = {};

    for (int k0 = 0; k0 < K; k0 += BK) {
        #pragma unroll
        for (int t = 0; t < NAG; t++) gll16(aga[t] + k0, ald[t]);
        #pragma unroll
        for (int t = 0; t < NBG; t++) gll16(bga[t] + k0, bld[t]);
        __syncthreads();

        #pragma unroll
        for (int kt = 0; kt < BK / 32; kt++) {
            const int rs = (((kt * 4 + quad) ^ (l16 % NSL))) * 8;
            bf16x8 af[MT], bfr[4];
            #pragma unroll
            for (int mt = 0; mt < MT; mt++)
                af[mt] = *(const bf16x8*)&As[(wmoff + mt * 16 + l16) * BK + rs];
            #pragma unroll
            for (int nt = 0; nt < 4; nt++)
                bfr[nt] = *(const bf16x8*)&Bs[(wnoff + nt * 16 + l16) * BK + rs];
            #pragma unroll
            for (int mt = 0; mt < MT; mt++)
                #pragma unroll
                for (int nt = 0; nt < 4; nt++)
                    acc[mt][nt] = __builtin_amdgcn_mfma_f32_16x16x32_bf16(
                        af[mt], bfr[nt], acc[mt][nt], 0, 0, 0);
        }
        __syncthreads();
    }

    // epilogue: C/D layout row=quad*4+j, col=l16
    #pragma unroll
    for (int mt = 0; mt < MT; mt++) {
        #pragma unroll
        for (int nt = 0; nt < 4; nt++) {
            #pragma unroll
            for (int j = 0; j < 4; j++) {
                int row = bm + wmoff + mt * 16 + quad * 4 + j;
                int col = bn + wnoff + nt * 16 + l16;
                if (col >= N) continue;
                float v = acc[mt][nt][j];
                if (MODE == 0) {
                    ((ushort*)outp)[(size_t)(dir * MROWS + row) * DPROJ + col] = f2b(v);
                    if (col >= 4224)
                        dtraw[(size_t)(dir * MROWS + row) * NH + (col - 4224)] = v;
                } else if (MODE == 1) {
                    int mr = dir ? ((row & 1024) | (1023 - (row & 1023))) : row;
                    ((ushort*)outp)[(size_t)mr * (2 * DMODEL) + dir * DMODEL + col] = f2b(v);
                } else {
                    float r = resid[(size_t)row * DMODEL + col] + bias[col];
                    ((float*)outp)[(size_t)row * DMODEL + col] = v + r;
                }
            }
        }
    }
}

// ---------------------------------------------------------------------------
// causal depthwise conv(width 4) + bias + SiLU — vectorized 4 chans/thread.
// dt = softplus(raw+bias); ldA = A*dt. dt/ldA TRANSPOSED: [dirb*32+h][l]
// ---------------------------------------------------------------------------
__global__ __launch_bounds__(256) void conv_k(
    const ushort* __restrict__ zx, const float* __restrict__ dtr,
    const float* __restrict__ cw0, const float* __restrict__ cb0,
    const float* __restrict__ cw1, const float* __restrict__ cb1,
    const float* __restrict__ dtb0, const float* __restrict__ al0,
    const float* __restrict__ dtb1, const float* __restrict__ al1,
    ushort* __restrict__ xs, float* __restrict__ Bq, float* __restrict__ Cq,
    float* __restrict__ dtq, float* __restrict__ ldq)
{
    int id = blockIdx.x;
    int dir = id >> 11;
    int m = id & 2047;
    int l = m & 1023;
    const float* cw = dir ? cw1 : cw0;
    const float* cb = dir ? cb1 : cb0;
    int tid = threadIdx.x;

    for (int c = tid * 4; c < CONVD; c += 1024) {
        float4 cbv = *(const float4*)&cb[c];
        float acc[4] = { cbv.x, cbv.y, cbv.z, cbv.w };
        #pragma unroll
        for (int t = 0; t < 4; t++) {
            int ls = l - 3 + t;
            if (ls >= 0) {
                float4 wv = *(const float4*)&cw[t * CONVD + c];
                ushort4 xv = *(const ushort4*)&zx[(size_t)(id - l + ls) * DPROJ + 2048 + c];
                acc[0] += wv.x * b2f(xv.x);
                acc[1] += wv.y * b2f(xv.y);
                acc[2] += wv.z * b2f(xv.z);
                acc[3] += wv.w * b2f(xv.w);
            }
        }
        float v[4];
        #pragma unroll
        for (int i = 0; i < 4; i++) v[i] = acc[i] / (1.f + expf(-acc[i]));
        if (c < DINNER) {
            ushort4 u;
            u.x = f2b(v[0]); u.y = f2b(v[1]); u.z = f2b(v[2]); u.w = f2b(v[3]);
            *(ushort4*)&xs[(size_t)id * DINNER + c] = u;
        } else if (c < DINNER + DSTATE) {
            *(float4*)&Bq[(size_t)id * DSTATE + (c - DINNER)] =
                make_float4(v[0], v[1], v[2], v[3]);
        } else {
            *(float4*)&Cq[(size_t)id * DSTATE + (c - DINNER - DSTATE)] =
                make_float4(v[0], v[1], v[2], v[3]);
        }
    }
    if (tid < NH) {
        const float* dtb = dir ? dtb1 : dtb0;
        const float* al  = dir ? al1 : al0;
        float raw = dtr[(size_t)id * NH + tid] + dtb[tid];
        float dt = raw > 20.f ? raw : log1pf(expf(raw));
        float ldA = -expf(al[tid]) * dt;
        int dirb = id >> 10;
        dtq[(size_t)(dirb * NH + tid) * SEQ + l] = dt;
        ldq[(size_t)(dirb * NH + tid) * SEQ + l] = ldA;
    }
}

// ---------------------------------------------------------------------------
// states_k: chunk-local end state via MFMA.
// ---------------------------------------------------------------------------
__global__ __launch_bounds__(256) void states_k(
    const float* __restrict__ Bq, const float* __restrict__ dtT,
    const float* __restrict__ ldT, const ushort* __restrict__ xsq,
    ushort* __restrict__ cs)
{
    int id = blockIdx.x;
    int h = id & 31;
    int c = blockIdx.y;
    int tid = threadIdx.x;
    int wave = tid >> 6, lane = tid & 63;
    int quad = lane >> 4;
    int base = (id >> 5) << 10;
    int l0 = c * QC;

    __shared__ float wsh[QC];
    __shared__ ushort Xw[64][80];
    __shared__ ushort Bt[64][72];

    if (tid < 64) {
        float ld = ldT[(size_t)id * SEQ + l0 + tid];
        #pragma unroll
        for (int st = 1; st < 64; st <<= 1) {
            float o = __shfl_up(ld, st);
            if (tid >= st) ld += o;
        }
        float tot = __shfl(ld, 63);
        wsh[tid] = dtT[(size_t)id * SEQ + l0 + tid] * expf(tot - ld);
    }
    __syncthreads();

    {
        int j = tid >> 2, p0 = (tid & 3) * 16;
        float wj = wsh[j];
        const ushort* xrow = xsq + (size_t)(base + l0 + j) * DINNER + h * HD + p0;
        #pragma unroll
        for (int q = 0; q < 4; q++) {
            ushort4 xv = *(const ushort4*)(xrow + q * 4);
            Xw[p0 + q * 4 + 0][j] = f2b(b2f(xv.x) * wj);
            Xw[p0 + q * 4 + 1][j] = f2b(b2f(xv.y) * wj);
            Xw[p0 + q * 4 + 2][j] = f2b(b2f(xv.z) * wj);
            Xw[p0 + q * 4 + 3][j] = f2b(b2f(xv.w) * wj);
        }
        int j2 = lane, ng = wave * 16;
        const float* brow = Bq + (size_t)(base + l0 + j2) * DSTATE + ng;
        #pragma unroll
        for (int q = 0; q < 4; q++) {
            float4 f = *(const float4*)(brow + q * 4);
            Bt[ng + q * 4 + 0][j2] = f2b(f.x);
            Bt[ng + q * 4 + 1][j2] = f2b(f.y);
            Bt[ng + q * 4 + 2][j2] = f2b(f.z);
            Bt[ng + q * 4 + 3][j2] = f2b(f.w);
        }
    }
    __syncthreads();

    f32x4 acc[4] = {};
    #pragma unroll
    for (int kt = 0; kt < 2; kt++) {
        int k = kt * 32 + quad * 8;
        bf16x8 af = *(const bf16x8*)&Xw[wave * 16 + (lane & 15)][k];
        #pragma unroll
        for (int ni = 0; ni < 4; ni++) {
            bf16x8 bf = *(const bf16x8*)&Bt[ni * 16 + (lane & 15)][k];
            acc[ni] = __builtin_amdgcn_mfma_f32_16x16x32_bf16(af, bf, acc[ni], 0, 0, 0);
        }
    }

    ushort* out = cs + ((size_t)id * NCHUNK + c) * HD * DSTATE;
    #pragma unroll
    for (int ni = 0; ni < 4; ni++) {
        #pragma unroll
        for (int j = 0; j < 4; j++) {
            int p = wave * 16 + quad * 4 + j;
            int n = ni * 16 + (lane & 15);
            out[(size_t)p * DSTATE + n] = f2b(acc[ni][j]);
        }
    }
}

// ---------------------------------------------------------------------------
// Stitch: H_{c+1} = S_c + exp(sum ldA) * H_c (in place -> chunk-start H_c)
// ---------------------------------------------------------------------------
__global__ __launch_bounds__(256) void stitch_k(
    const float* __restrict__ ldT, ushort* __restrict__ cs)
{
    int id = blockIdx.x;
    int tid = threadIdx.x;
    __shared__ float red[256];
    __shared__ float dec[NCHUNK];

    float4 d4 = *(const float4*)(ldT + (size_t)id * SEQ + tid * 4);
    red[tid] = d4.x + d4.y + d4.z + d4.w;
    __syncthreads();
    if (tid < NCHUNK) {
        float s = 0.f;
        #pragma unroll
        for (int i = 0; i < 16; i++) s += red[tid * 16 + i];
        dec[tid] = expf(s);
    }
    __syncthreads();

    int p = tid >> 2, n0 = (tid & 3) * 16;
    ushort* ptr = cs + (size_t)id * NCHUNK * HD * DSTATE + p * DSTATE + n0;

    float st[16];
    #pragma unroll
    for (int i = 0; i < 16; i++) st[i] = 0.f;

    for (int c = 0; c < NCHUNK; c++) {
        ushort* row = ptr + (size_t)c * HD * DSTATE;
        float tmp[16];
        #pragma unroll
        for (int i = 0; i < 16; i++) tmp[i] = b2f(row[i]);
        #pragma unroll
        for (int i = 0; i < 16; i++) row[i] = f2b(st[i]);
        float d = dec[c];
        #pragma unroll
        for (int i = 0; i < 16; i++) st[i] = fmaf(d, st[i], tmp[i]);
    }
}

// ---------------------------------------------------------------------------
// ssd_k: intra-chunk SSD matmul + seed + D*x
// ---------------------------------------------------------------------------
__global__ __launch_bounds__(256) void ssd_k(
    const float* __restrict__ Bq, const float* __restrict__ Cq,
    const float* __restrict__ dtT, const float* __restrict__ ldT,
    const ushort* __restrict__ xsq, const ushort* __restrict__ cs,
    const float* __restrict__ D0, const float* __restrict__ D1,
    ushort* __restrict__ yout)
{
    int id = blockIdx.x;
    int dir = id >> 6, h = id & 31;
    int c = blockIdx.y;
    int tid = threadIdx.x;
    int wave = tid >> 6, lane = tid & 63;
    int quad = lane >> 4;
    int base = (id >> 5) << 10;
    int l0 = c * QC;

    __shared__ float cum[QC], dts[QC];
    __shared__ ushort Ms[64][72];
    __shared__ ushort Xb[64][80];

    {
        int j = tid >> 2, p0 = (tid & 3) * 16;
        const ushort* xrow = xsq + (size_t)(base + l0 + j) * DINNER + h * HD + p0;
        #pragma unroll
        for (int q = 0; q < 4; q++) {
            ushort4 xv = *(const ushort4*)(xrow + q * 4);
            Xb[p0 + q * 4 + 0][j] = xv.x;
            Xb[p0 + q * 4 + 1][j] = xv.y;
            Xb[p0 + q * 4 + 2][j] = xv.z;
            Xb[p0 + q * 4 + 3][j] = xv.w;
        }
    }
    if (tid < 64) {
        float ld = ldT[(size_t)id * SEQ + l0 + tid];
        #pragma unroll
        for (int st = 1; st < 64; st <<= 1) {
            float o = __shfl_up(ld, st);
            if (tid >= st) ld += o;
        }
        cum[tid] = ld;
        dts[tid] = dtT[(size_t)id * SEQ + l0 + tid];
    }

    f32x4 sacc[4] = {};
    #pragma unroll
    for (int kt = 0; kt < 2; kt++) {
        int k = kt * 32 + quad * 8;
        const float* cp = Cq + (size_t)(base + l0 + wave * 16 + (lane & 15)) * DSTATE + k;
        bf16x8 af = pack8(*(const float4*)cp, *(const float4*)(cp + 4));
        #pragma unroll
        for (int ni = 0; ni < 4; ni++) {
            const float* bp = Bq + (size_t)(base + l0 + ni * 16 + (lane & 15)) * DSTATE + k;
            bf16x8 bf = pack8(*(const float4*)bp, *(const float4*)(bp + 4));
            sacc[ni] = __builtin_amdgcn_mfma_f32_16x16x32_bf16(af, bf, sacc[ni], 0, 0, 0);
        }
    }
    __syncthreads();

    #pragma unroll
    for (int ni = 0; ni < 4; ni++) {
        int j = ni * 16 + (lane & 15);
        float cj = cum[j], dj = dts[j];
        #pragma unroll
        for (int r = 0; r < 4; r++) {
            int l = wave * 16 + quad * 4 + r;
            float v = 0.f;
            if (l >= j) v = expf(cum[l] - cj) * dj * sacc[ni][r];
            Ms[l][j] = f2b(v);
        }
    }
    __syncthreads();

    f32x4 acc[4] = {};
    #pragma unroll
    for (int kt = 0; kt < 2; kt++) {
        int k = kt * 32 + quad * 8;
        bf16x8 af = *(const bf16x8*)&Ms[wave * 16 + (lane & 15)][k];
        #pragma unroll
        for (int ni = 0; ni < 4; ni++) {
            bf16x8 bf = *(const bf16x8*)&Xb[ni * 16 + (lane & 15)][k];
            acc[ni] = __builtin_amdgcn_mfma_f32_16x16x32_bf16(af, bf, acc[ni], 0, 0, 0);
        }
    }
    const ushort* Hrow = cs + ((size_t)id * NCHUNK + c) * HD * DSTATE;
    {
        float cl = expf(cum[wave * 16 + (lane & 15)]);
        #pragma unroll
        for (int kt = 0; kt < 2; kt++) {
            int k = kt * 32 + quad * 8;
            const float* cp = Cq + (size_t)(base + l0 + wave * 16 + (lane & 15)) * DSTATE + k;
            float4 c0 = *(const float4*)cp;
            float4 c1 = *(const float4*)(cp + 4);
            float4 s0 = {c0.x * cl, c0.y * cl, c0.z * cl, c0.w * cl};
            float4 s1 = {c1.x * cl, c1.y * cl, c1.z * cl, c1.w * cl};
            bf16x8 af = pack8(s0, s1);
            #pragma unroll
            for (int ni = 0; ni < 4; ni++) {
                bf16x8 bf = *(const bf16x8*)(Hrow + (size_t)(ni * 16 + (lane & 15)) * DSTATE + k);
                acc[ni] = __builtin_amdgcn_mfma_f32_16x16x32_bf16(af, bf, acc[ni], 0, 0, 0);
            }
        }
    }

    float Dv = (dir ? D1 : D0)[h];
    int lb = wave * 16 + quad * 4;
    #pragma unroll
    for (int ni = 0; ni < 4; ni++) {
        int p = ni * 16 + (lane & 15);
        ushort4 x4 = *(const ushort4*)&Xb[p][lb];
        float xv[4] = { b2f(x4.x), b2f(x4.y), b2f(x4.z), b2f(x4.w) };
        #pragma unroll
        for (int r = 0; r < 4; r++) {
            int l = lb + r;
            yout[(size_t)(base + l0 + l) * DPROJ + 2048 + h * HD + p] =
                f2b(acc[ni][r] + Dv * xv[r]);
        }
    }
}

// ---------------------------------------------------------------------------
// gated RMSNorm (blocks 0..4095) fused with out_proj/final weight conversion
// (blocks 4096..10239; wo/wp live in the CS region — disjoint from zx).
// ---------------------------------------------------------------------------
__global__ __launch_bounds__(256) void grms_cvt_k(
    const ushort* __restrict__ zx,
    const float* __restrict__ rw0, const float* __restrict__ rw1,
    ushort* __restrict__ yn,
    const float* __restrict__ fow, const float* __restrict__ bow,
    const float* __restrict__ pw,
    ushort* __restrict__ wo, ushort* __restrict__ wp)
{
    int blk = blockIdx.x;
    int tid = threadIdx.x;
    if (blk >= 4096) {
        int b = blk - 4096;                 // 0..6143, rows of 1024 floats
        const float* s; ushort* d; size_t off;
        if (b < 2048)      { s = fow; d = wo;                           off = (size_t)b * 1024; }
        else if (b < 4096) { s = bow; d = wo + (size_t)DMODEL * DINNER; off = (size_t)(b - 2048) * 1024; }
        else               { s = pw;  d = wp;                           off = (size_t)(b - 4096) * 1024; }
        size_t i = off + tid * 4;
        float4 f = *(const float4*)(s + i);
        ushort4 u;
        u.x = f2b(f.x); u.y = f2b(f.y); u.z = f2b(f.z); u.w = f2b(f.w);
        *(ushort4*)(d + i) = u;
        return;
    }
    int id = blk;
    int dir = id >> 11;
    const float* rw = dir ? rw1 : rw0;
    int c0 = tid * 8;
    ushort zv[8], yv[8];
    *(uint4*)zv = *(const uint4*)&zx[(size_t)id * DPROJ + c0];
    *(uint4*)yv = *(const uint4*)&zx[(size_t)id * DPROJ + 2048 + c0];
    float g[8];
    float ss = 0.f;
    #pragma unroll
    for (int i = 0; i < 8; i++) {
        float z = b2f(zv[i]);
        float v = b2f(yv[i]) * (z / (1.f + expf(-z)));
        g[i] = v;
        ss += v * v;
    }
    for (int o = 32; o; o >>= 1) ss += __shfl_down(ss, o);
    __shared__ float t4[4];
    if ((tid & 63) == 0) t4[tid >> 6] = ss;
    __syncthreads();
    ss = t4[0] + t4[1] + t4[2] + t4[3];
    float sc = rsqrtf(ss * (1.f / DINNER) + 1e-5f);
    ushort u[8];
    #pragma unroll
    for (int i = 0; i < 8; i++) u[i] = f2b(g[i] * sc * rw[c0 + i]);
    *(uint4*)&yn[(size_t)id * DINNER + c0] = *(uint4*)u;
}

// ---------------------------------------------------------------------------
// LayerNorm -> fp32 out — vectorized: one float4/thread.
// ---------------------------------------------------------------------------
__global__ __launch_bounds__(256) void ln_k(
    const float* __restrict__ h, const float* __restrict__ lw,
    const float* __restrict__ lb, float* __restrict__ out)
{
    int m = blockIdx.x;
    int tid = threadIdx.x;
    int c = tid * 4;
    float4 v = *(const float4*)&h[(size_t)m * DMODEL + c];
    float s  = v.x + v.y + v.z + v.w;
    float s2 = v.x * v.x + v.y * v.y + v.z * v.z + v.w * v.w;
    for (int o = 32; o; o >>= 1) { s += __shfl_down(s, o); s2 += __shfl_down(s2, o); }
    __shared__ float ts[4], ts2[4];
    if ((tid & 63) == 0) { ts[tid >> 6] = s; ts2[tid >> 6] = s2; }
    __syncthreads();
    s  = ts[0] + ts[1] + ts[2] + ts[3];
    s2 = ts2[0] + ts2[1] + ts2[2] + ts2[3];
    float mu  = s * (1.f / DMODEL);
    float var = s2 * (1.f / DMODEL) - mu * mu;
    float sc  = rsqrtf(var + 1e-5f);
    float4 w4 = *(const float4*)&lw[c];
    float4 b4 = *(const float4*)&lb[c];
    float4 o4;
    o4.x = (v.x - mu) * sc * w4.x + b4.x;
    o4.y = (v.y - mu) * sc * w4.y + b4.y;
    o4.z = (v.z - mu) * sc * w4.z + b4.z;
    o4.w = (v.w - mu) * sc * w4.w + b4.w;
    *(float4*)&out[(size_t)m * DMODEL + c] = o4;
}

extern "C" void kernel_launch(void* const* d_in, const int* in_sizes, int n_in,
                              void* d_out, int out_size, void* d_ws, size_t ws_size,
                              hipStream_t stream)
{
    const float* x     = (const float*)d_in[0];
    const float* f_inw = (const float*)d_in[1];
    const float* f_cw  = (const float*)d_in[2];
    const float* f_cb  = (const float*)d_in[3];
    const float* f_dtb = (const float*)d_in[4];
    const float* f_al  = (const float*)d_in[5];
    const float* f_Dp  = (const float*)d_in[6];
    const float* f_rw  = (const float*)d_in[7];
    const float* f_ow  = (const float*)d_in[8];
    const float* b_inw = (const float*)d_in[9];
    const float* b_cw  = (const float*)d_in[10];
    const float* b_cb  = (const float*)d_in[11];
    const float* b_dtb = (const float*)d_in[12];
    const float* b_al  = (const float*)d_in[13];
    const float* b_Dp  = (const float*)d_in[14];
    const float* b_rw  = (const float*)d_in[15];
    const float* b_ow  = (const float*)d_in[16];
    const float* projw = (const float*)d_in[17];
    const float* projb = (const float*)d_in[18];
    const float* lnw   = (const float*)d_in[19];
    const float* lnb   = (const float*)d_in[20];

    char* ws = (char*)d_ws;
    ushort* zx  = (ushort*)(ws + OFF_ZX);
    ushort* xs  = (ushort*)(ws + OFF_XS);
    float*  Bq  = (float*)(ws + OFF_BB);
    float*  Cq  = (float*)(ws + OFF_CC);
    float*  dtq = (float*)(ws + OFF_DT);
    float*  ldq = (float*)(ws + OFF_DA);
    float*  dtr = (float*)(ws + OFF_DR);
    ushort* wbf = (ushort*)(ws + OFF_CS);
    ushort* cs  = (ushort*)(ws + OFF_CS);
    ushort* xbf = (ushort*)(ws + OFF_XS);   // x bf16, dead once conv_k writes xs
    ushort* yn  = (ushort*)(ws + OFF_XS);   // aliases xs (dead after ssd)
    ushort* dd  = (ushort*)(ws + OFF_DD);   // aliases zx (dead after grms)
    float*  hb  = (float*)(ws + OFF_H);
    ushort* wo  = (ushort*)(ws + OFF_WO);   // CS region (dead after ssd)
    ushort* wp  = (ushort*)(ws + OFF_WP);

    // K0: bf16 conversions needed before in_proj (one launch)
    cvt3_k<<<dim3(2 * DPROJ + MROWS), 256, 0, stream>>>(
        f_inw, b_inw, x, wbf, wbf + (size_t)DPROJ * DMODEL, xbf, DPROJ, DPROJ);

    // K1: in_proj, N=4256, K=1024, BN=128, BK=64
    gemm_k<0, 128, 64><<<dim3((DPROJ + 127) / 128, MROWS / 128, 2), 256, 0, stream>>>(
        xbf, wbf, (size_t)DPROJ * DMODEL, (void*)zx, nullptr, nullptr, dtr,
        DPROJ, DMODEL);

    // K2: conv + activations (overwrites xbf region with xs)
    conv_k<<<dim3(2 * MROWS), 256, 0, stream>>>(
        zx, dtr, f_cw, f_cb, b_cw, b_cb, f_dtb, f_al, b_dtb, b_al,
        xs, Bq, Cq, dtq, ldq);

    // K3: chunked SSD (states / stitch / intra-chunk matmul)
    states_k<<<dim3(128, NCHUNK), 256, 0, stream>>>(Bq, dtq, ldq, xs, cs);
    stitch_k<<<dim3(128), 256, 0, stream>>>(ldq, cs);
    ssd_k<<<dim3(128, NCHUNK), 256, 0, stream>>>(
        Bq, Cq, dtq, ldq, xs, cs, f_Dp, b_Dp, zx);

    // K4: gated RMSNorm + weight conversions (CS region now dead) fused
    grms_cvt_k<<<dim3(4096 + 3 * MROWS), 256, 0, stream>>>(
        zx, f_rw, b_rw, yn, f_ow, b_ow, projw, wo, wp);

    // K5: out_proj, N=1024, K=2048, BN=64, BK=128; packs [dou0|flip(dou1)] into dd
    gemm_k<1, 64, 128><<<dim3(DMODEL / 64, MROWS / 128, 2), 256, 0, stream>>>(
        yn, wo, (size_t)DMODEL * DINNER, (void*)dd, nullptr, nullptr, nullptr,
        DMODEL, DINNER);

    // K6: final proj + residual + bias, N=1024, K=2048, BN=64, BK=128 (fp32 out)
    gemm_k<2, 64, 128><<<dim3(DMODEL / 64, MROWS / 128, 1), 256, 0, stream>>>(
        dd, wp, 0, (void*)hb, x, projb, nullptr, DMODEL, DINNER);

    // K7: LayerNorm -> fp32 out
    ln_k<<<dim3(MROWS), 256, 0, stream>>>(hb, lnw, lnb, (float*)d_out);
}

// Round 14
// 347.184 us; speedup vs baseline: 2.9892x; 1.0099x over previous
//
#include <hip/hip_runtime.h>
#include <hip/hip_bf16.h>

#define DEV __device__ __forceinline__

typedef short bf16x8 __attribute__((ext_vector_type(8)));
typedef float f32x4 __attribute__((ext_vector_type(4)));

static constexpr int BATCH  = 2;
static constexpr int SEQ    = 1024;
static constexpr int DMODEL = 1024;
static constexpr int DINNER = 2048;
static constexpr int DSTATE = 64;
static constexpr int NH     = 32;
static constexpr int HD     = 64;
static constexpr int CONVD  = 2176;
static constexpr int DPROJ  = 4256;
static constexpr int MROWS  = BATCH * SEQ;   // 2048
static constexpr int NCHUNK = 16;
static constexpr int QC     = 64;

// ---- workspace layout (bytes) ---- peak 74.8 MB (proven)
static constexpr size_t OFF_ZX = 0;                                  // bf16 [4096][4256]
static constexpr size_t OFF_XS = OFF_ZX + (size_t)2*MROWS*DPROJ*2;   // bf16 [4096][2048]; xbf pre-conv, xs after, yn after ssd
static constexpr size_t OFF_BB = OFF_XS + (size_t)2*MROWS*DINNER*2;  // f32 [4096][64]
static constexpr size_t OFF_CC = OFF_BB + (size_t)2*MROWS*DSTATE*4;  // f32 [4096][64]
static constexpr size_t OFF_DT = OFF_CC + (size_t)2*MROWS*DSTATE*4;  // f32 [4][32][1024] dt
static constexpr size_t OFF_DA = OFF_DT + (size_t)2*MROWS*NH*4;      // f32 [4][32][1024] ldA
static constexpr size_t OFF_DR = OFF_DA + (size_t)2*MROWS*NH*4;      // f32 [4096][32] raw dt spill
// CS region (16.8 MB), time-shared:
//  (a) bf16 in_proj weights [2][4256][1024] until gemm0
//  (b) chunk states [128][16][64][64] until ssd
//  (c) wo (bf16 [2][1024][2048], 8.4MB) + wp (bf16 [1024][2048], 4.2MB) after ssd
static constexpr size_t OFF_CS = OFF_DR + (size_t)2*MROWS*NH*4;
static constexpr size_t OFF_WO = OFF_CS;
static constexpr size_t OFF_WP = OFF_CS + (size_t)2*DMODEL*DINNER*2;
// aliased into zx (dead after grms):
static constexpr size_t OFF_DD = 0;                                  // bf16 [2048][2048] packed dir outs
static constexpr size_t OFF_H  = OFF_DD + (size_t)MROWS*2*DMODEL;    // f32 [2048][1024]

DEV float b2f(ushort u) {
    union { unsigned int i; float f; } v;
    v.i = ((unsigned int)u) << 16;
    return v.f;
}
DEV ushort f2b(float f) {
    union { float f; unsigned int u; } v;
    v.f = f;
    unsigned int r = 0x7FFFu + ((v.u >> 16) & 1u);
    return (ushort)((v.u + r) >> 16);
}
DEV bf16x8 pack8(float4 a, float4 b) {
    bf16x8 r;
    r[0] = (short)f2b(a.x); r[1] = (short)f2b(a.y);
    r[2] = (short)f2b(a.z); r[3] = (short)f2b(a.w);
    r[4] = (short)f2b(b.x); r[5] = (short)f2b(b.y);
    r[6] = (short)f2b(b.z); r[7] = (short)f2b(b.w);
    return r;
}
DEV void gll16(const ushort* g, ushort* l) {
    __builtin_amdgcn_global_load_lds(
        (const __attribute__((address_space(1))) unsigned int*)g,
        (__attribute__((address_space(3))) unsigned int*)l, 16, 0, 0);
}
// XCD-locality remap for 128-id grids (4 dirb x 32 h): each XCD owns one
// dirb and a 16-h slice -> shared xs/Bq/Cq rows stay in that XCD's L2.
DEV int idmap128(int bx) {
    int x8 = bx & 7, g = bx >> 3;          // g in 0..15
    return (x8 & 3) * 32 + (x8 >> 2) * 16 + g;
}

// ---------------------------------------------------------------------------
// cvt3: three fp32->bf16 conversions in one launch (rows of 1024 floats).
// ---------------------------------------------------------------------------
__global__ __launch_bounds__(256) void cvt3_k(
    const float* __restrict__ s0, const float* __restrict__ s1,
    const float* __restrict__ s2,
    ushort* __restrict__ d0, ushort* __restrict__ d1, ushort* __restrict__ d2,
    int b0, int b1)
{
    int blk = blockIdx.x;
    const float* s; ushort* d; size_t off;
    if (blk < b0)            { s = s0; d = d0; off = (size_t)blk * 1024; }
    else if (blk < b0 + b1)  { s = s1; d = d1; off = (size_t)(blk - b0) * 1024; }
    else                     { s = s2; d = d2; off = (size_t)(blk - b0 - b1) * 1024; }
    size_t i = off + threadIdx.x * 4;
    float4 f = *(const float4*)(s + i);
    ushort4 u;
    u.x = f2b(f.x); u.y = f2b(f.y); u.z = f2b(f.z); u.w = f2b(f.w);
    *(ushort4*)(d + i) = u;
}

// ---------------------------------------------------------------------------
// GEMM: C[m][n] = sum_k A[m][k]*W[n][k], all bf16, global_load_lds width-16
// staging, BM=128, BN ∈ {64,128}, BK ∈ {64,128}.
// Generalized XOR swizzle: LDS[row][slot] holds global colgroup
// slot ^ (row mod BK/8) (16 B groups) -> conflict-free ds_read_b128.
// MODE 0: bn tiles remapped (bx+2*by)%gridX for XCD-stable W partition.
// ---------------------------------------------------------------------------
template<int MODE, int BN, int BK>
__global__ __launch_bounds__(256) void gemm_k(
    const ushort* __restrict__ A, const ushort* __restrict__ W,
    size_t wstride, void* __restrict__ outp, const float* __restrict__ resid,
    const float* __restrict__ bias, float* __restrict__ dtraw,
    int N, int K)
{
    constexpr int BM = 128;
    constexpr int MT = (BN == 128) ? 4 : 2;
    constexpr int NSL = BK / 8;          // 16B slots per LDS row
    constexpr int RPG = 64 / NSL;        // rows per gll group
    constexpr int NAG = BM / RPG / 4;    // A gll groups per wave
    constexpr int NBG = BN / RPG / 4;    // B gll groups per wave
    __shared__ ushort As[BM * BK];
    __shared__ ushort Bs[BN * BK];
    const int tid = threadIdx.x;
    const int wave = tid >> 6, lane = tid & 63;
    const int quad = lane >> 4, l16 = lane & 15;
    const int bxu = (MODE == 0)
        ? (int)((blockIdx.x + 2 * blockIdx.y) % gridDim.x) : (int)blockIdx.x;
    const int bn = bxu * BN, bm = blockIdx.y * BM;
    const int dir = blockIdx.z;
    const ushort* Wd = W + (size_t)dir * wstride;
    const int wmoff = (BN == 128) ? (wave >> 1) * 64 : wave * 32;
    const int wnoff = (BN == 128) ? (wave & 1) * 64 : 0;

    const int lrow = lane / NSL, lslot = lane % NSL;
    const ushort* aga[NAG];
    ushort* ald[NAG];
    #pragma unroll
    for (int t = 0; t < NAG; t++) {
        int li = wave * NAG + t;
        int absr = li * RPG + lrow;
        int m = bm + absr;
        size_t rowidx;
        if (MODE == 0) {
            int b = m >> 10, l = m & 1023;
            int ls = dir ? (1023 - l) : l;
            rowidx = (size_t)((b << 10) + ls);
        } else if (MODE == 1) {
            rowidx = (size_t)(dir * MROWS + m);
        } else {
            rowidx = (size_t)m;
        }
        aga[t] = A + rowidx * K + (lslot ^ (absr % NSL)) * 8;
        ald[t] = &As[li * 512];
    }
    const ushort* bga[NBG];
    ushort* bld[NBG];
    #pragma unroll
    for (int t = 0; t < NBG; t++) {
        int li = wave * NBG + t;
        int absr = li * RPG + lrow;
        int n = bn + absr;
        if (n >= N) n = N - 1;            // clamp; cols >= N discarded
        bga[t] = Wd + (size_t)n * K + (lslot ^ (absr % NSL)) * 8;
        bld[t] = &Bs[li * 512];
    }

    f32x4 acc[MT][4] = {};

    for (int k0 = 0; k0 < K; k0 += BK) {
        #pragma unroll
        for (int t = 0; t < NAG; t++) gll16(aga[t] + k0, ald[t]);
        #pragma unroll
        for (int t = 0; t < NBG; t++) gll16(bga[t] + k0, bld[t]);
        __syncthreads();

        #pragma unroll
        for (int kt = 0; kt < BK / 32; kt++) {
            const int rs = (((kt * 4 + quad) ^ (l16 % NSL))) * 8;
            bf16x8 af[MT], bfr[4];
            #pragma unroll
            for (int mt = 0; mt < MT; mt++)
                af[mt] = *(const bf16x8*)&As[(wmoff + mt * 16 + l16) * BK + rs];
            #pragma unroll
            for (int nt = 0; nt < 4; nt++)
                bfr[nt] = *(const bf16x8*)&Bs[(wnoff + nt * 16 + l16) * BK + rs];
            #pragma unroll
            for (int mt = 0; mt < MT; mt++)
                #pragma unroll
                for (int nt = 0; nt < 4; nt++)
                    acc[mt][nt] = __builtin_amdgcn_mfma_f32_16x16x32_bf16(
                        af[mt], bfr[nt], acc[mt][nt], 0, 0, 0);
        }
        __syncthreads();
    }

    // epilogue: C/D layout row=quad*4+j, col=l16
    #pragma unroll
    for (int mt = 0; mt < MT; mt++) {
        #pragma unroll
        for (int nt = 0; nt < 4; nt++) {
            #pragma unroll
            for (int j = 0; j < 4; j++) {
                int row = bm + wmoff + mt * 16 + quad * 4 + j;
                int col = bn + wnoff + nt * 16 + l16;
                if (col >= N) continue;
                float v = acc[mt][nt][j];
                if (MODE == 0) {
                    ((ushort*)outp)[(size_t)(dir * MROWS + row) * DPROJ + col] = f2b(v);
                    if (col >= 4224)
                        dtraw[(size_t)(dir * MROWS + row) * NH + (col - 4224)] = v;
                } else if (MODE == 1) {
                    int mr = dir ? ((row & 1024) | (1023 - (row & 1023))) : row;
                    ((ushort*)outp)[(size_t)mr * (2 * DMODEL) + dir * DMODEL + col] = f2b(v);
                } else {
                    float r = resid[(size_t)row * DMODEL + col] + bias[col];
                    ((float*)outp)[(size_t)row * DMODEL + col] = v + r;
                }
            }
        }
    }
}

// ---------------------------------------------------------------------------
// causal depthwise conv(width 4) + bias + SiLU — vectorized 4 chans/thread.
// Block remap: XCD owns a contiguous 512-row range so conv taps (rows
// id-3..id) stay L2-hot. dt = softplus(raw+bias); ldA = A*dt.
// dt/ldA TRANSPOSED: [dirb*32+h][l]
// ---------------------------------------------------------------------------
__global__ __launch_bounds__(256) void conv_k(
    const ushort* __restrict__ zx, const float* __restrict__ dtr,
    const float* __restrict__ cw0, const float* __restrict__ cb0,
    const float* __restrict__ cw1, const float* __restrict__ cb1,
    const float* __restrict__ dtb0, const float* __restrict__ al0,
    const float* __restrict__ dtb1, const float* __restrict__ al1,
    ushort* __restrict__ xs, float* __restrict__ Bq, float* __restrict__ Cq,
    float* __restrict__ dtq, float* __restrict__ ldq)
{
    int bx = blockIdx.x;
    int id = (bx & 7) * 512 + (bx >> 3);   // XCD-contiguous row ranges
    int dir = id >> 11;
    int m = id & 2047;
    int l = m & 1023;
    const float* cw = dir ? cw1 : cw0;
    const float* cb = dir ? cb1 : cb0;
    int tid = threadIdx.x;

    for (int c = tid * 4; c < CONVD; c += 1024) {
        float4 cbv = *(const float4*)&cb[c];
        float acc[4] = { cbv.x, cbv.y, cbv.z, cbv.w };
        #pragma unroll
        for (int t = 0; t < 4; t++) {
            int ls = l - 3 + t;
            if (ls >= 0) {
                float4 wv = *(const float4*)&cw[t * CONVD + c];
                ushort4 xv = *(const ushort4*)&zx[(size_t)(id - l + ls) * DPROJ + 2048 + c];
                acc[0] += wv.x * b2f(xv.x);
                acc[1] += wv.y * b2f(xv.y);
                acc[2] += wv.z * b2f(xv.z);
                acc[3] += wv.w * b2f(xv.w);
            }
        }
        float v[4];
        #pragma unroll
        for (int i = 0; i < 4; i++) v[i] = acc[i] / (1.f + expf(-acc[i]));
        if (c < DINNER) {
            ushort4 u;
            u.x = f2b(v[0]); u.y = f2b(v[1]); u.z = f2b(v[2]); u.w = f2b(v[3]);
            *(ushort4*)&xs[(size_t)id * DINNER + c] = u;
        } else if (c < DINNER + DSTATE) {
            *(float4*)&Bq[(size_t)id * DSTATE + (c - DINNER)] =
                make_float4(v[0], v[1], v[2], v[3]);
        } else {
            *(float4*)&Cq[(size_t)id * DSTATE + (c - DINNER - DSTATE)] =
                make_float4(v[0], v[1], v[2], v[3]);
        }
    }
    if (tid < NH) {
        const float* dtb = dir ? dtb1 : dtb0;
        const float* al  = dir ? al1 : al0;
        float raw = dtr[(size_t)id * NH + tid] + dtb[tid];
        float dt = raw > 20.f ? raw : log1pf(expf(raw));
        float ldA = -expf(al[tid]) * dt;
        int dirb = id >> 10;
        dtq[(size_t)(dirb * NH + tid) * SEQ + l] = dt;
        ldq[(size_t)(dirb * NH + tid) * SEQ + l] = ldA;
    }
}

// ---------------------------------------------------------------------------
// states_k: chunk-local end state via MFMA. Block remap via idmap128.
// ---------------------------------------------------------------------------
__global__ __launch_bounds__(256) void states_k(
    const float* __restrict__ Bq, const float* __restrict__ dtT,
    const float* __restrict__ ldT, const ushort* __restrict__ xsq,
    ushort* __restrict__ cs)
{
    int id = idmap128(blockIdx.x);
    int h = id & 31;
    int c = blockIdx.y;
    int tid = threadIdx.x;
    int wave = tid >> 6, lane = tid & 63;
    int quad = lane >> 4;
    int base = (id >> 5) << 10;
    int l0 = c * QC;

    __shared__ float wsh[QC];
    __shared__ ushort Xw[64][80];
    __shared__ ushort Bt[64][72];

    if (tid < 64) {
        float ld = ldT[(size_t)id * SEQ + l0 + tid];
        #pragma unroll
        for (int st = 1; st < 64; st <<= 1) {
            float o = __shfl_up(ld, st);
            if (tid >= st) ld += o;
        }
        float tot = __shfl(ld, 63);
        wsh[tid] = dtT[(size_t)id * SEQ + l0 + tid] * expf(tot - ld);
    }
    __syncthreads();

    {
        int j = tid >> 2, p0 = (tid & 3) * 16;
        float wj = wsh[j];
        const ushort* xrow = xsq + (size_t)(base + l0 + j) * DINNER + h * HD + p0;
        #pragma unroll
        for (int q = 0; q < 4; q++) {
            ushort4 xv = *(const ushort4*)(xrow + q * 4);
            Xw[p0 + q * 4 + 0][j] = f2b(b2f(xv.x) * wj);
            Xw[p0 + q * 4 + 1][j] = f2b(b2f(xv.y) * wj);
            Xw[p0 + q * 4 + 2][j] = f2b(b2f(xv.z) * wj);
            Xw[p0 + q * 4 + 3][j] = f2b(b2f(xv.w) * wj);
        }
        int j2 = lane, ng = wave * 16;
        const float* brow = Bq + (size_t)(base + l0 + j2) * DSTATE + ng;
        #pragma unroll
        for (int q = 0; q < 4; q++) {
            float4 f = *(const float4*)(brow + q * 4);
            Bt[ng + q * 4 + 0][j2] = f2b(f.x);
            Bt[ng + q * 4 + 1][j2] = f2b(f.y);
            Bt[ng + q * 4 + 2][j2] = f2b(f.z);
            Bt[ng + q * 4 + 3][j2] = f2b(f.w);
        }
    }
    __syncthreads();

    f32x4 acc[4] = {};
    #pragma unroll
    for (int kt = 0; kt < 2; kt++) {
        int k = kt * 32 + quad * 8;
        bf16x8 af = *(const bf16x8*)&Xw[wave * 16 + (lane & 15)][k];
        #pragma unroll
        for (int ni = 0; ni < 4; ni++) {
            bf16x8 bf = *(const bf16x8*)&Bt[ni * 16 + (lane & 15)][k];
            acc[ni] = __builtin_amdgcn_mfma_f32_16x16x32_bf16(af, bf, acc[ni], 0, 0, 0);
        }
    }

    ushort* out = cs + ((size_t)id * NCHUNK + c) * HD * DSTATE;
    #pragma unroll
    for (int ni = 0; ni < 4; ni++) {
        #pragma unroll
        for (int j = 0; j < 4; j++) {
            int p = wave * 16 + quad * 4 + j;
            int n = ni * 16 + (lane & 15);
            out[(size_t)p * DSTATE + n] = f2b(acc[ni][j]);
        }
    }
}

// ---------------------------------------------------------------------------
// Stitch: H_{c+1} = S_c + exp(sum ldA) * H_c (in place -> chunk-start H_c)
// ---------------------------------------------------------------------------
__global__ __launch_bounds__(256) void stitch_k(
    const float* __restrict__ ldT, ushort* __restrict__ cs)
{
    int id = blockIdx.x;
    int tid = threadIdx.x;
    __shared__ float red[256];
    __shared__ float dec[NCHUNK];

    float4 d4 = *(const float4*)(ldT + (size_t)id * SEQ + tid * 4);
    red[tid] = d4.x + d4.y + d4.z + d4.w;
    __syncthreads();
    if (tid < NCHUNK) {
        float s = 0.f;
        #pragma unroll
        for (int i = 0; i < 16; i++) s += red[tid * 16 + i];
        dec[tid] = expf(s);
    }
    __syncthreads();

    int p = tid >> 2, n0 = (tid & 3) * 16;
    ushort* ptr = cs + (size_t)id * NCHUNK * HD * DSTATE + p * DSTATE + n0;

    float st[16];
    #pragma unroll
    for (int i = 0; i < 16; i++) st[i] = 0.f;

    for (int c = 0; c < NCHUNK; c++) {
        ushort* row = ptr + (size_t)c * HD * DSTATE;
        float tmp[16];
        #pragma unroll
        for (int i = 0; i < 16; i++) tmp[i] = b2f(row[i]);
        #pragma unroll
        for (int i = 0; i < 16; i++) row[i] = f2b(st[i]);
        float d = dec[c];
        #pragma unroll
        for (int i = 0; i < 16; i++) st[i] = fmaf(d, st[i], tmp[i]);
    }
}

// ---------------------------------------------------------------------------
// ssd_k: intra-chunk SSD matmul + seed + D*x. Block remap via idmap128.
// ---------------------------------------------------------------------------
__global__ __launch_bounds__(256) void ssd_k(
    const float* __restrict__ Bq, const float* __restrict__ Cq,
    const float* __restrict__ dtT, const float* __restrict__ ldT,
    const ushort* __restrict__ xsq, const ushort* __restrict__ cs,
    const float* __restrict__ D0, const float* __restrict__ D1,
    ushort* __restrict__ yout)
{
    int id = idmap128(blockIdx.x);
    int dir = id >> 6, h = id & 31;
    int c = blockIdx.y;
    int tid = threadIdx.x;
    int wave = tid >> 6, lane = tid & 63;
    int quad = lane >> 4;
    int base = (id >> 5) << 10;
    int l0 = c * QC;

    __shared__ float cum[QC], dts[QC];
    __shared__ ushort Ms[64][72];
    __shared__ ushort Xb[64][80];

    {
        int j = tid >> 2, p0 = (tid & 3) * 16;
        const ushort* xrow = xsq + (size_t)(base + l0 + j) * DINNER + h * HD + p0;
        #pragma unroll
        for (int q = 0; q < 4; q++) {
            ushort4 xv = *(const ushort4*)(xrow + q * 4);
            Xb[p0 + q * 4 + 0][j] = xv.x;
            Xb[p0 + q * 4 + 1][j] = xv.y;
            Xb[p0 + q * 4 + 2][j] = xv.z;
            Xb[p0 + q * 4 + 3][j] = xv.w;
        }
    }
    if (tid < 64) {
        float ld = ldT[(size_t)id * SEQ + l0 + tid];
        #pragma unroll
        for (int st = 1; st < 64; st <<= 1) {
            float o = __shfl_up(ld, st);
            if (tid >= st) ld += o;
        }
        cum[tid] = ld;
        dts[tid] = dtT[(size_t)id * SEQ + l0 + tid];
    }

    f32x4 sacc[4] = {};
    #pragma unroll
    for (int kt = 0; kt < 2; kt++) {
        int k = kt * 32 + quad * 8;
        const float* cp = Cq + (size_t)(base + l0 + wave * 16 + (lane & 15)) * DSTATE + k;
        bf16x8 af = pack8(*(const float4*)cp, *(const float4*)(cp + 4));
        #pragma unroll
        for (int ni = 0; ni < 4; ni++) {
            const float* bp = Bq + (size_t)(base + l0 + ni * 16 + (lane & 15)) * DSTATE + k;
            bf16x8 bf = pack8(*(const float4*)bp, *(const float4*)(bp + 4));
            sacc[ni] = __builtin_amdgcn_mfma_f32_16x16x32_bf16(af, bf, sacc[ni], 0, 0, 0);
        }
    }
    __syncthreads();

    #pragma unroll
    for (int ni = 0; ni < 4; ni++) {
        int j = ni * 16 + (lane & 15);
        float cj = cum[j], dj = dts[j];
        #pragma unroll
        for (int r = 0; r < 4; r++) {
            int l = wave * 16 + quad * 4 + r;
            float v = 0.f;
            if (l >= j) v = expf(cum[l] - cj) * dj * sacc[ni][r];
            Ms[l][j] = f2b(v);
        }
    }
    __syncthreads();

    f32x4 acc[4] = {};
    #pragma unroll
    for (int kt = 0; kt < 2; kt++) {
        int k = kt * 32 + quad * 8;
        bf16x8 af = *(const bf16x8*)&Ms[wave * 16 + (lane & 15)][k];
        #pragma unroll
        for (int ni = 0; ni < 4; ni++) {
            bf16x8 bf = *(const bf16x8*)&Xb[ni * 16 + (lane & 15)][k];
            acc[ni] = __builtin_amdgcn_mfma_f32_16x16x32_bf16(af, bf, acc[ni], 0, 0, 0);
        }
    }
    const ushort* Hrow = cs + ((size_t)id * NCHUNK + c) * HD * DSTATE;
    {
        float cl = expf(cum[wave * 16 + (lane & 15)]);
        #pragma unroll
        for (int kt = 0; kt < 2; kt++) {
            int k = kt * 32 + quad * 8;
            const float* cp = Cq + (size_t)(base + l0 + wave * 16 + (lane & 15)) * DSTATE + k;
            float4 c0 = *(const float4*)cp;
            float4 c1 = *(const float4*)(cp + 4);
            float4 s0 = {c0.x * cl, c0.y * cl, c0.z * cl, c0.w * cl};
            float4 s1 = {c1.x * cl, c1.y * cl, c1.z * cl, c1.w * cl};
            bf16x8 af = pack8(s0, s1);
            #pragma unroll
            for (int ni = 0; ni < 4; ni++) {
                bf16x8 bf = *(const bf16x8*)(Hrow + (size_t)(ni * 16 + (lane & 15)) * DSTATE + k);
                acc[ni] = __builtin_amdgcn_mfma_f32_16x16x32_bf16(af, bf, acc[ni], 0, 0, 0);
            }
        }
    }

    float Dv = (dir ? D1 : D0)[h];
    int lb = wave * 16 + quad * 4;
    #pragma unroll
    for (int ni = 0; ni < 4; ni++) {
        int p = ni * 16 + (lane & 15);
        ushort4 x4 = *(const ushort4*)&Xb[p][lb];
        float xv[4] = { b2f(x4.x), b2f(x4.y), b2f(x4.z), b2f(x4.w) };
        #pragma unroll
        for (int r = 0; r < 4; r++) {
            int l = lb + r;
            yout[(size_t)(base + l0 + l) * DPROJ + 2048 + h * HD + p] =
                f2b(acc[ni][r] + Dv * xv[r]);
        }
    }
}

// ---------------------------------------------------------------------------
// gated RMSNorm (blocks 0..4095) fused with out_proj/final weight conversion
// (blocks 4096..10239; wo/wp live in the CS region — disjoint from zx).
// ---------------------------------------------------------------------------
__global__ __launch_bounds__(256) void grms_cvt_k(
    const ushort* __restrict__ zx,
    const float* __restrict__ rw0, const float* __restrict__ rw1,
    ushort* __restrict__ yn,
    const float* __restrict__ fow, const float* __restrict__ bow,
    const float* __restrict__ pw,
    ushort* __restrict__ wo, ushort* __restrict__ wp)
{
    int blk = blockIdx.x;
    int tid = threadIdx.x;
    if (blk >= 4096) {
        int b = blk - 4096;                 // 0..6143, rows of 1024 floats
        const float* s; ushort* d; size_t off;
        if (b < 2048)      { s = fow; d = wo;                           off = (size_t)b * 1024; }
        else if (b < 4096) { s = bow; d = wo + (size_t)DMODEL * DINNER; off = (size_t)(b - 2048) * 1024; }
        else               { s = pw;  d = wp;                           off = (size_t)(b - 4096) * 1024; }
        size_t i = off + tid * 4;
        float4 f = *(const float4*)(s + i);
        ushort4 u;
        u.x = f2b(f.x); u.y = f2b(f.y); u.z = f2b(f.z); u.w = f2b(f.w);
        *(ushort4*)(d + i) = u;
        return;
    }
    int id = blk;
    int dir = id >> 11;
    const float* rw = dir ? rw1 : rw0;
    int c0 = tid * 8;
    ushort zv[8], yv[8];
    *(uint4*)zv = *(const uint4*)&zx[(size_t)id * DPROJ + c0];
    *(uint4*)yv = *(const uint4*)&zx[(size_t)id * DPROJ + 2048 + c0];
    float g[8];
    float ss = 0.f;
    #pragma unroll
    for (int i = 0; i < 8; i++) {
        float z = b2f(zv[i]);
        float v = b2f(yv[i]) * (z / (1.f + expf(-z)));
        g[i] = v;
        ss += v * v;
    }
    for (int o = 32; o; o >>= 1) ss += __shfl_down(ss, o);
    __shared__ float t4[4];
    if ((tid & 63) == 0) t4[tid >> 6] = ss;
    __syncthreads();
    ss = t4[0] + t4[1] + t4[2] + t4[3];
    float sc = rsqrtf(ss * (1.f / DINNER) + 1e-5f);
    ushort u[8];
    #pragma unroll
    for (int i = 0; i < 8; i++) u[i] = f2b(g[i] * sc * rw[c0 + i]);
    *(uint4*)&yn[(size_t)id * DINNER + c0] = *(uint4*)u;
}

// ---------------------------------------------------------------------------
// LayerNorm -> fp32 out — vectorized: one float4/thread.
// ---------------------------------------------------------------------------
__global__ __launch_bounds__(256) void ln_k(
    const float* __restrict__ h, const float* __restrict__ lw,
    const float* __restrict__ lb, float* __restrict__ out)
{
    int m = blockIdx.x;
    int tid = threadIdx.x;
    int c = tid * 4;
    float4 v = *(const float4*)&h[(size_t)m * DMODEL + c];
    float s  = v.x + v.y + v.z + v.w;
    float s2 = v.x * v.x + v.y * v.y + v.z * v.z + v.w * v.w;
    for (int o = 32; o; o >>= 1) { s += __shfl_down(s, o); s2 += __shfl_down(s2, o); }
    __shared__ float ts[4], ts2[4];
    if ((tid & 63) == 0) { ts[tid >> 6] = s; ts2[tid >> 6] = s2; }
    __syncthreads();
    s  = ts[0] + ts[1] + ts[2] + ts[3];
    s2 = ts2[0] + ts2[1] + ts2[2] + ts2[3];
    float mu  = s * (1.f / DMODEL);
    float var = s2 * (1.f / DMODEL) - mu * mu;
    float sc  = rsqrtf(var + 1e-5f);
    float4 w4 = *(const float4*)&lw[c];
    float4 b4 = *(const float4*)&lb[c];
    float4 o4;
    o4.x = (v.x - mu) * sc * w4.x + b4.x;
    o4.y = (v.y - mu) * sc * w4.y + b4.y;
    o4.z = (v.z - mu) * sc * w4.z + b4.z;
    o4.w = (v.w - mu) * sc * w4.w + b4.w;
    *(float4*)&out[(size_t)m * DMODEL + c] = o4;
}

extern "C" void kernel_launch(void* const* d_in, const int* in_sizes, int n_in,
                              void* d_out, int out_size, void* d_ws, size_t ws_size,
                              hipStream_t stream)
{
    const float* x     = (const float*)d_in[0];
    const float* f_inw = (const float*)d_in[1];
    const float* f_cw  = (const float*)d_in[2];
    const float* f_cb  = (const float*)d_in[3];
    const float* f_dtb = (const float*)d_in[4];
    const float* f_al  = (const float*)d_in[5];
    const float* f_Dp  = (const float*)d_in[6];
    const float* f_rw  = (const float*)d_in[7];
    const float* f_ow  = (const float*)d_in[8];
    const float* b_inw = (const float*)d_in[9];
    const float* b_cw  = (const float*)d_in[10];
    const float* b_cb  = (const float*)d_in[11];
    const float* b_dtb = (const float*)d_in[12];
    const float* b_al  = (const float*)d_in[13];
    const float* b_Dp  = (const float*)d_in[14];
    const float* b_rw  = (const float*)d_in[15];
    const float* b_ow  = (const float*)d_in[16];
    const float* projw = (const float*)d_in[17];
    const float* projb = (const float*)d_in[18];
    const float* lnw   = (const float*)d_in[19];
    const float* lnb   = (const float*)d_in[20];

    char* ws = (char*)d_ws;
    ushort* zx  = (ushort*)(ws + OFF_ZX);
    ushort* xs  = (ushort*)(ws + OFF_XS);
    float*  Bq  = (float*)(ws + OFF_BB);
    float*  Cq  = (float*)(ws + OFF_CC);
    float*  dtq = (float*)(ws + OFF_DT);
    float*  ldq = (float*)(ws + OFF_DA);
    float*  dtr = (float*)(ws + OFF_DR);
    ushort* wbf = (ushort*)(ws + OFF_CS);
    ushort* cs  = (ushort*)(ws + OFF_CS);
    ushort* xbf = (ushort*)(ws + OFF_XS);   // x bf16, dead once conv_k writes xs
    ushort* yn  = (ushort*)(ws + OFF_XS);   // aliases xs (dead after ssd)
    ushort* dd  = (ushort*)(ws + OFF_DD);   // aliases zx (dead after grms)
    float*  hb  = (float*)(ws + OFF_H);
    ushort* wo  = (ushort*)(ws + OFF_WO);   // CS region (dead after ssd)
    ushort* wp  = (ushort*)(ws + OFF_WP);

    // K0: bf16 conversions needed before in_proj (one launch)
    cvt3_k<<<dim3(2 * DPROJ + MROWS), 256, 0, stream>>>(
        f_inw, b_inw, x, wbf, wbf + (size_t)DPROJ * DMODEL, xbf, DPROJ, DPROJ);

    // K1: in_proj, N=4256, K=1024, BN=128, BK=64
    gemm_k<0, 128, 64><<<dim3((DPROJ + 127) / 128, MROWS / 128, 2), 256, 0, stream>>>(
        xbf, wbf, (size_t)DPROJ * DMODEL, (void*)zx, nullptr, nullptr, dtr,
        DPROJ, DMODEL);

    // K2: conv + activations (overwrites xbf region with xs)
    conv_k<<<dim3(2 * MROWS), 256, 0, stream>>>(
        zx, dtr, f_cw, f_cb, b_cw, b_cb, f_dtb, f_al, b_dtb, b_al,
        xs, Bq, Cq, dtq, ldq);

    // K3: chunked SSD (states / stitch / intra-chunk matmul)
    states_k<<<dim3(128, NCHUNK), 256, 0, stream>>>(Bq, dtq, ldq, xs, cs);
    stitch_k<<<dim3(128), 256, 0, stream>>>(ldq, cs);
    ssd_k<<<dim3(128, NCHUNK), 256, 0, stream>>>(
        Bq, Cq, dtq, ldq, xs, cs, f_Dp, b_Dp, zx);

    // K4: gated RMSNorm + weight conversions (CS region now dead) fused
    grms_cvt_k<<<dim3(4096 + 3 * MROWS), 256, 0, stream>>>(
        zx, f_rw, b_rw, yn, f_ow, b_ow, projw, wo, wp);

    // K5: out_proj, N=1024, K=2048, BN=64, BK=128; packs [dou0|flip(dou1)] into dd
    gemm_k<1, 64, 128><<<dim3(DMODEL / 64, MROWS / 128, 2), 256, 0, stream>>>(
        yn, wo, (size_t)DMODEL * DINNER, (void*)dd, nullptr, nullptr, nullptr,
        DMODEL, DINNER);

    // K6: final proj + residual + bias, N=1024, K=2048, BN=64, BK=128 (fp32 out)
    gemm_k<2, 64, 128><<<dim3(DMODEL / 64, MROWS / 128, 1), 256, 0, stream>>>(
        dd, wp, 0, (void*)hb, x, projb, nullptr, DMODEL, DINNER);

    // K7: LayerNorm -> fp32 out
    ln_k<<<dim3(MROWS), 256, 0, stream>>>(hb, lnw, lnb, (float*)d_out);
}